// Round 1
// baseline (2135.144 us; speedup 1.0000x reference)
//
#include <hip/hip_runtime.h>
#include <hip/hip_bf16.h>
#include <math.h>

#define NN 50000
#define EE 800000
#define BBATCH 64
#define DDIM 64
#define NLAYER 4
#define NIN 7
#define NHEAD 4

// ---------------- device helpers ----------------
static __device__ __forceinline__ float wave_sum(float v) {
#pragma unroll
  for (int m = 32; m > 0; m >>= 1) v += __shfl_xor(v, m, 64);
  return v;
}

static __device__ __forceinline__ float gelu_t(float x) {
  // tanh-approximate GELU (jax.nn.gelu default)
  float z = 0.7978845608f * (x + 0.044715f * x * x * x);
  float t = 2.f / (1.f + __expf(-2.f * z)) - 1.f;
  return 0.5f * x * (1.f + t);
}

// ---------------- CSR build ----------------
__global__ void k_init_cnt(int* cnt, int n) {
  int i = blockIdx.x * blockDim.x + threadIdx.x;
  if (i < n) cnt[i] = 1;  // self loop
}

__global__ void k_count_edges(const int* __restrict__ dst, int e, int* cnt) {
  int i = blockIdx.x * blockDim.x + threadIdx.x;
  if (i < e) atomicAdd(&cnt[dst[i]], 1);
}

// scan stage 1: per-1024-chunk sums
__global__ void k_scan_bsum(const int* __restrict__ cnt, int n, int* bsum) {
  __shared__ int red[256];
  int b = blockIdx.x, t = threadIdx.x;
  int s = 0;
  for (int i = b * 1024 + t; i < (b + 1) * 1024; i += 256)
    if (i < n) s += cnt[i];
  red[t] = s;
  __syncthreads();
  for (int o = 128; o > 0; o >>= 1) {
    if (t < o) red[t] += red[t + o];
    __syncthreads();
  }
  if (t == 0) bsum[b] = red[0];
}

// scan stage 2: exclusive scan of block sums (small)
__global__ void k_scan_offsets(int* bsum, int nb) {
  if (threadIdx.x == 0 && blockIdx.x == 0) {
    int acc = 0;
    for (int i = 0; i < nb; i++) { int v = bsum[i]; bsum[i] = acc; acc += v; }
  }
}

// scan stage 3: per-chunk exclusive scan + offset; writes indptr[0..n]
__global__ void k_scan_final(const int* __restrict__ cnt, int n,
                             const int* __restrict__ bsum, int* indptr) {
  __shared__ int lds[256];
  int b = blockIdx.x, t = threadIdx.x;
  int base = b * 1024;
  int v[4];
  int s = 0;
#pragma unroll
  for (int j = 0; j < 4; j++) {
    int i = base + t * 4 + j;
    v[j] = (i < n) ? cnt[i] : 0;
    s += v[j];
  }
  lds[t] = s;
  __syncthreads();
  // inclusive Hillis-Steele over 256 thread-sums
  for (int o = 1; o < 256; o <<= 1) {
    int x = (t >= o) ? lds[t - o] : 0;
    __syncthreads();
    lds[t] += x;
    __syncthreads();
  }
  int run = bsum[b] + lds[t] - s;  // exclusive prefix for this thread's first elem
#pragma unroll
  for (int j = 0; j < 4; j++) {
    int i = base + t * 4 + j;
    if (i <= n) indptr[i] = run;
    run += v[j];
  }
}

__global__ void k_csr_self(const int* __restrict__ indptr, int* nxt, int* esrc, int n) {
  int i = blockIdx.x * blockDim.x + threadIdx.x;
  if (i < n) {
    int p = indptr[i];
    esrc[p] = i;      // self loop first
    nxt[i] = p + 1;
  }
}

__global__ void k_csr_fill(const int* __restrict__ src, const int* __restrict__ dst,
                           int e, int* nxt, int* esrc) {
  int i = blockIdx.x * blockDim.x + threadIdx.x;
  if (i < e) {
    int p = atomicAdd(&nxt[dst[i]], 1);
    esrc[p] = src[i];
  }
}

// ---------------- batch segment starts (batch is sorted) ----------------
__global__ void k_batch_starts(const int* __restrict__ batch, int n, int nb, int* starts) {
  int i = blockIdx.x * blockDim.x + threadIdx.x;
  if (i >= n) return;
  int b = batch[i];
  if (i == 0) {
    for (int x = 0; x <= b; x++) starts[x] = 0;
  } else {
    int pb = batch[i - 1];
    if (pb != b)
      for (int x = pb + 1; x <= b; x++) starts[x] = i;
  }
  if (i == n - 1) {
    for (int x = b + 1; x <= nb; x++) starts[x] = n;
  }
}

// ---------------- encoder ----------------
__global__ void k_encoder(const float* __restrict__ x, const float* __restrict__ W,
                          const float* __restrict__ bias, float* __restrict__ h, int n) {
  int idx = blockIdx.x * blockDim.x + threadIdx.x;
  if (idx >= n * 64) return;
  int i = idx >> 6, d = idx & 63;
  float acc = bias[d];
#pragma unroll
  for (int k = 0; k < NIN; k++) acc += x[i * NIN + k] * W[k * 64 + d];
  h[idx] = acc;
}

// ---------------- generic tiled fp32 GEMM: C = act(A[n,K] @ W[K,Co] + bias) (+res) --------
// A row stride == K. tile: 64 nodes x 64 cols, 4x4 per thread.
#define GPAD 4
template <int K, int ACT, bool RES>
__global__ __launch_bounds__(256) void k_gemm(const float* __restrict__ A,
                                              const float* __restrict__ W,
                                              const float* __restrict__ bias,
                                              const float* __restrict__ res,
                                              float* __restrict__ C, int n, int Co) {
  __shared__ float At[K][64 + GPAD];
  __shared__ float Ws[K][64 + GPAD];
  const int tid = threadIdx.x;
  const int nb = blockIdx.x * 64, c0 = blockIdx.y * 64;
  for (int idx = tid; idx < 64 * K; idx += 256) {
    int r = idx / K, k = idx % K;
    int gn = nb + r;
    At[k][r] = (gn < n) ? A[(size_t)gn * K + k] : 0.f;
  }
  for (int idx = tid; idx < 64 * K; idx += 256) {
    int k = idx >> 6, c = idx & 63;
    Ws[k][c] = W[k * Co + c0 + c];
  }
  __syncthreads();
  const int tr = (tid & 15) * 4, tc = (tid >> 4) * 4;
  float acc[4][4] = {};
#pragma unroll 8
  for (int k = 0; k < K; k++) {
    float4 a = *(const float4*)&At[k][tr];
    float4 b = *(const float4*)&Ws[k][tc];
    float av[4] = {a.x, a.y, a.z, a.w};
    float bv[4] = {b.x, b.y, b.z, b.w};
#pragma unroll
    for (int i = 0; i < 4; i++)
#pragma unroll
      for (int j = 0; j < 4; j++) acc[i][j] += av[i] * bv[j];
  }
  float bs[4];
#pragma unroll
  for (int j = 0; j < 4; j++) bs[j] = bias ? bias[c0 + tc + j] : 0.f;
#pragma unroll
  for (int i = 0; i < 4; i++) {
    int gn = nb + tr + i;
    if (gn < n) {
#pragma unroll
      for (int j = 0; j < 4; j++) {
        float v = acc[i][j] + bs[j];
        if (ACT == 1) v = (v >= 0.f) ? v : 0.2f * v;
        else if (ACT == 2) v = gelu_t(v);
        if (RES) v += res[(size_t)gn * Co + c0 + tc + j];
        C[(size_t)gn * Co + c0 + tc + j] = v;
      }
    }
  }
}

// ---------------- GATv2 aggregation + residual + LayerNorm (fused) ----------------
// one wave per node; online softmax over incoming edges
__global__ __launch_bounds__(256) void k_gat(const float* __restrict__ xl,
                                             const float* __restrict__ xr,
                                             const float* __restrict__ att,
                                             const float* __restrict__ gbias,
                                             const float* __restrict__ lng,
                                             const float* __restrict__ lnb,
                                             const float* __restrict__ h,
                                             const int* __restrict__ indptr,
                                             const int* __restrict__ esrc,
                                             float* __restrict__ h2, int n) {
  int wave = threadIdx.x >> 6, lane = threadIdx.x & 63;
  int node = blockIdx.x * 4 + wave;
  if (node >= n) return;
  float xr_d[4], att_d[4];
  float acc[4] = {0.f, 0.f, 0.f, 0.f};
  float den[4] = {0.f, 0.f, 0.f, 0.f};
  float m[4] = {-INFINITY, -INFINITY, -INFINITY, -INFINITY};
  const float* xrp = xr + (size_t)node * 256;
#pragma unroll
  for (int hh = 0; hh < 4; hh++) {
    xr_d[hh] = xrp[hh * 64 + lane];
    att_d[hh] = att[hh * 64 + lane];
  }
  int beg = indptr[node], end = indptr[node + 1];
  for (int j = beg; j < end; j++) {
    int s = esrc[j];
    const float* xp = xl + (size_t)s * 256;
    float xs[4], e[4];
#pragma unroll
    for (int hh = 0; hh < 4; hh++) xs[hh] = xp[hh * 64 + lane];
#pragma unroll
    for (int hh = 0; hh < 4; hh++) {
      float t = xs[hh] + xr_d[hh];
      t = (t >= 0.f) ? t : 0.2f * t;
      t *= att_d[hh];
      e[hh] = wave_sum(t);
    }
#pragma unroll
    for (int hh = 0; hh < 4; hh++) {
      float nm = fmaxf(m[hh], e[hh]);
      float so = __expf(m[hh] - nm);   // exp(-inf)=0 on first edge
      float pw = __expf(e[hh] - nm);
      den[hh] = den[hh] * so + pw;
      acc[hh] = acc[hh] * so + pw * xs[hh];
      m[hh] = nm;
    }
  }
  float o = 0.25f * (acc[0] / den[0] + acc[1] / den[1] + acc[2] / den[2] + acc[3] / den[3]) +
            gbias[lane];
  float y = h[(size_t)node * 64 + lane] + o;
  float mu = wave_sum(y) * (1.f / 64.f);
  float dd = y - mu;
  float var = wave_sum(dd * dd) * (1.f / 64.f);
  float outv = dd * rsqrtf(var + 1e-5f) * lng[lane] + lnb[lane];
  h2[(size_t)node * 64 + lane] = outv;
}

// ---------------- global pooling (mean+max per batch) ----------------
__global__ void k_pool(const float* __restrict__ lat, const int* __restrict__ starts,
                       float* __restrict__ gl) {
  int b = blockIdx.x;
  int t = threadIdx.x;
  int lane = t & 63, sub = t >> 6;
  int s = starts[b], e = starts[b + 1];
  float sum = 0.f, mx = -3.4e38f;
  for (int i = s + sub; i < e; i += 4) {
    float v = lat[(size_t)i * 64 + lane];
    sum += v;
    mx = fmaxf(mx, v);
  }
  __shared__ float ls[4][64], lm[4][64];
  ls[sub][lane] = sum;
  lm[sub][lane] = mx;
  __syncthreads();
  if (sub == 0) {
#pragma unroll
    for (int j = 1; j < 4; j++) {
      sum += ls[j][lane];
      mx = fmaxf(mx, lm[j][lane]);
    }
    int cnt = e - s;
    float mean = sum / fmaxf((float)cnt, 1.0f);
    gl[b * 128 + lane] = mean;
    gl[b * 128 + 64 + lane] = mx;
  }
}

// ---------------- ctx = gelu(gl @ W1 + b1) @ W2 + b2, per batch ----------------
__global__ void k_ctx(const float* __restrict__ gl, const float* __restrict__ W1,
                      const float* __restrict__ b1, const float* __restrict__ W2,
                      const float* __restrict__ b2, float* __restrict__ ctx) {
  int b = blockIdx.x;
  int j = threadIdx.x;  // 64 threads
  __shared__ float g[128], tt[64];
  g[j] = gl[b * 128 + j];
  g[64 + j] = gl[b * 128 + 64 + j];
  __syncthreads();
  float acc = b1[j];
  for (int k = 0; k < 128; k++) acc += g[k] * W1[k * 64 + j];
  tt[j] = gelu_t(acc);
  __syncthreads();
  float acc2 = b2[j];
  for (int k = 0; k < 64; k++) acc2 += tt[k] * W2[k * 64 + j];
  ctx[b * 64 + j] = acc2;
}

__global__ void k_add_ctx(float* __restrict__ h, const float* __restrict__ ctx,
                          const int* __restrict__ batch, int n) {
  int idx = blockIdx.x * blockDim.x + threadIdx.x;
  if (idx >= n * 64) return;
  int i = idx >> 6, d = idx & 63;
  h[idx] += ctx[batch[i] * 64 + d];
}

// ---------------- decoder stage 2: out = tD @ W2 + b2 ([64,2]) ----------------
__global__ void k_dec2(const float* __restrict__ tD, const float* __restrict__ W2,
                       const float* __restrict__ b2, float* __restrict__ out, int n) {
  int idx = blockIdx.x * blockDim.x + threadIdx.x;
  if (idx >= n * 2) return;
  int i = idx >> 1, j = idx & 1;
  float acc = b2[j];
#pragma unroll 8
  for (int k = 0; k < 64; k++) acc += tD[(size_t)i * 64 + k] * W2[k * 2 + j];
  out[idx] = acc;
}

// ---------------- host ----------------
extern "C" void kernel_launch(void* const* d_in, const int* in_sizes, int n_in,
                              void* d_out, int out_size, void* d_ws, size_t ws_size,
                              hipStream_t stream) {
  const float* x = (const float*)d_in[0];
  const int* ei = (const int*)d_in[1];
  const int* batch = (const int*)d_in[2];
  const float* enc_W = (const float*)d_in[3];
  const float* enc_b = (const float*)d_in[4];
  const float* gat_Wl = (const float*)d_in[5];
  const float* gat_Wr = (const float*)d_in[6];
  const float* gat_att = (const float*)d_in[7];
  const float* gat_b = (const float*)d_in[8];
  const float* ln_g = (const float*)d_in[9];
  const float* ln_b = (const float*)d_in[10];
  const float* ffn_W1 = (const float*)d_in[11];
  const float* ffn_b1 = (const float*)d_in[12];
  const float* ffn_W2 = (const float*)d_in[13];
  const float* ffn_b2 = (const float*)d_in[14];
  const float* n2g_W1 = (const float*)d_in[15];
  const float* n2g_b1 = (const float*)d_in[16];
  const float* n2g_W2 = (const float*)d_in[17];
  const float* n2g_b2 = (const float*)d_in[18];
  const float* g2n_W1 = (const float*)d_in[19];
  const float* g2n_b1 = (const float*)d_in[20];
  const float* g2n_W2 = (const float*)d_in[21];
  const float* g2n_b2 = (const float*)d_in[22];
  const float* dec_W1 = (const float*)d_in[23];
  const float* dec_b1 = (const float*)d_in[24];
  const float* dec_W2 = (const float*)d_in[25];
  const float* dec_b2 = (const float*)d_in[26];

  const int N = NN, E = EE;
  const int* e_src = ei;
  const int* e_dst = ei + E;

  // workspace carve
  float* h = (float*)d_ws;                 // N*64
  float* h2 = h + (size_t)N * 64;          // N*64
  float* xl = h2 + (size_t)N * 64;         // N*256
  float* xr = xl + (size_t)N * 256;        // N*256
  float* t1 = xr + (size_t)N * 256;        // N*128 (tmpA = t1, lat = t1 + N*64)
  float* gl = t1 + (size_t)N * 128;        // B*128
  float* ctx = gl + BBATCH * 128;          // B*64
  int* cnt = (int*)(ctx + BBATCH * 64);    // N (reused as nxt)
  int* indptr = cnt + N;                   // N+1
  int* esrc = indptr + N + 1;              // E+N
  int* bsum = esrc + (E + N);              // scan chunks
  int* starts = bsum + 64;                 // B+1
  float* tmpA = t1;
  float* lat = t1 + (size_t)N * 64;

  const int TPB = 256;
  const int NBLK_SCAN = (N + 1 + 1023) / 1024;  // 49

  // ---- CSR build ----
  hipLaunchKernelGGL(k_init_cnt, dim3((N + TPB - 1) / TPB), dim3(TPB), 0, stream, cnt, N);
  hipLaunchKernelGGL(k_count_edges, dim3((E + TPB - 1) / TPB), dim3(TPB), 0, stream, e_dst, E, cnt);
  hipLaunchKernelGGL(k_scan_bsum, dim3(NBLK_SCAN), dim3(256), 0, stream, cnt, N, bsum);
  hipLaunchKernelGGL(k_scan_offsets, dim3(1), dim3(64), 0, stream, bsum, NBLK_SCAN);
  hipLaunchKernelGGL(k_scan_final, dim3(NBLK_SCAN), dim3(256), 0, stream, cnt, N, bsum, indptr);
  hipLaunchKernelGGL(k_csr_self, dim3((N + TPB - 1) / TPB), dim3(TPB), 0, stream, indptr, cnt, esrc, N);
  hipLaunchKernelGGL(k_csr_fill, dim3((E + TPB - 1) / TPB), dim3(TPB), 0, stream, e_src, e_dst, E, cnt, esrc);
  hipLaunchKernelGGL(k_batch_starts, dim3((N + TPB - 1) / TPB), dim3(TPB), 0, stream, batch, N, BBATCH, starts);

  // ---- encoder ----
  hipLaunchKernelGGL(k_encoder, dim3((N * 64 + TPB - 1) / TPB), dim3(TPB), 0, stream,
                     x, enc_W, enc_b, h, N);

  const int GN = (N + 63) / 64;  // 782

  for (int l = 0; l < NLAYER; l++) {
    const float* Wl = gat_Wl + (size_t)l * 64 * 256;
    const float* Wr = gat_Wr + (size_t)l * 64 * 256;
    const float* attl = gat_att + (size_t)l * 256;
    const float* gbl = gat_b + (size_t)l * 64;
    const float* lngl = ln_g + (size_t)l * 64;
    const float* lnbl = ln_b + (size_t)l * 64;
    const float* fW1 = ffn_W1 + (size_t)l * 64 * 128;
    const float* fb1 = ffn_b1 + (size_t)l * 128;
    const float* fW2 = ffn_W2 + (size_t)l * 128 * 64;
    const float* fb2 = ffn_b2 + (size_t)l * 64;
    const float* nW1 = n2g_W1 + (size_t)l * 64 * 64;
    const float* nb1 = n2g_b1 + (size_t)l * 64;
    const float* nW2 = n2g_W2 + (size_t)l * 64 * 64;
    const float* nb2 = n2g_b2 + (size_t)l * 64;
    const float* gW1 = g2n_W1 + (size_t)l * 128 * 64;
    const float* gb1 = g2n_b1 + (size_t)l * 64;
    const float* gW2 = g2n_W2 + (size_t)l * 64 * 64;
    const float* gb2 = g2n_b2 + (size_t)l * 64;

    // xl = h @ Wl ; xr = h @ Wr  (no bias)
    hipLaunchKernelGGL((k_gemm<64, 0, false>), dim3(GN, 4), dim3(256), 0, stream,
                       h, Wl, (const float*)nullptr, (const float*)nullptr, xl, N, 256);
    hipLaunchKernelGGL((k_gemm<64, 0, false>), dim3(GN, 4), dim3(256), 0, stream,
                       h, Wr, (const float*)nullptr, (const float*)nullptr, xr, N, 256);
    // GAT aggregate + residual + LN -> h2
    hipLaunchKernelGGL(k_gat, dim3((N + 3) / 4), dim3(256), 0, stream,
                       xl, xr, attl, gbl, lngl, lnbl, h, indptr, esrc, h2, N);
    // FFN
    hipLaunchKernelGGL((k_gemm<64, 1, false>), dim3(GN, 2), dim3(256), 0, stream,
                       h2, fW1, fb1, (const float*)nullptr, t1, N, 128);
    hipLaunchKernelGGL((k_gemm<128, 0, true>), dim3(GN, 1), dim3(256), 0, stream,
                       t1, fW2, fb2, h2, h, N, 64);
    // global context: lat = gelu(h@nW1+nb1)@nW2+nb2
    hipLaunchKernelGGL((k_gemm<64, 2, false>), dim3(GN, 1), dim3(256), 0, stream,
                       h, nW1, nb1, (const float*)nullptr, tmpA, N, 64);
    hipLaunchKernelGGL((k_gemm<64, 0, false>), dim3(GN, 1), dim3(256), 0, stream,
                       tmpA, nW2, nb2, (const float*)nullptr, lat, N, 64);
    hipLaunchKernelGGL(k_pool, dim3(BBATCH), dim3(256), 0, stream, lat, starts, gl);
    hipLaunchKernelGGL(k_ctx, dim3(BBATCH), dim3(64), 0, stream, gl, gW1, gb1, gW2, gb2, ctx);
    hipLaunchKernelGGL(k_add_ctx, dim3((N * 64 + TPB - 1) / TPB), dim3(TPB), 0, stream,
                       h, ctx, batch, N);
  }

  // decoder
  hipLaunchKernelGGL((k_gemm<64, 2, false>), dim3(GN, 1), dim3(256), 0, stream,
                     h, dec_W1, dec_b1, (const float*)nullptr, tmpA, N, 64);
  hipLaunchKernelGGL(k_dec2, dim3((N * 2 + TPB - 1) / TPB), dim3(TPB), 0, stream,
                     tmpA, dec_W2, dec_b2, (float*)d_out, N);
}

// Round 2
// 1773.374 us; speedup vs baseline: 1.2040x; 1.2040x over previous
//
#include <hip/hip_runtime.h>
#include <hip/hip_bf16.h>
#include <math.h>

#define NN 50000
#define EE 800000
#define BBATCH 64
#define DDIM 64
#define NLAYER 4
#define NIN 7
#define NHEAD 4

// ---------------- device helpers ----------------
static __device__ __forceinline__ float wave_sum(float v) {
#pragma unroll
  for (int m = 32; m > 0; m >>= 1) v += __shfl_xor(v, m, 64);
  return v;
}

static __device__ __forceinline__ float gelu_t(float x) {
  // tanh-approximate GELU (jax.nn.gelu default)
  float z = 0.7978845608f * (x + 0.044715f * x * x * x);
  float t = 2.f / (1.f + __expf(-2.f * z)) - 1.f;
  return 0.5f * x * (1.f + t);
}

// ---------------- CSR build ----------------
__global__ void k_init_cnt(int* cnt, int n) {
  int i = blockIdx.x * blockDim.x + threadIdx.x;
  if (i < n) cnt[i] = 1;  // self loop
}

__global__ void k_count_edges(const int* __restrict__ dst, int e, int* cnt) {
  int i = blockIdx.x * blockDim.x + threadIdx.x;
  if (i < e) atomicAdd(&cnt[dst[i]], 1);
}

// scan stage 1: per-1024-chunk sums
__global__ void k_scan_bsum(const int* __restrict__ cnt, int n, int* bsum) {
  __shared__ int red[256];
  int b = blockIdx.x, t = threadIdx.x;
  int s = 0;
  for (int i = b * 1024 + t; i < (b + 1) * 1024; i += 256)
    if (i < n) s += cnt[i];
  red[t] = s;
  __syncthreads();
  for (int o = 128; o > 0; o >>= 1) {
    if (t < o) red[t] += red[t + o];
    __syncthreads();
  }
  if (t == 0) bsum[b] = red[0];
}

// scan stage 2: exclusive scan of block sums (small)
__global__ void k_scan_offsets(int* bsum, int nb) {
  if (threadIdx.x == 0 && blockIdx.x == 0) {
    int acc = 0;
    for (int i = 0; i < nb; i++) { int v = bsum[i]; bsum[i] = acc; acc += v; }
  }
}

// scan stage 3: per-chunk exclusive scan + offset; writes indptr[0..n]
__global__ void k_scan_final(const int* __restrict__ cnt, int n,
                             const int* __restrict__ bsum, int* indptr) {
  __shared__ int lds[256];
  int b = blockIdx.x, t = threadIdx.x;
  int base = b * 1024;
  int v[4];
  int s = 0;
#pragma unroll
  for (int j = 0; j < 4; j++) {
    int i = base + t * 4 + j;
    v[j] = (i < n) ? cnt[i] : 0;
    s += v[j];
  }
  lds[t] = s;
  __syncthreads();
  // inclusive Hillis-Steele over 256 thread-sums
  for (int o = 1; o < 256; o <<= 1) {
    int x = (t >= o) ? lds[t - o] : 0;
    __syncthreads();
    lds[t] += x;
    __syncthreads();
  }
  int run = bsum[b] + lds[t] - s;  // exclusive prefix for this thread's first elem
#pragma unroll
  for (int j = 0; j < 4; j++) {
    int i = base + t * 4 + j;
    if (i <= n) indptr[i] = run;
    run += v[j];
  }
}

__global__ void k_csr_self(const int* __restrict__ indptr, int* nxt, int* esrc, int n) {
  int i = blockIdx.x * blockDim.x + threadIdx.x;
  if (i < n) {
    int p = indptr[i];
    esrc[p] = i;      // self loop first
    nxt[i] = p + 1;
  }
}

__global__ void k_csr_fill(const int* __restrict__ src, const int* __restrict__ dst,
                           int e, int* nxt, int* esrc) {
  int i = blockIdx.x * blockDim.x + threadIdx.x;
  if (i < e) {
    int p = atomicAdd(&nxt[dst[i]], 1);
    esrc[p] = src[i];
  }
}

// ---------------- batch segment starts (batch is sorted) ----------------
__global__ void k_batch_starts(const int* __restrict__ batch, int n, int nb, int* starts) {
  int i = blockIdx.x * blockDim.x + threadIdx.x;
  if (i >= n) return;
  int b = batch[i];
  if (i == 0) {
    for (int x = 0; x <= b; x++) starts[x] = 0;
  } else {
    int pb = batch[i - 1];
    if (pb != b)
      for (int x = pb + 1; x <= b; x++) starts[x] = i;
  }
  if (i == n - 1) {
    for (int x = b + 1; x <= nb; x++) starts[x] = n;
  }
}

// ---------------- encoder ----------------
__global__ void k_encoder(const float* __restrict__ x, const float* __restrict__ W,
                          const float* __restrict__ bias, float* __restrict__ h, int n) {
  int idx = blockIdx.x * blockDim.x + threadIdx.x;
  if (idx >= n * 64) return;
  int i = idx >> 6, d = idx & 63;
  float acc = bias[d];
#pragma unroll
  for (int k = 0; k < NIN; k++) acc += x[i * NIN + k] * W[k * 64 + d];
  h[idx] = acc;
}

// ---------------- generic tiled fp32 GEMM: C = act(A[n,K] @ W[K,Co] + bias) (+res) --------
// A row stride == K. tile: 64 nodes x 64 cols, 4x4 per thread.
#define GPAD 4
template <int K, int ACT, bool RES>
__global__ __launch_bounds__(256) void k_gemm(const float* __restrict__ A,
                                              const float* __restrict__ W,
                                              const float* __restrict__ bias,
                                              const float* __restrict__ res,
                                              float* __restrict__ C, int n, int Co) {
  __shared__ float At[K][64 + GPAD];
  __shared__ float Ws[K][64 + GPAD];
  const int tid = threadIdx.x;
  const int nb = blockIdx.x * 64, c0 = blockIdx.y * 64;
  for (int idx = tid; idx < 64 * K; idx += 256) {
    int r = idx / K, k = idx % K;
    int gn = nb + r;
    At[k][r] = (gn < n) ? A[(size_t)gn * K + k] : 0.f;
  }
  for (int idx = tid; idx < 64 * K; idx += 256) {
    int k = idx >> 6, c = idx & 63;
    Ws[k][c] = W[k * Co + c0 + c];
  }
  __syncthreads();
  const int tr = (tid & 15) * 4, tc = (tid >> 4) * 4;
  float acc[4][4] = {};
#pragma unroll 8
  for (int k = 0; k < K; k++) {
    float4 a = *(const float4*)&At[k][tr];
    float4 b = *(const float4*)&Ws[k][tc];
    float av[4] = {a.x, a.y, a.z, a.w};
    float bv[4] = {b.x, b.y, b.z, b.w};
#pragma unroll
    for (int i = 0; i < 4; i++)
#pragma unroll
      for (int j = 0; j < 4; j++) acc[i][j] += av[i] * bv[j];
  }
  float bs[4];
#pragma unroll
  for (int j = 0; j < 4; j++) bs[j] = bias ? bias[c0 + tc + j] : 0.f;
#pragma unroll
  for (int i = 0; i < 4; i++) {
    int gn = nb + tr + i;
    if (gn < n) {
#pragma unroll
      for (int j = 0; j < 4; j++) {
        float v = acc[i][j] + bs[j];
        if (ACT == 1) v = (v >= 0.f) ? v : 0.2f * v;
        else if (ACT == 2) v = gelu_t(v);
        if (RES) v += res[(size_t)gn * Co + c0 + tc + j];
        C[(size_t)gn * Co + c0 + tc + j] = v;
      }
    }
  }
}

// ---------------- GATv2 aggregation + residual + LayerNorm (fused) ----------------
// one wave per node; 4 edges per iteration, 16 lanes per edge.
// lane = 16*q + r : edge-stream q, dims 4r..4r+3 (per head), float4 gathers.
// each 16-lane group keeps its own online-softmax state; states merged at the end.
__global__ __launch_bounds__(256) void k_gat(const float* __restrict__ xl,
                                             const float* __restrict__ xr,
                                             const float* __restrict__ att,
                                             const float* __restrict__ gbias,
                                             const float* __restrict__ lng,
                                             const float* __restrict__ lnb,
                                             const float* __restrict__ h,
                                             const int* __restrict__ indptr,
                                             const int* __restrict__ esrc,
                                             float* __restrict__ h2, int n) {
  const int wave = threadIdx.x >> 6, lane = threadIdx.x & 63;
  const int node = blockIdx.x * 4 + wave;
  if (node >= n) return;
  const int q = lane >> 4, r = lane & 15;

  float4 xr_d[4], att_d[4];
  const float* xrp = xr + (size_t)node * 256 + 4 * r;
#pragma unroll
  for (int hh = 0; hh < 4; hh++) {
    xr_d[hh] = *(const float4*)(xrp + hh * 64);
    att_d[hh] = *(const float4*)(att + hh * 64 + 4 * r);
  }

  float acc[4][4] = {};                       // [head][dim4]
  float den[4] = {0.f, 0.f, 0.f, 0.f};
  float m[4] = {-1e30f, -1e30f, -1e30f, -1e30f};  // -1e30 sentinel, NOT -inf (NaN-safe merges)

  const int beg = indptr[node], end = indptr[node + 1];
  for (int jb = beg; jb < end; jb += 4) {
    const int j = jb + q;
    const bool valid = j < end;               // uniform within each 16-lane group
    const int s = valid ? esrc[j] : 0;
    const float* xp = xl + (size_t)s * 256 + 4 * r;
    float4 xs[4];
#pragma unroll
    for (int hh = 0; hh < 4; hh++) xs[hh] = *(const float4*)(xp + hh * 64);

    float p[4];
#pragma unroll
    for (int hh = 0; hh < 4; hh++) {
      float t0 = xs[hh].x + xr_d[hh].x; t0 = fmaxf(t0, 0.2f * t0);
      float t1 = xs[hh].y + xr_d[hh].y; t1 = fmaxf(t1, 0.2f * t1);
      float t2 = xs[hh].z + xr_d[hh].z; t2 = fmaxf(t2, 0.2f * t2);
      float t3 = xs[hh].w + xr_d[hh].w; t3 = fmaxf(t3, 0.2f * t3);
      p[hh] = t0 * att_d[hh].x + t1 * att_d[hh].y + t2 * att_d[hh].z + t3 * att_d[hh].w;
    }
    // reduce within 16-lane group (xor masks < 16 stay inside the group)
#pragma unroll
    for (int msk = 1; msk < 16; msk <<= 1) {
#pragma unroll
      for (int hh = 0; hh < 4; hh++) p[hh] += __shfl_xor(p[hh], msk, 64);
    }
#pragma unroll
    for (int hh = 0; hh < 4; hh++) {
      const float e = valid ? p[hh] : -1e30f;
      const float nm = fmaxf(m[hh], e);
      const float so = __expf(m[hh] - nm);    // 0 when m was sentinel and e finite
      const float pw = __expf(e - nm);        // 0 when e is sentinel and m finite
      den[hh] = den[hh] * so + pw;
      m[hh] = nm;
      const float* xsf = (const float*)&xs[hh];
#pragma unroll
      for (int j4 = 0; j4 < 4; j4++) acc[hh][j4] = acc[hh][j4] * so + pw * xsf[j4];
    }
  }

  // merge the 4 group states (flash-style) via butterfly xor 16, 32
#pragma unroll
  for (int msk = 16; msk < 64; msk <<= 1) {
#pragma unroll
    for (int hh = 0; hh < 4; hh++) {
      const float mo = __shfl_xor(m[hh], msk, 64);
      const float deno = __shfl_xor(den[hh], msk, 64);
      float ao[4];
#pragma unroll
      for (int j4 = 0; j4 < 4; j4++) ao[j4] = __shfl_xor(acc[hh][j4], msk, 64);
      const float M = fmaxf(m[hh], mo);
      const float sA = __expf(m[hh] - M);     // both-sentinel pair -> exp(0)=1, den/acc are 0
      const float sB = __expf(mo - M);
      den[hh] = den[hh] * sA + deno * sB;
#pragma unroll
      for (int j4 = 0; j4 < 4; j4++) acc[hh][j4] = acc[hh][j4] * sA + ao[j4] * sB;
      m[hh] = M;
    }
  }

  // epilogue: head-average + bias + residual + LayerNorm (all lanes redundant x4 per dim)
  float rden[4];
#pragma unroll
  for (int hh = 0; hh < 4; hh++) rden[hh] = 1.f / (den[hh] + 1e-16f);
  const float4 hv = *(const float4*)(h + (size_t)node * 64 + 4 * r);
  const float4 gb = *(const float4*)(gbias + 4 * r);
  const float* hvf = (const float*)&hv;
  const float* gbf = (const float*)&gb;
  float y[4];
  float s4 = 0.f;
#pragma unroll
  for (int j4 = 0; j4 < 4; j4++) {
    const float o = 0.25f * (acc[0][j4] * rden[0] + acc[1][j4] * rden[1] +
                             acc[2][j4] * rden[2] + acc[3][j4] * rden[3]) + gbf[j4];
    y[j4] = hvf[j4] + o;
    s4 += y[j4];
  }
  const float mu = wave_sum(s4) * (1.f / 256.f);  // each dim counted 4x
  float v4 = 0.f;
  float dv[4];
#pragma unroll
  for (int j4 = 0; j4 < 4; j4++) {
    dv[j4] = y[j4] - mu;
    v4 += dv[j4] * dv[j4];
  }
  const float var = wave_sum(v4) * (1.f / 256.f);
  const float rstd = rsqrtf(var + 1e-5f);
  if (q == 0) {
    const float4 gv = *(const float4*)(lng + 4 * r);
    const float4 bv = *(const float4*)(lnb + 4 * r);
    const float* gvf = (const float*)&gv;
    const float* bvf = (const float*)&bv;
    float4 outv;
    ((float*)&outv)[0] = dv[0] * rstd * gvf[0] + bvf[0];
    ((float*)&outv)[1] = dv[1] * rstd * gvf[1] + bvf[1];
    ((float*)&outv)[2] = dv[2] * rstd * gvf[2] + bvf[2];
    ((float*)&outv)[3] = dv[3] * rstd * gvf[3] + bvf[3];
    *(float4*)(h2 + (size_t)node * 64 + 4 * r) = outv;
  }
}

// ---------------- global pooling (mean+max per batch) ----------------
__global__ void k_pool(const float* __restrict__ lat, const int* __restrict__ starts,
                       float* __restrict__ gl) {
  int b = blockIdx.x;
  int t = threadIdx.x;
  int lane = t & 63, sub = t >> 6;
  int s = starts[b], e = starts[b + 1];
  float sum = 0.f, mx = -3.4e38f;
  for (int i = s + sub; i < e; i += 4) {
    float v = lat[(size_t)i * 64 + lane];
    sum += v;
    mx = fmaxf(mx, v);
  }
  __shared__ float ls[4][64], lm[4][64];
  ls[sub][lane] = sum;
  lm[sub][lane] = mx;
  __syncthreads();
  if (sub == 0) {
#pragma unroll
    for (int j = 1; j < 4; j++) {
      sum += ls[j][lane];
      mx = fmaxf(mx, lm[j][lane]);
    }
    int cnt = e - s;
    float mean = sum / fmaxf((float)cnt, 1.0f);
    gl[b * 128 + lane] = mean;
    gl[b * 128 + 64 + lane] = mx;
  }
}

// ---------------- ctx = gelu(gl @ W1 + b1) @ W2 + b2, per batch ----------------
__global__ void k_ctx(const float* __restrict__ gl, const float* __restrict__ W1,
                      const float* __restrict__ b1, const float* __restrict__ W2,
                      const float* __restrict__ b2, float* __restrict__ ctx) {
  int b = blockIdx.x;
  int j = threadIdx.x;  // 64 threads
  __shared__ float g[128], tt[64];
  g[j] = gl[b * 128 + j];
  g[64 + j] = gl[b * 128 + 64 + j];
  __syncthreads();
  float acc = b1[j];
  for (int k = 0; k < 128; k++) acc += g[k] * W1[k * 64 + j];
  tt[j] = gelu_t(acc);
  __syncthreads();
  float acc2 = b2[j];
  for (int k = 0; k < 64; k++) acc2 += tt[k] * W2[k * 64 + j];
  ctx[b * 64 + j] = acc2;
}

__global__ void k_add_ctx(float* __restrict__ h, const float* __restrict__ ctx,
                          const int* __restrict__ batch, int n) {
  int idx = blockIdx.x * blockDim.x + threadIdx.x;
  if (idx >= n * 64) return;
  int i = idx >> 6, d = idx & 63;
  h[idx] += ctx[batch[i] * 64 + d];
}

// ---------------- decoder stage 2: out = tD @ W2 + b2 ([64,2]) ----------------
__global__ void k_dec2(const float* __restrict__ tD, const float* __restrict__ W2,
                       const float* __restrict__ b2, float* __restrict__ out, int n) {
  int idx = blockIdx.x * blockDim.x + threadIdx.x;
  if (idx >= n * 2) return;
  int i = idx >> 1, j = idx & 1;
  float acc = b2[j];
#pragma unroll 8
  for (int k = 0; k < 64; k++) acc += tD[(size_t)i * 64 + k] * W2[k * 2 + j];
  out[idx] = acc;
}

// ---------------- host ----------------
extern "C" void kernel_launch(void* const* d_in, const int* in_sizes, int n_in,
                              void* d_out, int out_size, void* d_ws, size_t ws_size,
                              hipStream_t stream) {
  const float* x = (const float*)d_in[0];
  const int* ei = (const int*)d_in[1];
  const int* batch = (const int*)d_in[2];
  const float* enc_W = (const float*)d_in[3];
  const float* enc_b = (const float*)d_in[4];
  const float* gat_Wl = (const float*)d_in[5];
  const float* gat_Wr = (const float*)d_in[6];
  const float* gat_att = (const float*)d_in[7];
  const float* gat_b = (const float*)d_in[8];
  const float* ln_g = (const float*)d_in[9];
  const float* ln_b = (const float*)d_in[10];
  const float* ffn_W1 = (const float*)d_in[11];
  const float* ffn_b1 = (const float*)d_in[12];
  const float* ffn_W2 = (const float*)d_in[13];
  const float* ffn_b2 = (const float*)d_in[14];
  const float* n2g_W1 = (const float*)d_in[15];
  const float* n2g_b1 = (const float*)d_in[16];
  const float* n2g_W2 = (const float*)d_in[17];
  const float* n2g_b2 = (const float*)d_in[18];
  const float* g2n_W1 = (const float*)d_in[19];
  const float* g2n_b1 = (const float*)d_in[20];
  const float* g2n_W2 = (const float*)d_in[21];
  const float* g2n_b2 = (const float*)d_in[22];
  const float* dec_W1 = (const float*)d_in[23];
  const float* dec_b1 = (const float*)d_in[24];
  const float* dec_W2 = (const float*)d_in[25];
  const float* dec_b2 = (const float*)d_in[26];

  const int N = NN, E = EE;
  const int* e_src = ei;
  const int* e_dst = ei + E;

  // workspace carve
  float* h = (float*)d_ws;                 // N*64
  float* h2 = h + (size_t)N * 64;          // N*64
  float* xl = h2 + (size_t)N * 64;         // N*256
  float* xr = xl + (size_t)N * 256;        // N*256
  float* t1 = xr + (size_t)N * 256;        // N*128 (tmpA = t1, lat = t1 + N*64)
  float* gl = t1 + (size_t)N * 128;        // B*128
  float* ctx = gl + BBATCH * 128;          // B*64
  int* cnt = (int*)(ctx + BBATCH * 64);    // N (reused as nxt)
  int* indptr = cnt + N;                   // N+1
  int* esrc = indptr + N + 1;              // E+N
  int* bsum = esrc + (E + N);              // scan chunks
  int* starts = bsum + 64;                 // B+1
  float* tmpA = t1;
  float* lat = t1 + (size_t)N * 64;

  const int TPB = 256;
  const int NBLK_SCAN = (N + 1 + 1023) / 1024;  // 49

  // ---- CSR build ----
  hipLaunchKernelGGL(k_init_cnt, dim3((N + TPB - 1) / TPB), dim3(TPB), 0, stream, cnt, N);
  hipLaunchKernelGGL(k_count_edges, dim3((E + TPB - 1) / TPB), dim3(TPB), 0, stream, e_dst, E, cnt);
  hipLaunchKernelGGL(k_scan_bsum, dim3(NBLK_SCAN), dim3(256), 0, stream, cnt, N, bsum);
  hipLaunchKernelGGL(k_scan_offsets, dim3(1), dim3(64), 0, stream, bsum, NBLK_SCAN);
  hipLaunchKernelGGL(k_scan_final, dim3(NBLK_SCAN), dim3(256), 0, stream, cnt, N, bsum, indptr);
  hipLaunchKernelGGL(k_csr_self, dim3((N + TPB - 1) / TPB), dim3(TPB), 0, stream, indptr, cnt, esrc, N);
  hipLaunchKernelGGL(k_csr_fill, dim3((E + TPB - 1) / TPB), dim3(TPB), 0, stream, e_src, e_dst, E, cnt, esrc);
  hipLaunchKernelGGL(k_batch_starts, dim3((N + TPB - 1) / TPB), dim3(TPB), 0, stream, batch, N, BBATCH, starts);

  // ---- encoder ----
  hipLaunchKernelGGL(k_encoder, dim3((N * 64 + TPB - 1) / TPB), dim3(TPB), 0, stream,
                     x, enc_W, enc_b, h, N);

  const int GN = (N + 63) / 64;  // 782

  for (int l = 0; l < NLAYER; l++) {
    const float* Wl = gat_Wl + (size_t)l * 64 * 256;
    const float* Wr = gat_Wr + (size_t)l * 64 * 256;
    const float* attl = gat_att + (size_t)l * 256;
    const float* gbl = gat_b + (size_t)l * 64;
    const float* lngl = ln_g + (size_t)l * 64;
    const float* lnbl = ln_b + (size_t)l * 64;
    const float* fW1 = ffn_W1 + (size_t)l * 64 * 128;
    const float* fb1 = ffn_b1 + (size_t)l * 128;
    const float* fW2 = ffn_W2 + (size_t)l * 128 * 64;
    const float* fb2 = ffn_b2 + (size_t)l * 64;
    const float* nW1 = n2g_W1 + (size_t)l * 64 * 64;
    const float* nb1 = n2g_b1 + (size_t)l * 64;
    const float* nW2 = n2g_W2 + (size_t)l * 64 * 64;
    const float* nb2 = n2g_b2 + (size_t)l * 64;
    const float* gW1 = g2n_W1 + (size_t)l * 128 * 64;
    const float* gb1 = g2n_b1 + (size_t)l * 64;
    const float* gW2 = g2n_W2 + (size_t)l * 64 * 64;
    const float* gb2 = g2n_b2 + (size_t)l * 64;

    // xl = h @ Wl ; xr = h @ Wr  (no bias)
    hipLaunchKernelGGL((k_gemm<64, 0, false>), dim3(GN, 4), dim3(256), 0, stream,
                       h, Wl, (const float*)nullptr, (const float*)nullptr, xl, N, 256);
    hipLaunchKernelGGL((k_gemm<64, 0, false>), dim3(GN, 4), dim3(256), 0, stream,
                       h, Wr, (const float*)nullptr, (const float*)nullptr, xr, N, 256);
    // GAT aggregate + residual + LN -> h2
    hipLaunchKernelGGL(k_gat, dim3((N + 3) / 4), dim3(256), 0, stream,
                       xl, xr, attl, gbl, lngl, lnbl, h, indptr, esrc, h2, N);
    // FFN
    hipLaunchKernelGGL((k_gemm<64, 1, false>), dim3(GN, 2), dim3(256), 0, stream,
                       h2, fW1, fb1, (const float*)nullptr, t1, N, 128);
    hipLaunchKernelGGL((k_gemm<128, 0, true>), dim3(GN, 1), dim3(256), 0, stream,
                       t1, fW2, fb2, h2, h, N, 64);
    // global context: lat = gelu(h@nW1+nb1)@nW2+nb2
    hipLaunchKernelGGL((k_gemm<64, 2, false>), dim3(GN, 1), dim3(256), 0, stream,
                       h, nW1, nb1, (const float*)nullptr, tmpA, N, 64);
    hipLaunchKernelGGL((k_gemm<64, 0, false>), dim3(GN, 1), dim3(256), 0, stream,
                       tmpA, nW2, nb2, (const float*)nullptr, lat, N, 64);
    hipLaunchKernelGGL(k_pool, dim3(BBATCH), dim3(256), 0, stream, lat, starts, gl);
    hipLaunchKernelGGL(k_ctx, dim3(BBATCH), dim3(64), 0, stream, gl, gW1, gb1, gW2, gb2, ctx);
    hipLaunchKernelGGL(k_add_ctx, dim3((N * 64 + TPB - 1) / TPB), dim3(TPB), 0, stream,
                       h, ctx, batch, N);
  }

  // decoder
  hipLaunchKernelGGL((k_gemm<64, 2, false>), dim3(GN, 1), dim3(256), 0, stream,
                     h, dec_W1, dec_b1, (const float*)nullptr, tmpA, N, 64);
  hipLaunchKernelGGL(k_dec2, dim3((N * 2 + TPB - 1) / TPB), dim3(TPB), 0, stream,
                     tmpA, dec_W2, dec_b2, (float*)d_out, N);
}

// Round 3
// 1352.010 us; speedup vs baseline: 1.5792x; 1.3117x over previous
//
#include <hip/hip_runtime.h>
#include <hip/hip_bf16.h>
#include <math.h>

#define NN 50000
#define EE 800000
#define BBATCH 64
#define DDIM 64
#define NLAYER 4
#define NIN 7
#define NHEAD 4

typedef __attribute__((ext_vector_type(8))) short short8v;   // 8 bf16 (4 VGPRs)
typedef __attribute__((ext_vector_type(4))) float f32x4;     // mfma acc

// ---------------- device helpers ----------------
static __device__ __forceinline__ float wave_sum(float v) {
#pragma unroll
  for (int m = 32; m > 0; m >>= 1) v += __shfl_xor(v, m, 64);
  return v;
}

static __device__ __forceinline__ float gelu_t(float x) {
  float z = 0.7978845608f * (x + 0.044715f * x * x * x);
  float t = 2.f / (1.f + __expf(-2.f * z)) - 1.f;
  return 0.5f * x * (1.f + t);
}

static __device__ __forceinline__ unsigned short f2b(float v) {
  __hip_bfloat16 b = __float2bfloat16(v);
  return *reinterpret_cast<unsigned short*>(&b);
}

// ---------------- CSR build ----------------
__global__ void k_init_cnt(int* cnt, int n) {
  int i = blockIdx.x * blockDim.x + threadIdx.x;
  if (i < n) cnt[i] = 1;  // self loop
}

__global__ void k_count_edges(const int* __restrict__ dst, int e, int* cnt) {
  int i = blockIdx.x * blockDim.x + threadIdx.x;
  if (i < e) atomicAdd(&cnt[dst[i]], 1);
}

__global__ void k_scan_bsum(const int* __restrict__ cnt, int n, int* bsum) {
  __shared__ int red[256];
  int b = blockIdx.x, t = threadIdx.x;
  int s = 0;
  for (int i = b * 1024 + t; i < (b + 1) * 1024; i += 256)
    if (i < n) s += cnt[i];
  red[t] = s;
  __syncthreads();
  for (int o = 128; o > 0; o >>= 1) {
    if (t < o) red[t] += red[t + o];
    __syncthreads();
  }
  if (t == 0) bsum[b] = red[0];
}

__global__ void k_scan_offsets(int* bsum, int nb) {
  if (threadIdx.x == 0 && blockIdx.x == 0) {
    int acc = 0;
    for (int i = 0; i < nb; i++) { int v = bsum[i]; bsum[i] = acc; acc += v; }
  }
}

__global__ void k_scan_final(const int* __restrict__ cnt, int n,
                             const int* __restrict__ bsum, int* indptr) {
  __shared__ int lds[256];
  int b = blockIdx.x, t = threadIdx.x;
  int base = b * 1024;
  int v[4];
  int s = 0;
#pragma unroll
  for (int j = 0; j < 4; j++) {
    int i = base + t * 4 + j;
    v[j] = (i < n) ? cnt[i] : 0;
    s += v[j];
  }
  lds[t] = s;
  __syncthreads();
  for (int o = 1; o < 256; o <<= 1) {
    int x = (t >= o) ? lds[t - o] : 0;
    __syncthreads();
    lds[t] += x;
    __syncthreads();
  }
  int run = bsum[b] + lds[t] - s;
#pragma unroll
  for (int j = 0; j < 4; j++) {
    int i = base + t * 4 + j;
    if (i <= n) indptr[i] = run;
    run += v[j];
  }
}

__global__ void k_csr_self(const int* __restrict__ indptr, int* nxt, int* esrc, int n) {
  int i = blockIdx.x * blockDim.x + threadIdx.x;
  if (i < n) {
    int p = indptr[i];
    esrc[p] = i;
    nxt[i] = p + 1;
  }
}

__global__ void k_csr_fill(const int* __restrict__ src, const int* __restrict__ dst,
                           int e, int* nxt, int* esrc) {
  int i = blockIdx.x * blockDim.x + threadIdx.x;
  if (i < e) {
    int p = atomicAdd(&nxt[dst[i]], 1);
    esrc[p] = src[i];
  }
}

// ---------------- batch segment starts (batch is sorted) ----------------
__global__ void k_batch_starts(const int* __restrict__ batch, int n, int nb, int* starts) {
  int i = blockIdx.x * blockDim.x + threadIdx.x;
  if (i >= n) return;
  int b = batch[i];
  if (i == 0) {
    for (int x = 0; x <= b; x++) starts[x] = 0;
  } else {
    int pb = batch[i - 1];
    if (pb != b)
      for (int x = pb + 1; x <= b; x++) starts[x] = i;
  }
  if (i == n - 1) {
    for (int x = b + 1; x <= nb; x++) starts[x] = n;
  }
}

// ---------------- weight prep: W[l][K][Co] fp32 -> Wt[l][Co][K] bf16 ----------------
template <int K, int Co>
__global__ void k_wprep(const float* __restrict__ W, unsigned short* __restrict__ Wt, int L) {
  int idx = blockIdx.x * blockDim.x + threadIdx.x;
  if (idx >= L * K * Co) return;
  int l = idx / (K * Co), rem = idx % (K * Co);
  int k = rem / Co, c = rem % Co;
  Wt[(size_t)l * K * Co + (size_t)c * K + k] = f2b(W[idx]);
}

// ---------------- encoder (also emits bf16 shadow) ----------------
__global__ void k_encoder(const float* __restrict__ x, const float* __restrict__ W,
                          const float* __restrict__ bias, float* __restrict__ h,
                          unsigned short* __restrict__ hb, int n) {
  int idx = blockIdx.x * blockDim.x + threadIdx.x;
  if (idx >= n * 64) return;
  int i = idx >> 6, d = idx & 63;
  float acc = bias[d];
#pragma unroll
  for (int k = 0; k < NIN; k++) acc += x[i * NIN + k] * W[k * 64 + d];
  h[idx] = acc;
  hb[idx] = f2b(acc);
}

// ---------------- MFMA bf16 GEMM: C = act(A[n,K]bf16 @ W[K,Co]bf16 + bias) (+res) ------
// Wt is W transposed: [Co][K] bf16. Block: 256 thr = 4 waves; 64 rows x 64 cols / block.
// Wave w: rows row0+16w .. +15. Frag layout (m89-verified):
//   A: row=lane&15, k=(lane>>4)*8+j ; B: k=(lane>>4)*8+j, col=lane&15
//   D: col=lane&15, row=(lane>>4)*4+reg
template <int K, int ACT, bool RES, bool BIAS, bool OUTF, bool OUTB>
__global__ __launch_bounds__(256) void k_mgemm(const unsigned short* __restrict__ A,
                                               const unsigned short* __restrict__ Wt,
                                               const float* __restrict__ bias,
                                               const float* __restrict__ res,
                                               float* __restrict__ C,
                                               unsigned short* __restrict__ Cb,
                                               int n, int Co) {
  constexpr int NF = K / 32;
  const int lane = threadIdx.x & 63, wave = threadIdx.x >> 6;
  const int row0 = blockIdx.x * 64 + wave * 16;
  const int c0 = blockIdx.y * 64;
  const int karow = (lane >> 4) * 8;
  const int arow = row0 + (lane & 15);
  const size_t abase = (size_t)(arow < n ? arow : 0) * K + karow;

  short8v a[NF];
#pragma unroll
  for (int f = 0; f < NF; f++)
    a[f] = *(const short8v*)(A + abase + f * 32);

  f32x4 acc[4];
#pragma unroll
  for (int cc = 0; cc < 4; cc++) {
    const int c = c0 + cc * 16 + (lane & 15);
    f32x4 t = {0.f, 0.f, 0.f, 0.f};
#pragma unroll
    for (int f = 0; f < NF; f++) {
      short8v b = *(const short8v*)(Wt + (size_t)c * K + f * 32 + karow);
      t = __builtin_amdgcn_mfma_f32_16x16x32_bf16(a[f], b, t, 0, 0, 0);
    }
    acc[cc] = t;
  }

#pragma unroll
  for (int cc = 0; cc < 4; cc++) {
    const int c = c0 + cc * 16 + (lane & 15);
    const float bv = BIAS ? bias[c] : 0.f;
#pragma unroll
    for (int r = 0; r < 4; r++) {
      const int row = row0 + (lane >> 4) * 4 + r;
      if (row < n) {
        float v = acc[cc][r] + bv;
        if (ACT == 1) v = fmaxf(v, 0.2f * v);
        else if (ACT == 2) v = gelu_t(v);
        if (RES) v += res[(size_t)row * Co + c];
        if (OUTF) C[(size_t)row * Co + c] = v;
        if (OUTB) Cb[(size_t)row * Co + c] = f2b(v);
      }
    }
  }
}

// ---------------- GATv2 aggregation + residual + LayerNorm (fused) ----------------
__global__ __launch_bounds__(256) void k_gat(const float* __restrict__ xl,
                                             const float* __restrict__ xr,
                                             const float* __restrict__ att,
                                             const float* __restrict__ gbias,
                                             const float* __restrict__ lng,
                                             const float* __restrict__ lnb,
                                             const float* __restrict__ h,
                                             const int* __restrict__ indptr,
                                             const int* __restrict__ esrc,
                                             float* __restrict__ h2,
                                             unsigned short* __restrict__ h2b, int n) {
  const int wave = threadIdx.x >> 6, lane = threadIdx.x & 63;
  const int node = blockIdx.x * 4 + wave;
  if (node >= n) return;
  const int q = lane >> 4, r = lane & 15;

  float4 xr_d[4], att_d[4];
  const float* xrp = xr + (size_t)node * 256 + 4 * r;
#pragma unroll
  for (int hh = 0; hh < 4; hh++) {
    xr_d[hh] = *(const float4*)(xrp + hh * 64);
    att_d[hh] = *(const float4*)(att + hh * 64 + 4 * r);
  }

  float acc[4][4] = {};
  float den[4] = {0.f, 0.f, 0.f, 0.f};
  float m[4] = {-1e30f, -1e30f, -1e30f, -1e30f};

  const int beg = indptr[node], end = indptr[node + 1];
  for (int jb = beg; jb < end; jb += 4) {
    const int j = jb + q;
    const bool valid = j < end;
    const int s = valid ? esrc[j] : 0;
    const float* xp = xl + (size_t)s * 256 + 4 * r;
    float4 xs[4];
#pragma unroll
    for (int hh = 0; hh < 4; hh++) xs[hh] = *(const float4*)(xp + hh * 64);

    float p[4];
#pragma unroll
    for (int hh = 0; hh < 4; hh++) {
      float t0 = xs[hh].x + xr_d[hh].x; t0 = fmaxf(t0, 0.2f * t0);
      float t1 = xs[hh].y + xr_d[hh].y; t1 = fmaxf(t1, 0.2f * t1);
      float t2 = xs[hh].z + xr_d[hh].z; t2 = fmaxf(t2, 0.2f * t2);
      float t3 = xs[hh].w + xr_d[hh].w; t3 = fmaxf(t3, 0.2f * t3);
      p[hh] = t0 * att_d[hh].x + t1 * att_d[hh].y + t2 * att_d[hh].z + t3 * att_d[hh].w;
    }
#pragma unroll
    for (int msk = 1; msk < 16; msk <<= 1) {
#pragma unroll
      for (int hh = 0; hh < 4; hh++) p[hh] += __shfl_xor(p[hh], msk, 64);
    }
#pragma unroll
    for (int hh = 0; hh < 4; hh++) {
      const float e = valid ? p[hh] : -1e30f;
      const float nm = fmaxf(m[hh], e);
      const float so = __expf(m[hh] - nm);
      const float pw = __expf(e - nm);
      den[hh] = den[hh] * so + pw;
      m[hh] = nm;
      const float* xsf = (const float*)&xs[hh];
#pragma unroll
      for (int j4 = 0; j4 < 4; j4++) acc[hh][j4] = acc[hh][j4] * so + pw * xsf[j4];
    }
  }

#pragma unroll
  for (int msk = 16; msk < 64; msk <<= 1) {
#pragma unroll
    for (int hh = 0; hh < 4; hh++) {
      const float mo = __shfl_xor(m[hh], msk, 64);
      const float deno = __shfl_xor(den[hh], msk, 64);
      float ao[4];
#pragma unroll
      for (int j4 = 0; j4 < 4; j4++) ao[j4] = __shfl_xor(acc[hh][j4], msk, 64);
      const float M = fmaxf(m[hh], mo);
      const float sA = __expf(m[hh] - M);
      const float sB = __expf(mo - M);
      den[hh] = den[hh] * sA + deno * sB;
#pragma unroll
      for (int j4 = 0; j4 < 4; j4++) acc[hh][j4] = acc[hh][j4] * sA + ao[j4] * sB;
      m[hh] = M;
    }
  }

  float rden[4];
#pragma unroll
  for (int hh = 0; hh < 4; hh++) rden[hh] = 1.f / (den[hh] + 1e-16f);
  const float4 hv = *(const float4*)(h + (size_t)node * 64 + 4 * r);
  const float4 gb = *(const float4*)(gbias + 4 * r);
  const float* hvf = (const float*)&hv;
  const float* gbf = (const float*)&gb;
  float y[4];
  float s4 = 0.f;
#pragma unroll
  for (int j4 = 0; j4 < 4; j4++) {
    const float o = 0.25f * (acc[0][j4] * rden[0] + acc[1][j4] * rden[1] +
                             acc[2][j4] * rden[2] + acc[3][j4] * rden[3]) + gbf[j4];
    y[j4] = hvf[j4] + o;
    s4 += y[j4];
  }
  const float mu = wave_sum(s4) * (1.f / 256.f);
  float v4 = 0.f;
  float dv[4];
#pragma unroll
  for (int j4 = 0; j4 < 4; j4++) {
    dv[j4] = y[j4] - mu;
    v4 += dv[j4] * dv[j4];
  }
  const float var = wave_sum(v4) * (1.f / 256.f);
  const float rstd = rsqrtf(var + 1e-5f);
  if (q == 0) {
    const float4 gv = *(const float4*)(lng + 4 * r);
    const float4 bv = *(const float4*)(lnb + 4 * r);
    const float* gvf = (const float*)&gv;
    const float* bvf = (const float*)&bv;
    float outv[4];
    ushort4 ob;
#pragma unroll
    for (int j4 = 0; j4 < 4; j4++) outv[j4] = dv[j4] * rstd * gvf[j4] + bvf[j4];
    *(float4*)(h2 + (size_t)node * 64 + 4 * r) = *(float4*)outv;
    ob.x = f2b(outv[0]); ob.y = f2b(outv[1]); ob.z = f2b(outv[2]); ob.w = f2b(outv[3]);
    *(ushort4*)(h2b + (size_t)node * 64 + 4 * r) = ob;
  }
}

// ---------------- global pooling (mean+max per batch) ----------------
__global__ void k_pool(const float* __restrict__ lat, const int* __restrict__ starts,
                       float* __restrict__ gl) {
  int b = blockIdx.x;
  int t = threadIdx.x;
  int lane = t & 63, sub = t >> 6;
  int s = starts[b], e = starts[b + 1];
  float sum = 0.f, mx = -3.4e38f;
  for (int i = s + sub; i < e; i += 4) {
    float v = lat[(size_t)i * 64 + lane];
    sum += v;
    mx = fmaxf(mx, v);
  }
  __shared__ float ls[4][64], lm[4][64];
  ls[sub][lane] = sum;
  lm[sub][lane] = mx;
  __syncthreads();
  if (sub == 0) {
#pragma unroll
    for (int j = 1; j < 4; j++) {
      sum += ls[j][lane];
      mx = fmaxf(mx, lm[j][lane]);
    }
    int cnt = e - s;
    float mean = sum / fmaxf((float)cnt, 1.0f);
    gl[b * 128 + lane] = mean;
    gl[b * 128 + 64 + lane] = mx;
  }
}

// ---------------- ctx = gelu(gl @ W1 + b1) @ W2 + b2, per batch ----------------
__global__ void k_ctx(const float* __restrict__ gl, const float* __restrict__ W1,
                      const float* __restrict__ b1, const float* __restrict__ W2,
                      const float* __restrict__ b2, float* __restrict__ ctx) {
  int b = blockIdx.x;
  int j = threadIdx.x;
  __shared__ float g[128], tt[64];
  g[j] = gl[b * 128 + j];
  g[64 + j] = gl[b * 128 + 64 + j];
  __syncthreads();
  float acc = b1[j];
  for (int k = 0; k < 128; k++) acc += g[k] * W1[k * 64 + j];
  tt[j] = gelu_t(acc);
  __syncthreads();
  float acc2 = b2[j];
  for (int k = 0; k < 64; k++) acc2 += tt[k] * W2[k * 64 + j];
  ctx[b * 64 + j] = acc2;
}

__global__ void k_add_ctx(float* __restrict__ h, unsigned short* __restrict__ hb,
                          const float* __restrict__ ctx,
                          const int* __restrict__ batch, int n) {
  int idx = blockIdx.x * blockDim.x + threadIdx.x;
  if (idx >= n * 64) return;
  int i = idx >> 6, d = idx & 63;
  float v = h[idx] + ctx[batch[i] * 64 + d];
  h[idx] = v;
  hb[idx] = f2b(v);
}

// ---------------- decoder stage 2: out = tD @ W2 + b2 ([64,2]) ----------------
__global__ void k_dec2(const float* __restrict__ tD, const float* __restrict__ W2,
                       const float* __restrict__ b2, float* __restrict__ out, int n) {
  int idx = blockIdx.x * blockDim.x + threadIdx.x;
  if (idx >= n * 2) return;
  int i = idx >> 1, j = idx & 1;
  float acc = b2[j];
#pragma unroll 8
  for (int k = 0; k < 64; k++) acc += tD[(size_t)i * 64 + k] * W2[k * 2 + j];
  out[idx] = acc;
}

// ---------------- host ----------------
extern "C" void kernel_launch(void* const* d_in, const int* in_sizes, int n_in,
                              void* d_out, int out_size, void* d_ws, size_t ws_size,
                              hipStream_t stream) {
  const float* x = (const float*)d_in[0];
  const int* ei = (const int*)d_in[1];
  const int* batch = (const int*)d_in[2];
  const float* enc_W = (const float*)d_in[3];
  const float* enc_b = (const float*)d_in[4];
  const float* gat_Wl = (const float*)d_in[5];
  const float* gat_Wr = (const float*)d_in[6];
  const float* gat_att = (const float*)d_in[7];
  const float* gat_b = (const float*)d_in[8];
  const float* ln_g = (const float*)d_in[9];
  const float* ln_b = (const float*)d_in[10];
  const float* ffn_W1 = (const float*)d_in[11];
  const float* ffn_b1 = (const float*)d_in[12];
  const float* ffn_W2 = (const float*)d_in[13];
  const float* ffn_b2 = (const float*)d_in[14];
  const float* n2g_W1 = (const float*)d_in[15];
  const float* n2g_b1 = (const float*)d_in[16];
  const float* n2g_W2 = (const float*)d_in[17];
  const float* n2g_b2 = (const float*)d_in[18];
  const float* g2n_W1 = (const float*)d_in[19];
  const float* g2n_b1 = (const float*)d_in[20];
  const float* g2n_W2 = (const float*)d_in[21];
  const float* g2n_b2 = (const float*)d_in[22];
  const float* dec_W1 = (const float*)d_in[23];
  const float* dec_b1 = (const float*)d_in[24];
  const float* dec_W2 = (const float*)d_in[25];
  const float* dec_b2 = (const float*)d_in[26];

  const int N = NN, E = EE;
  const int* e_src = ei;
  const int* e_dst = ei + E;

  // ---- workspace carve (fp32 region, then int region, then bf16 region) ----
  float* h = (float*)d_ws;                 // N*64
  float* h2 = h + (size_t)N * 64;          // N*64
  float* xl = h2 + (size_t)N * 64;         // N*256
  float* xr = xl + (size_t)N * 256;        // N*256
  float* t1 = xr + (size_t)N * 256;        // N*128  (tmpA = t1, lat = t1 + N*64)
  float* gl = t1 + (size_t)N * 128;        // B*128
  float* ctx = gl + BBATCH * 128;          // B*64
  int* cnt = (int*)(ctx + BBATCH * 64);    // N
  int* indptr = cnt + N;                   // N+1
  int* esrc = indptr + N + 1;              // E+N
  int* bsum = esrc + (E + N);              // 64
  int* starts = bsum + 64;                 // B+1 (=65)
  // bf16 region, 16B-aligned
  size_t off = (size_t)(starts + BBATCH + 1) - (size_t)d_ws;
  off = (off + 15) & ~(size_t)15;
  unsigned short* hb = (unsigned short*)((char*)d_ws + off);   // N*64
  unsigned short* h2b = hb + (size_t)N * 64;                   // N*64
  unsigned short* tb = h2b + (size_t)N * 64;                   // N*128 (t1_bf / tmpA_bf shared)
  unsigned short* wWl = tb + (size_t)N * 128;                  // 4*256*64
  unsigned short* wWr = wWl + 4 * 256 * 64;
  unsigned short* wF1 = wWr + 4 * 256 * 64;                    // 4*128*64 ([Co=128][K=64])
  unsigned short* wF2 = wF1 + 4 * 128 * 64;                    // 4*64*128 ([Co=64][K=128])
  unsigned short* wN1 = wF2 + 4 * 64 * 128;                    // 4*64*64
  unsigned short* wN2 = wN1 + 4 * 64 * 64;
  unsigned short* wD1 = wN2 + 4 * 64 * 64;                     // 64*64

  float* tmpA = t1;
  float* lat = t1 + (size_t)N * 64;

  const int TPB = 256;
  const int NBLK_SCAN = (N + 1 + 1023) / 1024;

  // ---- weight prep (bf16 transposed) ----
  hipLaunchKernelGGL((k_wprep<64, 256>), dim3((4 * 64 * 256 + 255) / 256), dim3(256), 0, stream, gat_Wl, wWl, 4);
  hipLaunchKernelGGL((k_wprep<64, 256>), dim3((4 * 64 * 256 + 255) / 256), dim3(256), 0, stream, gat_Wr, wWr, 4);
  hipLaunchKernelGGL((k_wprep<64, 128>), dim3((4 * 64 * 128 + 255) / 256), dim3(256), 0, stream, ffn_W1, wF1, 4);
  hipLaunchKernelGGL((k_wprep<128, 64>), dim3((4 * 128 * 64 + 255) / 256), dim3(256), 0, stream, ffn_W2, wF2, 4);
  hipLaunchKernelGGL((k_wprep<64, 64>), dim3((4 * 64 * 64 + 255) / 256), dim3(256), 0, stream, n2g_W1, wN1, 4);
  hipLaunchKernelGGL((k_wprep<64, 64>), dim3((4 * 64 * 64 + 255) / 256), dim3(256), 0, stream, n2g_W2, wN2, 4);
  hipLaunchKernelGGL((k_wprep<64, 64>), dim3((64 * 64 + 255) / 256), dim3(256), 0, stream, dec_W1, wD1, 1);

  // ---- CSR build ----
  hipLaunchKernelGGL(k_init_cnt, dim3((N + TPB - 1) / TPB), dim3(TPB), 0, stream, cnt, N);
  hipLaunchKernelGGL(k_count_edges, dim3((E + TPB - 1) / TPB), dim3(TPB), 0, stream, e_dst, E, cnt);
  hipLaunchKernelGGL(k_scan_bsum, dim3(NBLK_SCAN), dim3(256), 0, stream, cnt, N, bsum);
  hipLaunchKernelGGL(k_scan_offsets, dim3(1), dim3(64), 0, stream, bsum, NBLK_SCAN);
  hipLaunchKernelGGL(k_scan_final, dim3(NBLK_SCAN), dim3(256), 0, stream, cnt, N, bsum, indptr);
  hipLaunchKernelGGL(k_csr_self, dim3((N + TPB - 1) / TPB), dim3(TPB), 0, stream, indptr, cnt, esrc, N);
  hipLaunchKernelGGL(k_csr_fill, dim3((E + TPB - 1) / TPB), dim3(TPB), 0, stream, e_src, e_dst, E, cnt, esrc);
  hipLaunchKernelGGL(k_batch_starts, dim3((N + TPB - 1) / TPB), dim3(TPB), 0, stream, batch, N, BBATCH, starts);

  // ---- encoder ----
  hipLaunchKernelGGL(k_encoder, dim3((N * 64 + TPB - 1) / TPB), dim3(TPB), 0, stream,
                     x, enc_W, enc_b, h, hb, N);

  const int GN = (N + 63) / 64;  // 782

  for (int l = 0; l < NLAYER; l++) {
    const unsigned short* Wlt = wWl + (size_t)l * 256 * 64;
    const unsigned short* Wrt = wWr + (size_t)l * 256 * 64;
    const unsigned short* F1t = wF1 + (size_t)l * 128 * 64;
    const unsigned short* F2t = wF2 + (size_t)l * 64 * 128;
    const unsigned short* N1t = wN1 + (size_t)l * 64 * 64;
    const unsigned short* N2t = wN2 + (size_t)l * 64 * 64;
    const float* attl = gat_att + (size_t)l * 256;
    const float* gbl = gat_b + (size_t)l * 64;
    const float* lngl = ln_g + (size_t)l * 64;
    const float* lnbl = ln_b + (size_t)l * 64;
    const float* fb1 = ffn_b1 + (size_t)l * 128;
    const float* fb2 = ffn_b2 + (size_t)l * 64;
    const float* nb1 = n2g_b1 + (size_t)l * 64;
    const float* nb2 = n2g_b2 + (size_t)l * 64;
    const float* gW1 = g2n_W1 + (size_t)l * 128 * 64;
    const float* gb1 = g2n_b1 + (size_t)l * 64;
    const float* gW2 = g2n_W2 + (size_t)l * 64 * 64;
    const float* gb2 = g2n_b2 + (size_t)l * 64;

    // xl = h @ Wl ; xr = h @ Wr  (fp32 out, no bias)
    hipLaunchKernelGGL((k_mgemm<64, 0, false, false, true, false>), dim3(GN, 4), dim3(256), 0, stream,
                       hb, Wlt, nullptr, nullptr, xl, nullptr, N, 256);
    hipLaunchKernelGGL((k_mgemm<64, 0, false, false, true, false>), dim3(GN, 4), dim3(256), 0, stream,
                       hb, Wrt, nullptr, nullptr, xr, nullptr, N, 256);
    // GAT aggregate + residual + LN -> h2 (+bf16)
    hipLaunchKernelGGL(k_gat, dim3((N + 3) / 4), dim3(256), 0, stream,
                       xl, xr, attl, gbl, lngl, lnbl, h, indptr, esrc, h2, h2b, N);
    // FFN1: t1_bf = leaky(h2 @ W1 + b1)  (bf16 only)
    hipLaunchKernelGGL((k_mgemm<64, 1, false, true, false, true>), dim3(GN, 2), dim3(256), 0, stream,
                       h2b, F1t, fb1, nullptr, nullptr, tb, N, 128);
    // FFN2: h = t1 @ W2 + b2 + h2  (fp32 + bf16)
    hipLaunchKernelGGL((k_mgemm<128, 0, true, true, true, true>), dim3(GN, 1), dim3(256), 0, stream,
                       tb, F2t, fb2, h2, h, hb, N, 64);
    // n2g1: tmp_bf = gelu(h @ nW1 + nb1)  (bf16 only)
    hipLaunchKernelGGL((k_mgemm<64, 2, false, true, false, true>), dim3(GN, 1), dim3(256), 0, stream,
                       hb, N1t, nb1, nullptr, nullptr, tb, N, 64);
    // n2g2: lat = tmp @ nW2 + nb2  (fp32)
    hipLaunchKernelGGL((k_mgemm<64, 0, false, true, true, false>), dim3(GN, 1), dim3(256), 0, stream,
                       tb, N2t, nb2, nullptr, lat, nullptr, N, 64);
    hipLaunchKernelGGL(k_pool, dim3(BBATCH), dim3(256), 0, stream, lat, starts, gl);
    hipLaunchKernelGGL(k_ctx, dim3(BBATCH), dim3(64), 0, stream, gl, gW1, gb1, gW2, gb2, ctx);
    hipLaunchKernelGGL(k_add_ctx, dim3((N * 64 + TPB - 1) / TPB), dim3(TPB), 0, stream,
                       h, hb, ctx, batch, N);
  }

  // decoder: tmpA = gelu(h @ dW1 + db1) (fp32), then out = tmpA @ W2 + b2
  hipLaunchKernelGGL((k_mgemm<64, 2, false, true, true, false>), dim3(GN, 1), dim3(256), 0, stream,
                     hb, wD1, dec_b1, nullptr, tmpA, nullptr, N, 64);
  hipLaunchKernelGGL(k_dec2, dim3((N * 2 + TPB - 1) / TPB), dim3(TPB), 0, stream,
                     tmpA, dec_W2, dec_b2, (float*)d_out, N);
}

// Round 4
// 1290.442 us; speedup vs baseline: 1.6546x; 1.0477x over previous
//
#include <hip/hip_runtime.h>
#include <hip/hip_bf16.h>
#include <math.h>

#define NN 50000
#define EE 800000
#define BBATCH 64
#define DDIM 64
#define NLAYER 4
#define NIN 7
#define NHEAD 4

typedef __attribute__((ext_vector_type(8))) short short8v;   // 8 bf16 (4 VGPRs)
typedef __attribute__((ext_vector_type(4))) float f32x4;     // mfma acc

// ---------------- device helpers ----------------
static __device__ __forceinline__ float wave_sum(float v) {
#pragma unroll
  for (int m = 32; m > 0; m >>= 1) v += __shfl_xor(v, m, 64);
  return v;
}

static __device__ __forceinline__ float gelu_t(float x) {
  float z = 0.7978845608f * (x + 0.044715f * x * x * x);
  float t = 2.f / (1.f + __expf(-2.f * z)) - 1.f;
  return 0.5f * x * (1.f + t);
}

static __device__ __forceinline__ unsigned short f2b(float v) {
  __hip_bfloat16 b = __float2bfloat16(v);
  return *reinterpret_cast<unsigned short*>(&b);
}

static __device__ __forceinline__ float b2f(unsigned short u) {
  unsigned int t = (unsigned int)u << 16;
  union { unsigned int i; float f; } c;
  c.i = t;
  return c.f;
}

// ---------------- CSR build ----------------
__global__ void k_init_cnt(int* cnt, int n) {
  int i = blockIdx.x * blockDim.x + threadIdx.x;
  if (i < n) cnt[i] = 1;  // self loop
}

__global__ void k_count_edges(const int* __restrict__ dst, int e, int* cnt) {
  int i = blockIdx.x * blockDim.x + threadIdx.x;
  if (i < e) atomicAdd(&cnt[dst[i]], 1);
}

__global__ void k_scan_bsum(const int* __restrict__ cnt, int n, int* bsum) {
  __shared__ int red[256];
  int b = blockIdx.x, t = threadIdx.x;
  int s = 0;
  for (int i = b * 1024 + t; i < (b + 1) * 1024; i += 256)
    if (i < n) s += cnt[i];
  red[t] = s;
  __syncthreads();
  for (int o = 128; o > 0; o >>= 1) {
    if (t < o) red[t] += red[t + o];
    __syncthreads();
  }
  if (t == 0) bsum[b] = red[0];
}

__global__ void k_scan_offsets(int* bsum, int nb) {
  if (threadIdx.x == 0 && blockIdx.x == 0) {
    int acc = 0;
    for (int i = 0; i < nb; i++) { int v = bsum[i]; bsum[i] = acc; acc += v; }
  }
}

__global__ void k_scan_final(const int* __restrict__ cnt, int n,
                             const int* __restrict__ bsum, int* indptr) {
  __shared__ int lds[256];
  int b = blockIdx.x, t = threadIdx.x;
  int base = b * 1024;
  int v[4];
  int s = 0;
#pragma unroll
  for (int j = 0; j < 4; j++) {
    int i = base + t * 4 + j;
    v[j] = (i < n) ? cnt[i] : 0;
    s += v[j];
  }
  lds[t] = s;
  __syncthreads();
  for (int o = 1; o < 256; o <<= 1) {
    int x = (t >= o) ? lds[t - o] : 0;
    __syncthreads();
    lds[t] += x;
    __syncthreads();
  }
  int run = bsum[b] + lds[t] - s;
#pragma unroll
  for (int j = 0; j < 4; j++) {
    int i = base + t * 4 + j;
    if (i <= n) indptr[i] = run;
    run += v[j];
  }
}

__global__ void k_csr_self(const int* __restrict__ indptr, int* nxt, int* esrc, int n) {
  int i = blockIdx.x * blockDim.x + threadIdx.x;
  if (i < n) {
    int p = indptr[i];
    esrc[p] = i;
    nxt[i] = p + 1;
  }
}

__global__ void k_csr_fill(const int* __restrict__ src, const int* __restrict__ dst,
                           int e, int* nxt, int* esrc) {
  int i = blockIdx.x * blockDim.x + threadIdx.x;
  if (i < e) {
    int p = atomicAdd(&nxt[dst[i]], 1);
    esrc[p] = src[i];
  }
}

// ---------------- batch segment starts (batch is sorted) ----------------
__global__ void k_batch_starts(const int* __restrict__ batch, int n, int nb, int* starts) {
  int i = blockIdx.x * blockDim.x + threadIdx.x;
  if (i >= n) return;
  int b = batch[i];
  if (i == 0) {
    for (int x = 0; x <= b; x++) starts[x] = 0;
  } else {
    int pb = batch[i - 1];
    if (pb != b)
      for (int x = pb + 1; x <= b; x++) starts[x] = i;
  }
  if (i == n - 1) {
    for (int x = b + 1; x <= nb; x++) starts[x] = n;
  }
}

// ---------------- weight prep: W[l][K][Co] fp32 -> Wt[l][Co][K] bf16 ----------------
template <int K, int Co>
__global__ void k_wprep(const float* __restrict__ W, unsigned short* __restrict__ Wt, int L) {
  int idx = blockIdx.x * blockDim.x + threadIdx.x;
  if (idx >= L * K * Co) return;
  int l = idx / (K * Co), rem = idx % (K * Co);
  int k = rem / Co, c = rem % Co;
  Wt[(size_t)l * K * Co + (size_t)c * K + k] = f2b(W[idx]);
}

// combined Wl|Wr prep: out [L][512][64] bf16, c<256 from Wl, else Wr (both [L][64][256])
__global__ void k_wprep_lr(const float* __restrict__ Wl, const float* __restrict__ Wr,
                           unsigned short* __restrict__ Wt, int L) {
  int idx = blockIdx.x * blockDim.x + threadIdx.x;
  if (idx >= L * 512 * 64) return;
  int l = idx / (512 * 64), rem = idx % (512 * 64);
  int c = rem / 64, k = rem % 64;
  float v = (c < 256) ? Wl[(size_t)l * 64 * 256 + k * 256 + c]
                      : Wr[(size_t)l * 64 * 256 + k * 256 + (c - 256)];
  Wt[idx] = f2b(v);
}

// ---------------- encoder (also emits bf16 shadow) ----------------
__global__ void k_encoder(const float* __restrict__ x, const float* __restrict__ W,
                          const float* __restrict__ bias, float* __restrict__ h,
                          unsigned short* __restrict__ hb, int n) {
  int idx = blockIdx.x * blockDim.x + threadIdx.x;
  if (idx >= n * 64) return;
  int i = idx >> 6, d = idx & 63;
  float acc = bias[d];
#pragma unroll
  for (int k = 0; k < NIN; k++) acc += x[i * NIN + k] * W[k * 64 + d];
  h[idx] = acc;
  hb[idx] = f2b(acc);
}

// ---------------- MFMA bf16 GEMM: C = act(A[n,K]bf16 @ W[K,Co]bf16 + bias) (+res) ------
// Wt is W transposed: [Co][K] bf16. Block: 256 thr = 4 waves; 64 rows x 64 cols / block.
template <int K, int ACT, bool RES, bool BIAS, bool OUTF, bool OUTB>
__global__ __launch_bounds__(256) void k_mgemm(const unsigned short* __restrict__ A,
                                               const unsigned short* __restrict__ Wt,
                                               const float* __restrict__ bias,
                                               const float* __restrict__ res,
                                               float* __restrict__ C,
                                               unsigned short* __restrict__ Cb,
                                               int n, int Co) {
  constexpr int NF = K / 32;
  const int lane = threadIdx.x & 63, wave = threadIdx.x >> 6;
  const int row0 = blockIdx.x * 64 + wave * 16;
  const int c0 = blockIdx.y * 64;
  const int karow = (lane >> 4) * 8;
  const int arow = row0 + (lane & 15);
  const size_t abase = (size_t)(arow < n ? arow : 0) * K + karow;

  short8v a[NF];
#pragma unroll
  for (int f = 0; f < NF; f++)
    a[f] = *(const short8v*)(A + abase + f * 32);

  f32x4 acc[4];
#pragma unroll
  for (int cc = 0; cc < 4; cc++) {
    const int c = c0 + cc * 16 + (lane & 15);
    f32x4 t = {0.f, 0.f, 0.f, 0.f};
#pragma unroll
    for (int f = 0; f < NF; f++) {
      short8v b = *(const short8v*)(Wt + (size_t)c * K + f * 32 + karow);
      t = __builtin_amdgcn_mfma_f32_16x16x32_bf16(a[f], b, t, 0, 0, 0);
    }
    acc[cc] = t;
  }

#pragma unroll
  for (int cc = 0; cc < 4; cc++) {
    const int c = c0 + cc * 16 + (lane & 15);
    const float bv = BIAS ? bias[c] : 0.f;
#pragma unroll
    for (int r = 0; r < 4; r++) {
      const int row = row0 + (lane >> 4) * 4 + r;
      if (row < n) {
        float v = acc[cc][r] + bv;
        if (ACT == 1) v = fmaxf(v, 0.2f * v);
        else if (ACT == 2) v = gelu_t(v);
        if (RES) v += res[(size_t)row * Co + c];
        if (OUTF) C[(size_t)row * Co + c] = v;
        if (OUTB) Cb[(size_t)row * Co + c] = f2b(v);
      }
    }
  }
}

// ---------------- GATv2 aggregation + residual + LayerNorm (fused) ----------------
// xlr[N][512] bf16: cols 0..255 = xl (gathered by src), 256..511 = xr (by dst node).
__global__ __launch_bounds__(256) void k_gat(const unsigned short* __restrict__ xlr,
                                             const float* __restrict__ att,
                                             const float* __restrict__ gbias,
                                             const float* __restrict__ lng,
                                             const float* __restrict__ lnb,
                                             const float* __restrict__ h,
                                             const int* __restrict__ indptr,
                                             const int* __restrict__ esrc,
                                             float* __restrict__ h2,
                                             unsigned short* __restrict__ h2b, int n) {
  const int wave = threadIdx.x >> 6, lane = threadIdx.x & 63;
  const int node = blockIdx.x * 4 + wave;
  if (node >= n) return;
  const int q = lane >> 4, r = lane & 15;

  float xr_d[4][4];
  float4 att_d[4];
  const unsigned short* xrp = xlr + (size_t)node * 512 + 256 + 4 * r;
#pragma unroll
  for (int hh = 0; hh < 4; hh++) {
    ushort4 u = *(const ushort4*)(xrp + hh * 64);
    xr_d[hh][0] = b2f(u.x); xr_d[hh][1] = b2f(u.y);
    xr_d[hh][2] = b2f(u.z); xr_d[hh][3] = b2f(u.w);
    att_d[hh] = *(const float4*)(att + hh * 64 + 4 * r);
  }

  float acc[4][4] = {};
  float den[4] = {0.f, 0.f, 0.f, 0.f};
  float m[4] = {-1e30f, -1e30f, -1e30f, -1e30f};

  const int beg = indptr[node], end = indptr[node + 1];
  for (int jb = beg; jb < end; jb += 4) {
    const int j = jb + q;
    const bool valid = j < end;
    const int s = valid ? esrc[j] : 0;
    const unsigned short* xp = xlr + (size_t)s * 512 + 4 * r;
    float xs[4][4];
#pragma unroll
    for (int hh = 0; hh < 4; hh++) {
      ushort4 u = *(const ushort4*)(xp + hh * 64);
      xs[hh][0] = b2f(u.x); xs[hh][1] = b2f(u.y);
      xs[hh][2] = b2f(u.z); xs[hh][3] = b2f(u.w);
    }

    float p[4];
#pragma unroll
    for (int hh = 0; hh < 4; hh++) {
      float t0 = xs[hh][0] + xr_d[hh][0]; t0 = fmaxf(t0, 0.2f * t0);
      float t1 = xs[hh][1] + xr_d[hh][1]; t1 = fmaxf(t1, 0.2f * t1);
      float t2 = xs[hh][2] + xr_d[hh][2]; t2 = fmaxf(t2, 0.2f * t2);
      float t3 = xs[hh][3] + xr_d[hh][3]; t3 = fmaxf(t3, 0.2f * t3);
      p[hh] = t0 * att_d[hh].x + t1 * att_d[hh].y + t2 * att_d[hh].z + t3 * att_d[hh].w;
    }
#pragma unroll
    for (int msk = 1; msk < 16; msk <<= 1) {
#pragma unroll
      for (int hh = 0; hh < 4; hh++) p[hh] += __shfl_xor(p[hh], msk, 64);
    }
#pragma unroll
    for (int hh = 0; hh < 4; hh++) {
      const float e = valid ? p[hh] : -1e30f;
      const float nm = fmaxf(m[hh], e);
      const float so = __expf(m[hh] - nm);
      const float pw = __expf(e - nm);
      den[hh] = den[hh] * so + pw;
      m[hh] = nm;
#pragma unroll
      for (int j4 = 0; j4 < 4; j4++) acc[hh][j4] = acc[hh][j4] * so + pw * xs[hh][j4];
    }
  }

#pragma unroll
  for (int msk = 16; msk < 64; msk <<= 1) {
#pragma unroll
    for (int hh = 0; hh < 4; hh++) {
      const float mo = __shfl_xor(m[hh], msk, 64);
      const float deno = __shfl_xor(den[hh], msk, 64);
      float ao[4];
#pragma unroll
      for (int j4 = 0; j4 < 4; j4++) ao[j4] = __shfl_xor(acc[hh][j4], msk, 64);
      const float M = fmaxf(m[hh], mo);
      const float sA = __expf(m[hh] - M);
      const float sB = __expf(mo - M);
      den[hh] = den[hh] * sA + deno * sB;
#pragma unroll
      for (int j4 = 0; j4 < 4; j4++) acc[hh][j4] = acc[hh][j4] * sA + ao[j4] * sB;
      m[hh] = M;
    }
  }

  float rden[4];
#pragma unroll
  for (int hh = 0; hh < 4; hh++) rden[hh] = 1.f / (den[hh] + 1e-16f);
  const float4 hv = *(const float4*)(h + (size_t)node * 64 + 4 * r);
  const float4 gb = *(const float4*)(gbias + 4 * r);
  const float* hvf = (const float*)&hv;
  const float* gbf = (const float*)&gb;
  float y[4];
  float s4 = 0.f;
#pragma unroll
  for (int j4 = 0; j4 < 4; j4++) {
    const float o = 0.25f * (acc[0][j4] * rden[0] + acc[1][j4] * rden[1] +
                             acc[2][j4] * rden[2] + acc[3][j4] * rden[3]) + gbf[j4];
    y[j4] = hvf[j4] + o;
    s4 += y[j4];
  }
  const float mu = wave_sum(s4) * (1.f / 256.f);
  float v4 = 0.f;
  float dv[4];
#pragma unroll
  for (int j4 = 0; j4 < 4; j4++) {
    dv[j4] = y[j4] - mu;
    v4 += dv[j4] * dv[j4];
  }
  const float var = wave_sum(v4) * (1.f / 256.f);
  const float rstd = rsqrtf(var + 1e-5f);
  if (q == 0) {
    const float4 gv = *(const float4*)(lng + 4 * r);
    const float4 bv = *(const float4*)(lnb + 4 * r);
    const float* gvf = (const float*)&gv;
    const float* bvf = (const float*)&bv;
    float outv[4];
    ushort4 ob;
#pragma unroll
    for (int j4 = 0; j4 < 4; j4++) outv[j4] = dv[j4] * rstd * gvf[j4] + bvf[j4];
    *(float4*)(h2 + (size_t)node * 64 + 4 * r) = *(float4*)outv;
    ob.x = f2b(outv[0]); ob.y = f2b(outv[1]); ob.z = f2b(outv[2]); ob.w = f2b(outv[3]);
    *(ushort4*)(h2b + (size_t)node * 64 + 4 * r) = ob;
  }
}

// ---------------- fused pooling (mean+max) + ctx MLP, one block per batch ----------------
__global__ void k_poolctx(const float* __restrict__ lat, const int* __restrict__ starts,
                          const float* __restrict__ W1, const float* __restrict__ b1,
                          const float* __restrict__ W2, const float* __restrict__ b2,
                          float* __restrict__ ctx) {
  int b = blockIdx.x;
  int t = threadIdx.x;
  int lane = t & 63, sub = t >> 6;
  int s = starts[b], e = starts[b + 1];
  float sum = 0.f, mx = -3.4e38f;
  for (int i = s + sub; i < e; i += 4) {
    float v = lat[(size_t)i * 64 + lane];
    sum += v;
    mx = fmaxf(mx, v);
  }
  __shared__ float ls[4][64], lm[4][64];
  __shared__ float g[128], tt[64];
  ls[sub][lane] = sum;
  lm[sub][lane] = mx;
  __syncthreads();
  if (sub == 0) {
#pragma unroll
    for (int j = 1; j < 4; j++) {
      sum += ls[j][lane];
      mx = fmaxf(mx, lm[j][lane]);
    }
    int cnt = e - s;
    g[lane] = sum / fmaxf((float)cnt, 1.0f);
    g[64 + lane] = mx;
  }
  __syncthreads();
  if (t < 64) {
    float acc = b1[t];
    for (int k = 0; k < 128; k++) acc += g[k] * W1[k * 64 + t];
    tt[t] = gelu_t(acc);
  }
  __syncthreads();
  if (t < 64) {
    float acc2 = b2[t];
    for (int k = 0; k < 64; k++) acc2 += tt[k] * W2[k * 64 + t];
    ctx[b * 64 + t] = acc2;
  }
}

__global__ void k_add_ctx(float* __restrict__ h, unsigned short* __restrict__ hb,
                          const float* __restrict__ ctx,
                          const int* __restrict__ batch, int n) {
  int idx = blockIdx.x * blockDim.x + threadIdx.x;
  if (idx >= n * 64) return;
  int i = idx >> 6, d = idx & 63;
  float v = h[idx] + ctx[batch[i] * 64 + d];
  h[idx] = v;
  hb[idx] = f2b(v);
}

// ---------------- decoder stage 2: out = tD @ W2 + b2 ([64,2]) ----------------
__global__ void k_dec2(const float* __restrict__ tD, const float* __restrict__ W2,
                       const float* __restrict__ b2, float* __restrict__ out, int n) {
  int idx = blockIdx.x * blockDim.x + threadIdx.x;
  if (idx >= n * 2) return;
  int i = idx >> 1, j = idx & 1;
  float acc = b2[j];
#pragma unroll 8
  for (int k = 0; k < 64; k++) acc += tD[(size_t)i * 64 + k] * W2[k * 2 + j];
  out[idx] = acc;
}

// ---------------- host ----------------
extern "C" void kernel_launch(void* const* d_in, const int* in_sizes, int n_in,
                              void* d_out, int out_size, void* d_ws, size_t ws_size,
                              hipStream_t stream) {
  const float* x = (const float*)d_in[0];
  const int* ei = (const int*)d_in[1];
  const int* batch = (const int*)d_in[2];
  const float* enc_W = (const float*)d_in[3];
  const float* enc_b = (const float*)d_in[4];
  const float* gat_Wl = (const float*)d_in[5];
  const float* gat_Wr = (const float*)d_in[6];
  const float* gat_att = (const float*)d_in[7];
  const float* gat_b = (const float*)d_in[8];
  const float* ln_g = (const float*)d_in[9];
  const float* ln_b = (const float*)d_in[10];
  const float* ffn_W1 = (const float*)d_in[11];
  const float* ffn_b1 = (const float*)d_in[12];
  const float* ffn_W2 = (const float*)d_in[13];
  const float* ffn_b2 = (const float*)d_in[14];
  const float* n2g_W1 = (const float*)d_in[15];
  const float* n2g_b1 = (const float*)d_in[16];
  const float* n2g_W2 = (const float*)d_in[17];
  const float* n2g_b2 = (const float*)d_in[18];
  const float* g2n_W1 = (const float*)d_in[19];
  const float* g2n_b1 = (const float*)d_in[20];
  const float* g2n_W2 = (const float*)d_in[21];
  const float* g2n_b2 = (const float*)d_in[22];
  const float* dec_W1 = (const float*)d_in[23];
  const float* dec_b1 = (const float*)d_in[24];
  const float* dec_W2 = (const float*)d_in[25];
  const float* dec_b2 = (const float*)d_in[26];

  const int N = NN, E = EE;
  const int* e_src = ei;
  const int* e_dst = ei + E;

  // ---- workspace carve: fp32, int, then bf16 (16B-aligned) ----
  float* h = (float*)d_ws;                 // N*64
  float* h2 = h + (size_t)N * 64;          // N*64
  float* t1 = h2 + (size_t)N * 64;         // N*128 (tmpA = t1, lat = t1 + N*64)
  float* ctx = t1 + (size_t)N * 128;       // B*64
  int* cnt = (int*)(ctx + BBATCH * 64);    // N
  int* indptr = cnt + N;                   // N+1
  int* esrc = indptr + N + 1;              // E+N
  int* bsum = esrc + (E + N);              // 64
  int* starts = bsum + 64;                 // B+1
  size_t off = (size_t)(starts + BBATCH + 1) - (size_t)d_ws;
  off = (off + 15) & ~(size_t)15;
  unsigned short* hb = (unsigned short*)((char*)d_ws + off);   // N*64
  unsigned short* h2b = hb + (size_t)N * 64;                   // N*64
  unsigned short* tb = h2b + (size_t)N * 64;                   // N*128
  unsigned short* xlr = tb + (size_t)N * 128;                  // N*512 (xl | xr)
  unsigned short* wLR = xlr + (size_t)N * 512;                 // 4*512*64
  unsigned short* wF1 = wLR + 4 * 512 * 64;                    // 4*128*64
  unsigned short* wF2 = wF1 + 4 * 128 * 64;                    // 4*64*128
  unsigned short* wN1 = wF2 + 4 * 64 * 128;                    // 4*64*64
  unsigned short* wN2 = wN1 + 4 * 64 * 64;
  unsigned short* wD1 = wN2 + 4 * 64 * 64;                     // 64*64

  float* tmpA = t1;
  float* lat = t1 + (size_t)N * 64;

  const int TPB = 256;
  const int NBLK_SCAN = (N + 1 + 1023) / 1024;

  // ---- weight prep (bf16 transposed) ----
  hipLaunchKernelGGL(k_wprep_lr, dim3((4 * 512 * 64 + 255) / 256), dim3(256), 0, stream, gat_Wl, gat_Wr, wLR, 4);
  hipLaunchKernelGGL((k_wprep<64, 128>), dim3((4 * 64 * 128 + 255) / 256), dim3(256), 0, stream, ffn_W1, wF1, 4);
  hipLaunchKernelGGL((k_wprep<128, 64>), dim3((4 * 128 * 64 + 255) / 256), dim3(256), 0, stream, ffn_W2, wF2, 4);
  hipLaunchKernelGGL((k_wprep<64, 64>), dim3((4 * 64 * 64 + 255) / 256), dim3(256), 0, stream, n2g_W1, wN1, 4);
  hipLaunchKernelGGL((k_wprep<64, 64>), dim3((4 * 64 * 64 + 255) / 256), dim3(256), 0, stream, n2g_W2, wN2, 4);
  hipLaunchKernelGGL((k_wprep<64, 64>), dim3((64 * 64 + 255) / 256), dim3(256), 0, stream, dec_W1, wD1, 1);

  // ---- CSR build ----
  hipLaunchKernelGGL(k_init_cnt, dim3((N + TPB - 1) / TPB), dim3(TPB), 0, stream, cnt, N);
  hipLaunchKernelGGL(k_count_edges, dim3((E + TPB - 1) / TPB), dim3(TPB), 0, stream, e_dst, E, cnt);
  hipLaunchKernelGGL(k_scan_bsum, dim3(NBLK_SCAN), dim3(256), 0, stream, cnt, N, bsum);
  hipLaunchKernelGGL(k_scan_offsets, dim3(1), dim3(64), 0, stream, bsum, NBLK_SCAN);
  hipLaunchKernelGGL(k_scan_final, dim3(NBLK_SCAN), dim3(256), 0, stream, cnt, N, bsum, indptr);
  hipLaunchKernelGGL(k_csr_self, dim3((N + TPB - 1) / TPB), dim3(TPB), 0, stream, indptr, cnt, esrc, N);
  hipLaunchKernelGGL(k_csr_fill, dim3((E + TPB - 1) / TPB), dim3(TPB), 0, stream, e_src, e_dst, E, cnt, esrc);
  hipLaunchKernelGGL(k_batch_starts, dim3((N + TPB - 1) / TPB), dim3(TPB), 0, stream, batch, N, BBATCH, starts);

  // ---- encoder ----
  hipLaunchKernelGGL(k_encoder, dim3((N * 64 + TPB - 1) / TPB), dim3(TPB), 0, stream,
                     x, enc_W, enc_b, h, hb, N);

  const int GN = (N + 63) / 64;  // 782

  for (int l = 0; l < NLAYER; l++) {
    const unsigned short* LRt = wLR + (size_t)l * 512 * 64;
    const unsigned short* F1t = wF1 + (size_t)l * 128 * 64;
    const unsigned short* F2t = wF2 + (size_t)l * 64 * 128;
    const unsigned short* N1t = wN1 + (size_t)l * 64 * 64;
    const unsigned short* N2t = wN2 + (size_t)l * 64 * 64;
    const float* attl = gat_att + (size_t)l * 256;
    const float* gbl = gat_b + (size_t)l * 64;
    const float* lngl = ln_g + (size_t)l * 64;
    const float* lnbl = ln_b + (size_t)l * 64;
    const float* fb1 = ffn_b1 + (size_t)l * 128;
    const float* fb2 = ffn_b2 + (size_t)l * 64;
    const float* nb1 = n2g_b1 + (size_t)l * 64;
    const float* nb2 = n2g_b2 + (size_t)l * 64;
    const float* gW1 = g2n_W1 + (size_t)l * 128 * 64;
    const float* gb1 = g2n_b1 + (size_t)l * 64;
    const float* gW2 = g2n_W2 + (size_t)l * 64 * 64;
    const float* gb2 = g2n_b2 + (size_t)l * 64;

    // xlr = h @ [Wl|Wr]  (bf16 out, no bias) — one dispatch, Co=512
    hipLaunchKernelGGL((k_mgemm<64, 0, false, false, false, true>), dim3(GN, 8), dim3(256), 0, stream,
                       hb, LRt, nullptr, nullptr, nullptr, xlr, N, 512);
    // GAT aggregate + residual + LN -> h2 (+bf16)
    hipLaunchKernelGGL(k_gat, dim3((N + 3) / 4), dim3(256), 0, stream,
                       xlr, attl, gbl, lngl, lnbl, h, indptr, esrc, h2, h2b, N);
    // FFN1: tb = leaky(h2 @ W1 + b1)  (bf16 only)
    hipLaunchKernelGGL((k_mgemm<64, 1, false, true, false, true>), dim3(GN, 2), dim3(256), 0, stream,
                       h2b, F1t, fb1, nullptr, nullptr, tb, N, 128);
    // FFN2: h = tb @ W2 + b2 + h2  (fp32 + bf16)
    hipLaunchKernelGGL((k_mgemm<128, 0, true, true, true, true>), dim3(GN, 1), dim3(256), 0, stream,
                       tb, F2t, fb2, h2, h, hb, N, 64);
    // n2g1: tb = gelu(h @ nW1 + nb1)  (bf16 only)
    hipLaunchKernelGGL((k_mgemm<64, 2, false, true, false, true>), dim3(GN, 1), dim3(256), 0, stream,
                       hb, N1t, nb1, nullptr, nullptr, tb, N, 64);
    // n2g2: lat = tb @ nW2 + nb2  (fp32)
    hipLaunchKernelGGL((k_mgemm<64, 0, false, true, true, false>), dim3(GN, 1), dim3(256), 0, stream,
                       tb, N2t, nb2, nullptr, lat, nullptr, N, 64);
    // fused pool (mean+max) + ctx MLP
    hipLaunchKernelGGL(k_poolctx, dim3(BBATCH), dim3(256), 0, stream,
                       lat, starts, gW1, gb1, gW2, gb2, ctx);
    hipLaunchKernelGGL(k_add_ctx, dim3((N * 64 + TPB - 1) / TPB), dim3(TPB), 0, stream,
                       h, hb, ctx, batch, N);
  }

  // decoder: tmpA = gelu(h @ dW1 + db1) (fp32), then out = tmpA @ W2 + b2
  hipLaunchKernelGGL((k_mgemm<64, 2, false, true, true, false>), dim3(GN, 1), dim3(256), 0, stream,
                     hb, wD1, dec_b1, nullptr, tmpA, nullptr, N, 64);
  hipLaunchKernelGGL(k_dec2, dim3((N * 2 + TPB - 1) / TPB), dim3(TPB), 0, stream,
                     tmpA, dec_W2, dec_b2, (float*)d_out, N);
}

// Round 5
// 1167.160 us; speedup vs baseline: 1.8293x; 1.1056x over previous
//
#include <hip/hip_runtime.h>
#include <hip/hip_bf16.h>
#include <math.h>

#define NN 50000
#define EE 800000
#define BBATCH 64
#define DDIM 64
#define NLAYER 4
#define NIN 7
#define NHEAD 4

typedef __attribute__((ext_vector_type(8))) short short8v;   // 8 bf16 (4 VGPRs)
typedef __attribute__((ext_vector_type(4))) float f32x4;     // mfma acc

// ---------------- device helpers ----------------
static __device__ __forceinline__ float wave_sum(float v) {
#pragma unroll
  for (int m = 32; m > 0; m >>= 1) v += __shfl_xor(v, m, 64);
  return v;
}

static __device__ __forceinline__ float gelu_t(float x) {
  float z = 0.7978845608f * (x + 0.044715f * x * x * x);
  float t = 2.f / (1.f + __expf(-2.f * z)) - 1.f;
  return 0.5f * x * (1.f + t);
}

static __device__ __forceinline__ unsigned short f2b(float v) {
  __hip_bfloat16 b = __float2bfloat16(v);
  return *reinterpret_cast<unsigned short*>(&b);
}

// cross-lane add via DPP (VALU pipe, no LDS): CTRL = quad_perm/row_ror encoding
template <int CTRL>
static __device__ __forceinline__ float dppf(float v) {
  int x = __builtin_amdgcn_mov_dpp(__builtin_bit_cast(int, v), CTRL, 0xF, 0xF, true);
  return __builtin_bit_cast(float, x);
}
// quad_perm [1,0,3,2] = 0xB1 (xor1), [2,3,0,1] = 0x4E (xor2)
// row_ror:4 = 0x124, row_ror:8 = 0x128 (head-coset rotation-reduce within 16-row)

static __device__ __forceinline__ void unpack8(uint4 u, float* xs) {
  unsigned int w[4] = {u.x, u.y, u.z, u.w};
#pragma unroll
  for (int k = 0; k < 4; k++) {
    xs[2 * k]     = __builtin_bit_cast(float, w[k] << 16);
    xs[2 * k + 1] = __builtin_bit_cast(float, w[k] & 0xFFFF0000u);
  }
}

// ---------------- CSR build ----------------
__global__ void k_init_cnt(int* cnt, int n) {
  int i = blockIdx.x * blockDim.x + threadIdx.x;
  if (i < n) cnt[i] = 1;  // self loop
}

__global__ void k_count_edges(const int* __restrict__ dst, int e, int* cnt) {
  int i = blockIdx.x * blockDim.x + threadIdx.x;
  if (i < e) atomicAdd(&cnt[dst[i]], 1);
}

__global__ void k_scan_bsum(const int* __restrict__ cnt, int n, int* bsum) {
  __shared__ int red[256];
  int b = blockIdx.x, t = threadIdx.x;
  int s = 0;
  for (int i = b * 1024 + t; i < (b + 1) * 1024; i += 256)
    if (i < n) s += cnt[i];
  red[t] = s;
  __syncthreads();
  for (int o = 128; o > 0; o >>= 1) {
    if (t < o) red[t] += red[t + o];
    __syncthreads();
  }
  if (t == 0) bsum[b] = red[0];
}

__global__ void k_scan_offsets(int* bsum, int nb) {
  if (threadIdx.x == 0 && blockIdx.x == 0) {
    int acc = 0;
    for (int i = 0; i < nb; i++) { int v = bsum[i]; bsum[i] = acc; acc += v; }
  }
}

__global__ void k_scan_final(const int* __restrict__ cnt, int n,
                             const int* __restrict__ bsum, int* indptr) {
  __shared__ int lds[256];
  int b = blockIdx.x, t = threadIdx.x;
  int base = b * 1024;
  int v[4];
  int s = 0;
#pragma unroll
  for (int j = 0; j < 4; j++) {
    int i = base + t * 4 + j;
    v[j] = (i < n) ? cnt[i] : 0;
    s += v[j];
  }
  lds[t] = s;
  __syncthreads();
  for (int o = 1; o < 256; o <<= 1) {
    int x = (t >= o) ? lds[t - o] : 0;
    __syncthreads();
    lds[t] += x;
    __syncthreads();
  }
  int run = bsum[b] + lds[t] - s;
#pragma unroll
  for (int j = 0; j < 4; j++) {
    int i = base + t * 4 + j;
    if (i <= n) indptr[i] = run;
    run += v[j];
  }
}

__global__ void k_csr_self(const int* __restrict__ indptr, int* nxt, int* esrc, int n) {
  int i = blockIdx.x * blockDim.x + threadIdx.x;
  if (i < n) {
    int p = indptr[i];
    esrc[p] = i;
    nxt[i] = p + 1;
  }
}

__global__ void k_csr_fill(const int* __restrict__ src, const int* __restrict__ dst,
                           int e, int* nxt, int* esrc) {
  int i = blockIdx.x * blockDim.x + threadIdx.x;
  if (i < e) {
    int p = atomicAdd(&nxt[dst[i]], 1);
    esrc[p] = src[i];
  }
}

// ---------------- batch segment starts (batch is sorted) ----------------
__global__ void k_batch_starts(const int* __restrict__ batch, int n, int nb, int* starts) {
  int i = blockIdx.x * blockDim.x + threadIdx.x;
  if (i >= n) return;
  int b = batch[i];
  if (i == 0) {
    for (int x = 0; x <= b; x++) starts[x] = 0;
  } else {
    int pb = batch[i - 1];
    if (pb != b)
      for (int x = pb + 1; x <= b; x++) starts[x] = i;
  }
  if (i == n - 1) {
    for (int x = b + 1; x <= nb; x++) starts[x] = n;
  }
}

// ---------------- weight prep: W[l][K][Co] fp32 -> Wt[l][Co][K] bf16 ----------------
template <int K, int Co>
__global__ void k_wprep(const float* __restrict__ W, unsigned short* __restrict__ Wt, int L) {
  int idx = blockIdx.x * blockDim.x + threadIdx.x;
  if (idx >= L * K * Co) return;
  int l = idx / (K * Co), rem = idx % (K * Co);
  int k = rem / Co, c = rem % Co;
  Wt[(size_t)l * K * Co + (size_t)c * K + k] = f2b(W[idx]);
}

// combined Wl|Wr prep: out [L][512][64] bf16, c<256 from Wl, else Wr (both [L][64][256])
__global__ void k_wprep_lr(const float* __restrict__ Wl, const float* __restrict__ Wr,
                           unsigned short* __restrict__ Wt, int L) {
  int idx = blockIdx.x * blockDim.x + threadIdx.x;
  if (idx >= L * 512 * 64) return;
  int l = idx / (512 * 64), rem = idx % (512 * 64);
  int c = rem / 64, k = rem % 64;
  float v = (c < 256) ? Wl[(size_t)l * 64 * 256 + k * 256 + c]
                      : Wr[(size_t)l * 64 * 256 + k * 256 + (c - 256)];
  Wt[idx] = f2b(v);
}

// ---------------- encoder (also emits bf16 shadow) ----------------
__global__ void k_encoder(const float* __restrict__ x, const float* __restrict__ W,
                          const float* __restrict__ bias, float* __restrict__ h,
                          unsigned short* __restrict__ hb, int n) {
  int idx = blockIdx.x * blockDim.x + threadIdx.x;
  if (idx >= n * 64) return;
  int i = idx >> 6, d = idx & 63;
  float acc = bias[d];
#pragma unroll
  for (int k = 0; k < NIN; k++) acc += x[i * NIN + k] * W[k * 64 + d];
  h[idx] = acc;
  hb[idx] = f2b(acc);
}

// ---------------- MFMA bf16 GEMM: C = act(A[n,K]bf16 @ W[K,Co]bf16 + bias) (+res) ------
template <int K, int ACT, bool RES, bool BIAS, bool OUTF, bool OUTB>
__global__ __launch_bounds__(256) void k_mgemm(const unsigned short* __restrict__ A,
                                               const unsigned short* __restrict__ Wt,
                                               const float* __restrict__ bias,
                                               const float* __restrict__ res,
                                               float* __restrict__ C,
                                               unsigned short* __restrict__ Cb,
                                               int n, int Co) {
  constexpr int NF = K / 32;
  const int lane = threadIdx.x & 63, wave = threadIdx.x >> 6;
  const int row0 = blockIdx.x * 64 + wave * 16;
  const int c0 = blockIdx.y * 64;
  const int karow = (lane >> 4) * 8;
  const int arow = row0 + (lane & 15);
  const size_t abase = (size_t)(arow < n ? arow : 0) * K + karow;

  short8v a[NF];
#pragma unroll
  for (int f = 0; f < NF; f++)
    a[f] = *(const short8v*)(A + abase + f * 32);

  f32x4 acc[4];
#pragma unroll
  for (int cc = 0; cc < 4; cc++) {
    const int c = c0 + cc * 16 + (lane & 15);
    f32x4 t = {0.f, 0.f, 0.f, 0.f};
#pragma unroll
    for (int f = 0; f < NF; f++) {
      short8v b = *(const short8v*)(Wt + (size_t)c * K + f * 32 + karow);
      t = __builtin_amdgcn_mfma_f32_16x16x32_bf16(a[f], b, t, 0, 0, 0);
    }
    acc[cc] = t;
  }

#pragma unroll
  for (int cc = 0; cc < 4; cc++) {
    const int c = c0 + cc * 16 + (lane & 15);
    const float bv = BIAS ? bias[c] : 0.f;
#pragma unroll
    for (int r = 0; r < 4; r++) {
      const int row = row0 + (lane >> 4) * 4 + r;
      if (row < n) {
        float v = acc[cc][r] + bv;
        if (ACT == 1) v = fmaxf(v, 0.2f * v);
        else if (ACT == 2) v = gelu_t(v);
        if (RES) v += res[(size_t)row * Co + c];
        if (OUTF) C[(size_t)row * Co + c] = v;
        if (OUTB) Cb[(size_t)row * Co + c] = f2b(v);
      }
    }
  }
}

// ---------------- GATv2 aggregation + residual + LayerNorm (fused) ----------------
// xlr[N][512] bf16: cols 0..255 = xl, 256..511 = xr.
// One wave per node, 4 edges/iter (q=lane>>4 = edge stream).
// Lane r=lane&15 owns head (r>>2), dims [(r&3)*16, +16) of that head.
// Score reduce = 2 quad-perm DPP stages (quad == head group).
// No-max softmax (scores bounded; clamp 60): pw=exp(e), den+=pw, acc+=pw*xs.
// Head-average via row_ror:4/8 DPP rotation-reduce over head cosets.
__global__ __launch_bounds__(256) void k_gat(const unsigned short* __restrict__ xlr,
                                             const float* __restrict__ att,
                                             const float* __restrict__ gbias,
                                             const float* __restrict__ lng,
                                             const float* __restrict__ lnb,
                                             const float* __restrict__ h,
                                             const int* __restrict__ indptr,
                                             const int* __restrict__ esrc,
                                             float* __restrict__ h2,
                                             unsigned short* __restrict__ h2b, int n) {
  const int wave = threadIdx.x >> 6, lane = threadIdx.x & 63;
  const int node = blockIdx.x * 4 + wave;
  if (node >= n) return;
  const int q = lane >> 4, r = lane & 15;
  const int c = r & 3;
  const int doff = (r >> 2) * 64 + c * 16;  // this lane's 16-elem chunk within 256

  float xr_d[16], att_d[16];
  {
    const uint4* xp = (const uint4*)(xlr + (size_t)node * 512 + 256 + doff);
    uint4 u0 = xp[0], u1 = xp[1];
    unpack8(u0, xr_d);
    unpack8(u1, xr_d + 8);
    const float4* ap = (const float4*)(att + doff);
#pragma unroll
    for (int k = 0; k < 4; k++) {
      float4 a = ap[k];
      att_d[4 * k] = a.x; att_d[4 * k + 1] = a.y;
      att_d[4 * k + 2] = a.z; att_d[4 * k + 3] = a.w;
    }
  }

  float acc[16] = {};
  float den = 0.f;
  const int beg = indptr[node], end = indptr[node + 1];
  for (int jb = beg; jb < end; jb += 4) {
    const int j = jb + q;
    const bool valid = j < end;
    const int s = esrc[valid ? j : beg];  // beg always valid (self-loop)
    float xs[16];
    const uint4* xp = (const uint4*)(xlr + (size_t)s * 512 + doff);
    uint4 u0 = xp[0], u1 = xp[1];
    unpack8(u0, xs);
    unpack8(u1, xs + 8);
    float p0 = 0.f, p1 = 0.f, p2 = 0.f, p3 = 0.f;
#pragma unroll
    for (int k = 0; k < 4; k++) {
      float t0 = xs[4 * k + 0] + xr_d[4 * k + 0]; t0 = fmaxf(t0, 0.2f * t0); p0 = fmaf(t0, att_d[4 * k + 0], p0);
      float t1 = xs[4 * k + 1] + xr_d[4 * k + 1]; t1 = fmaxf(t1, 0.2f * t1); p1 = fmaf(t1, att_d[4 * k + 1], p1);
      float t2 = xs[4 * k + 2] + xr_d[4 * k + 2]; t2 = fmaxf(t2, 0.2f * t2); p2 = fmaf(t2, att_d[4 * k + 2], p2);
      float t3 = xs[4 * k + 3] + xr_d[4 * k + 3]; t3 = fmaxf(t3, 0.2f * t3); p3 = fmaf(t3, att_d[4 * k + 3], p3);
    }
    float p = (p0 + p1) + (p2 + p3);
    p += dppf<0xB1>(p);  // xor1 within quad
    p += dppf<0x4E>(p);  // xor2 within quad -> full 64-dim head score
    const float pw = valid ? __expf(fminf(p, 60.f)) : 0.f;
    den += pw;
#pragma unroll
    for (int d = 0; d < 16; d++) acc[d] = fmaf(pw, xs[d], acc[d]);
  }

  // merge the 4 edge streams (plain sums; no max bookkeeping)
  den += __shfl_xor(den, 16, 64);
  den += __shfl_xor(den, 32, 64);
#pragma unroll
  for (int d = 0; d < 16; d++) {
    acc[d] += __shfl_xor(acc[d], 16, 64);
    acc[d] += __shfl_xor(acc[d], 32, 64);
  }

  const float rden = 0.25f / (den + 1e-16f);  // fold head-mean's 1/4
  float y[16];
  float s4 = 0.f;
  const float4* hp = (const float4*)(h + (size_t)node * 64 + c * 16);
  const float4* gp = (const float4*)(gbias + c * 16);
#pragma unroll
  for (int k = 0; k < 4; k++) {
    float4 hv = hp[k], gv = gp[k];
    float hf[4] = {hv.x, hv.y, hv.z, hv.w};
    float gf[4] = {gv.x, gv.y, gv.z, gv.w};
#pragma unroll
    for (int d2 = 0; d2 < 4; d2++) {
      int d = 4 * k + d2;
      float v = acc[d] * rden;
      v += dppf<0x124>(v);  // row_ror:4
      v += dppf<0x128>(v);  // row_ror:8 -> sum over 4 heads (coset {r, r^4-ish rotation})
      y[d] = hf[d2] + v + gf[d2];
      s4 += y[d];
    }
  }

  // LayerNorm: each distinct dim replicated in 16 lanes
  const float mu = wave_sum(s4) * (1.f / 1024.f);
  float v4 = 0.f;
  float dv[16];
#pragma unroll
  for (int d = 0; d < 16; d++) {
    dv[d] = y[d] - mu;
    v4 += dv[d] * dv[d];
  }
  const float var = wave_sum(v4) * (1.f / 1024.f);
  const float rstd = rsqrtf(var + 1e-5f);

  if (lane < 4) {  // q=0, head=0, c=lane: owns dims [lane*16, +16)
    float4* outp = (float4*)(h2 + (size_t)node * 64 + lane * 16);
    uint2* outb = (uint2*)(h2b + (size_t)node * 64 + lane * 16);
    const float4* lgp = (const float4*)(lng + lane * 16);
    const float4* lbp = (const float4*)(lnb + lane * 16);
#pragma unroll
    for (int k = 0; k < 4; k++) {
      float4 g = lgp[k], b = lbp[k];
      float o0 = dv[4 * k + 0] * rstd * g.x + b.x;
      float o1 = dv[4 * k + 1] * rstd * g.y + b.y;
      float o2 = dv[4 * k + 2] * rstd * g.z + b.z;
      float o3 = dv[4 * k + 3] * rstd * g.w + b.w;
      float4 of; of.x = o0; of.y = o1; of.z = o2; of.w = o3;
      outp[k] = of;
      uint2 pk;
      pk.x = (unsigned int)f2b(o0) | ((unsigned int)f2b(o1) << 16);
      pk.y = (unsigned int)f2b(o2) | ((unsigned int)f2b(o3) << 16);
      outb[k] = pk;
    }
  }
}

// ---------------- fused pooling (mean+max) + ctx MLP, one block per batch ----------------
__global__ void k_poolctx(const float* __restrict__ lat, const int* __restrict__ starts,
                          const float* __restrict__ W1, const float* __restrict__ b1,
                          const float* __restrict__ W2, const float* __restrict__ b2,
                          float* __restrict__ ctx) {
  int b = blockIdx.x;
  int t = threadIdx.x;
  int lane = t & 63, sub = t >> 6;
  int s = starts[b], e = starts[b + 1];
  float sum = 0.f, mx = -3.4e38f;
  for (int i = s + sub; i < e; i += 4) {
    float v = lat[(size_t)i * 64 + lane];
    sum += v;
    mx = fmaxf(mx, v);
  }
  __shared__ float ls[4][64], lm[4][64];
  __shared__ float g[128], tt[64];
  ls[sub][lane] = sum;
  lm[sub][lane] = mx;
  __syncthreads();
  if (sub == 0) {
#pragma unroll
    for (int j = 1; j < 4; j++) {
      sum += ls[j][lane];
      mx = fmaxf(mx, lm[j][lane]);
    }
    int cnt = e - s;
    g[lane] = sum / fmaxf((float)cnt, 1.0f);
    g[64 + lane] = mx;
  }
  __syncthreads();
  if (t < 64) {
    float acc = b1[t];
    for (int k = 0; k < 128; k++) acc += g[k] * W1[k * 64 + t];
    tt[t] = gelu_t(acc);
  }
  __syncthreads();
  if (t < 64) {
    float acc2 = b2[t];
    for (int k = 0; k < 64; k++) acc2 += tt[k] * W2[k * 64 + t];
    ctx[b * 64 + t] = acc2;
  }
}

__global__ void k_add_ctx(float* __restrict__ h, unsigned short* __restrict__ hb,
                          const float* __restrict__ ctx,
                          const int* __restrict__ batch, int n) {
  int idx = blockIdx.x * blockDim.x + threadIdx.x;
  if (idx >= n * 64) return;
  int i = idx >> 6, d = idx & 63;
  float v = h[idx] + ctx[batch[i] * 64 + d];
  h[idx] = v;
  hb[idx] = f2b(v);
}

// ---------------- decoder stage 2: out = tD @ W2 + b2 ([64,2]) ----------------
__global__ void k_dec2(const float* __restrict__ tD, const float* __restrict__ W2,
                       const float* __restrict__ b2, float* __restrict__ out, int n) {
  int idx = blockIdx.x * blockDim.x + threadIdx.x;
  if (idx >= n * 2) return;
  int i = idx >> 1, j = idx & 1;
  float acc = b2[j];
#pragma unroll 8
  for (int k = 0; k < 64; k++) acc += tD[(size_t)i * 64 + k] * W2[k * 2 + j];
  out[idx] = acc;
}

// ---------------- host ----------------
extern "C" void kernel_launch(void* const* d_in, const int* in_sizes, int n_in,
                              void* d_out, int out_size, void* d_ws, size_t ws_size,
                              hipStream_t stream) {
  const float* x = (const float*)d_in[0];
  const int* ei = (const int*)d_in[1];
  const int* batch = (const int*)d_in[2];
  const float* enc_W = (const float*)d_in[3];
  const float* enc_b = (const float*)d_in[4];
  const float* gat_Wl = (const float*)d_in[5];
  const float* gat_Wr = (const float*)d_in[6];
  const float* gat_att = (const float*)d_in[7];
  const float* gat_b = (const float*)d_in[8];
  const float* ln_g = (const float*)d_in[9];
  const float* ln_b = (const float*)d_in[10];
  const float* ffn_W1 = (const float*)d_in[11];
  const float* ffn_b1 = (const float*)d_in[12];
  const float* ffn_W2 = (const float*)d_in[13];
  const float* ffn_b2 = (const float*)d_in[14];
  const float* n2g_W1 = (const float*)d_in[15];
  const float* n2g_b1 = (const float*)d_in[16];
  const float* n2g_W2 = (const float*)d_in[17];
  const float* n2g_b2 = (const float*)d_in[18];
  const float* g2n_W1 = (const float*)d_in[19];
  const float* g2n_b1 = (const float*)d_in[20];
  const float* g2n_W2 = (const float*)d_in[21];
  const float* g2n_b2 = (const float*)d_in[22];
  const float* dec_W1 = (const float*)d_in[23];
  const float* dec_b1 = (const float*)d_in[24];
  const float* dec_W2 = (const float*)d_in[25];
  const float* dec_b2 = (const float*)d_in[26];

  const int N = NN, E = EE;
  const int* e_src = ei;
  const int* e_dst = ei + E;

  // ---- workspace carve: fp32, int, then bf16 (16B-aligned) ----
  float* h = (float*)d_ws;                 // N*64
  float* h2 = h + (size_t)N * 64;          // N*64
  float* t1 = h2 + (size_t)N * 64;         // N*128 (tmpA = t1, lat = t1 + N*64)
  float* ctx = t1 + (size_t)N * 128;       // B*64
  int* cnt = (int*)(ctx + BBATCH * 64);    // N
  int* indptr = cnt + N;                   // N+1
  int* esrc = indptr + N + 1;              // E+N
  int* bsum = esrc + (E + N);              // 64
  int* starts = bsum + 64;                 // B+1
  size_t off = (size_t)(starts + BBATCH + 1) - (size_t)d_ws;
  off = (off + 15) & ~(size_t)15;
  unsigned short* hb = (unsigned short*)((char*)d_ws + off);   // N*64
  unsigned short* h2b = hb + (size_t)N * 64;                   // N*64
  unsigned short* tb = h2b + (size_t)N * 64;                   // N*128
  unsigned short* xlr = tb + (size_t)N * 128;                  // N*512 (xl | xr)
  unsigned short* wLR = xlr + (size_t)N * 512;                 // 4*512*64
  unsigned short* wF1 = wLR + 4 * 512 * 64;                    // 4*128*64
  unsigned short* wF2 = wF1 + 4 * 128 * 64;                    // 4*64*128
  unsigned short* wN1 = wF2 + 4 * 64 * 128;                    // 4*64*64
  unsigned short* wN2 = wN1 + 4 * 64 * 64;
  unsigned short* wD1 = wN2 + 4 * 64 * 64;                     // 64*64

  float* tmpA = t1;
  float* lat = t1 + (size_t)N * 64;

  const int TPB = 256;
  const int NBLK_SCAN = (N + 1 + 1023) / 1024;

  // ---- weight prep (bf16 transposed) ----
  hipLaunchKernelGGL(k_wprep_lr, dim3((4 * 512 * 64 + 255) / 256), dim3(256), 0, stream, gat_Wl, gat_Wr, wLR, 4);
  hipLaunchKernelGGL((k_wprep<64, 128>), dim3((4 * 64 * 128 + 255) / 256), dim3(256), 0, stream, ffn_W1, wF1, 4);
  hipLaunchKernelGGL((k_wprep<128, 64>), dim3((4 * 128 * 64 + 255) / 256), dim3(256), 0, stream, ffn_W2, wF2, 4);
  hipLaunchKernelGGL((k_wprep<64, 64>), dim3((4 * 64 * 64 + 255) / 256), dim3(256), 0, stream, n2g_W1, wN1, 4);
  hipLaunchKernelGGL((k_wprep<64, 64>), dim3((4 * 64 * 64 + 255) / 256), dim3(256), 0, stream, n2g_W2, wN2, 4);
  hipLaunchKernelGGL((k_wprep<64, 64>), dim3((64 * 64 + 255) / 256), dim3(256), 0, stream, dec_W1, wD1, 1);

  // ---- CSR build ----
  hipLaunchKernelGGL(k_init_cnt, dim3((N + TPB - 1) / TPB), dim3(TPB), 0, stream, cnt, N);
  hipLaunchKernelGGL(k_count_edges, dim3((E + TPB - 1) / TPB), dim3(TPB), 0, stream, e_dst, E, cnt);
  hipLaunchKernelGGL(k_scan_bsum, dim3(NBLK_SCAN), dim3(256), 0, stream, cnt, N, bsum);
  hipLaunchKernelGGL(k_scan_offsets, dim3(1), dim3(64), 0, stream, bsum, NBLK_SCAN);
  hipLaunchKernelGGL(k_scan_final, dim3(NBLK_SCAN), dim3(256), 0, stream, cnt, N, bsum, indptr);
  hipLaunchKernelGGL(k_csr_self, dim3((N + TPB - 1) / TPB), dim3(TPB), 0, stream, indptr, cnt, esrc, N);
  hipLaunchKernelGGL(k_csr_fill, dim3((E + TPB - 1) / TPB), dim3(TPB), 0, stream, e_src, e_dst, E, cnt, esrc);
  hipLaunchKernelGGL(k_batch_starts, dim3((N + TPB - 1) / TPB), dim3(TPB), 0, stream, batch, N, BBATCH, starts);

  // ---- encoder ----
  hipLaunchKernelGGL(k_encoder, dim3((N * 64 + TPB - 1) / TPB), dim3(TPB), 0, stream,
                     x, enc_W, enc_b, h, hb, N);

  const int GN = (N + 63) / 64;  // 782

  for (int l = 0; l < NLAYER; l++) {
    const unsigned short* LRt = wLR + (size_t)l * 512 * 64;
    const unsigned short* F1t = wF1 + (size_t)l * 128 * 64;
    const unsigned short* F2t = wF2 + (size_t)l * 64 * 128;
    const unsigned short* N1t = wN1 + (size_t)l * 64 * 64;
    const unsigned short* N2t = wN2 + (size_t)l * 64 * 64;
    const float* attl = gat_att + (size_t)l * 256;
    const float* gbl = gat_b + (size_t)l * 64;
    const float* lngl = ln_g + (size_t)l * 64;
    const float* lnbl = ln_b + (size_t)l * 64;
    const float* fb1 = ffn_b1 + (size_t)l * 128;
    const float* fb2 = ffn_b2 + (size_t)l * 64;
    const float* nb1 = n2g_b1 + (size_t)l * 64;
    const float* nb2 = n2g_b2 + (size_t)l * 64;
    const float* gW1 = g2n_W1 + (size_t)l * 128 * 64;
    const float* gb1 = g2n_b1 + (size_t)l * 64;
    const float* gW2 = g2n_W2 + (size_t)l * 64 * 64;
    const float* gb2 = g2n_b2 + (size_t)l * 64;

    // xlr = h @ [Wl|Wr]  (bf16 out, no bias) — one dispatch, Co=512
    hipLaunchKernelGGL((k_mgemm<64, 0, false, false, false, true>), dim3(GN, 8), dim3(256), 0, stream,
                       hb, LRt, nullptr, nullptr, nullptr, xlr, N, 512);
    // GAT aggregate + residual + LN -> h2 (+bf16)
    hipLaunchKernelGGL(k_gat, dim3((N + 3) / 4), dim3(256), 0, stream,
                       xlr, attl, gbl, lngl, lnbl, h, indptr, esrc, h2, h2b, N);
    // FFN1: tb = leaky(h2 @ W1 + b1)  (bf16 only)
    hipLaunchKernelGGL((k_mgemm<64, 1, false, true, false, true>), dim3(GN, 2), dim3(256), 0, stream,
                       h2b, F1t, fb1, nullptr, nullptr, tb, N, 128);
    // FFN2: h = tb @ W2 + b2 + h2  (fp32 + bf16)
    hipLaunchKernelGGL((k_mgemm<128, 0, true, true, true, true>), dim3(GN, 1), dim3(256), 0, stream,
                       tb, F2t, fb2, h2, h, hb, N, 64);
    // n2g1: tb = gelu(h @ nW1 + nb1)  (bf16 only)
    hipLaunchKernelGGL((k_mgemm<64, 2, false, true, false, true>), dim3(GN, 1), dim3(256), 0, stream,
                       hb, N1t, nb1, nullptr, nullptr, tb, N, 64);
    // n2g2: lat = tb @ nW2 + nb2  (fp32)
    hipLaunchKernelGGL((k_mgemm<64, 0, false, true, true, false>), dim3(GN, 1), dim3(256), 0, stream,
                       tb, N2t, nb2, nullptr, lat, nullptr, N, 64);
    // fused pool (mean+max) + ctx MLP
    hipLaunchKernelGGL(k_poolctx, dim3(BBATCH), dim3(256), 0, stream,
                       lat, starts, gW1, gb1, gW2, gb2, ctx);
    hipLaunchKernelGGL(k_add_ctx, dim3((N * 64 + TPB - 1) / TPB), dim3(TPB), 0, stream,
                       h, hb, ctx, batch, N);
  }

  // decoder: tmpA = gelu(h @ dW1 + db1) (fp32), then out = tmpA @ W2 + b2
  hipLaunchKernelGGL((k_mgemm<64, 2, false, true, true, false>), dim3(GN, 1), dim3(256), 0, stream,
                     hb, wD1, dec_b1, nullptr, tmpA, nullptr, N, 64);
  hipLaunchKernelGGL(k_dec2, dim3((N * 2 + TPB - 1) / TPB), dim3(TPB), 0, stream,
                     tmpA, dec_W2, dec_b2, (float*)d_out, N);
}

// Round 6
// 943.413 us; speedup vs baseline: 2.2632x; 1.2372x over previous
//
#include <hip/hip_runtime.h>
#include <hip/hip_bf16.h>
#include <math.h>

#define NN 50000
#define EE 800000
#define BBATCH 64
#define DDIM 64
#define NLAYER 4
#define NIN 7
#define NHEAD 4

typedef __attribute__((ext_vector_type(8))) short short8v;   // 8 bf16 (4 VGPRs)
typedef __attribute__((ext_vector_type(4))) float f32x4;     // mfma acc

// ---------------- device helpers ----------------
static __device__ __forceinline__ float wave_sum(float v) {
#pragma unroll
  for (int m = 32; m > 0; m >>= 1) v += __shfl_xor(v, m, 64);
  return v;
}

static __device__ __forceinline__ float gelu_t(float x) {
  float z = 0.7978845608f * (x + 0.044715f * x * x * x);
  float t = 2.f / (1.f + __expf(-2.f * z)) - 1.f;
  return 0.5f * x * (1.f + t);
}

static __device__ __forceinline__ unsigned short f2b(float v) {
  __hip_bfloat16 b = __float2bfloat16(v);
  return *reinterpret_cast<unsigned short*>(&b);
}

static __device__ __forceinline__ float b2f(unsigned short u) {
  return __builtin_bit_cast(float, (unsigned int)u << 16);
}

// cross-lane add via DPP (VALU pipe, no LDS)
template <int CTRL>
static __device__ __forceinline__ float dppf(float v) {
  int x = __builtin_amdgcn_mov_dpp(__builtin_bit_cast(int, v), CTRL, 0xF, 0xF, true);
  return __builtin_bit_cast(float, x);
}
// quad_perm [1,0,3,2]=0xB1 (xor1), [2,3,0,1]=0x4E (xor2), row_ror:4=0x124, row_ror:8=0x128

static __device__ __forceinline__ void unpack8(uint4 u, float* xs) {
  unsigned int w[4] = {u.x, u.y, u.z, u.w};
#pragma unroll
  for (int k = 0; k < 4; k++) {
    xs[2 * k]     = __builtin_bit_cast(float, w[k] << 16);
    xs[2 * k + 1] = __builtin_bit_cast(float, w[k] & 0xFFFF0000u);
  }
}

// ---------------- CSR build ----------------
__global__ void k_init_cnt(int* cnt, int n) {
  int i = blockIdx.x * blockDim.x + threadIdx.x;
  if (i < n) cnt[i] = 1;  // self loop
}

__global__ void k_count_edges(const int* __restrict__ dst, int e, int* cnt) {
  int i = blockIdx.x * blockDim.x + threadIdx.x;
  if (i < e) atomicAdd(&cnt[dst[i]], 1);
}

__global__ void k_scan_bsum(const int* __restrict__ cnt, int n, int* bsum) {
  __shared__ int red[256];
  int b = blockIdx.x, t = threadIdx.x;
  int s = 0;
  for (int i = b * 1024 + t; i < (b + 1) * 1024; i += 256)
    if (i < n) s += cnt[i];
  red[t] = s;
  __syncthreads();
  for (int o = 128; o > 0; o >>= 1) {
    if (t < o) red[t] += red[t + o];
    __syncthreads();
  }
  if (t == 0) bsum[b] = red[0];
}

__global__ void k_scan_offsets(int* bsum, int nb) {
  if (threadIdx.x == 0 && blockIdx.x == 0) {
    int acc = 0;
    for (int i = 0; i < nb; i++) { int v = bsum[i]; bsum[i] = acc; acc += v; }
  }
}

__global__ void k_scan_final(const int* __restrict__ cnt, int n,
                             const int* __restrict__ bsum, int* indptr) {
  __shared__ int lds[256];
  int b = blockIdx.x, t = threadIdx.x;
  int base = b * 1024;
  int v[4];
  int s = 0;
#pragma unroll
  for (int j = 0; j < 4; j++) {
    int i = base + t * 4 + j;
    v[j] = (i < n) ? cnt[i] : 0;
    s += v[j];
  }
  lds[t] = s;
  __syncthreads();
  for (int o = 1; o < 256; o <<= 1) {
    int x = (t >= o) ? lds[t - o] : 0;
    __syncthreads();
    lds[t] += x;
    __syncthreads();
  }
  int run = bsum[b] + lds[t] - s;
#pragma unroll
  for (int j = 0; j < 4; j++) {
    int i = base + t * 4 + j;
    if (i <= n) indptr[i] = run;
    run += v[j];
  }
}

__global__ void k_csr_self(const int* __restrict__ indptr, int* nxt, int* esrc, int n) {
  int i = blockIdx.x * blockDim.x + threadIdx.x;
  if (i < n) {
    int p = indptr[i];
    esrc[p] = i;
    nxt[i] = p + 1;
  }
}

__global__ void k_csr_fill(const int* __restrict__ src, const int* __restrict__ dst,
                           int e, int* nxt, int* esrc) {
  int i = blockIdx.x * blockDim.x + threadIdx.x;
  if (i < e) {
    int p = atomicAdd(&nxt[dst[i]], 1);
    esrc[p] = src[i];
  }
}

// ---------------- batch segment starts (batch is sorted) ----------------
__global__ void k_batch_starts(const int* __restrict__ batch, int n, int nb, int* starts) {
  int i = blockIdx.x * blockDim.x + threadIdx.x;
  if (i >= n) return;
  int b = batch[i];
  if (i == 0) {
    for (int x = 0; x <= b; x++) starts[x] = 0;
  } else {
    int pb = batch[i - 1];
    if (pb != b)
      for (int x = pb + 1; x <= b; x++) starts[x] = i;
  }
  if (i == n - 1) {
    for (int x = b + 1; x <= nb; x++) starts[x] = n;
  }
}

// ---------------- merged weight prep: all fp32 W -> bf16 W^T in one dispatch ----------------
#define SEG_LR (4 * 512 * 64)
#define SEG_F1 (4 * 128 * 64)
#define SEG_F2 (4 * 64 * 128)
#define SEG_N  (4 * 64 * 64)
#define SEG_D  (64 * 64)
#define WPREP_TOTAL (SEG_LR + SEG_F1 + SEG_F2 + 2 * SEG_N + SEG_D)
__global__ void k_wprep_all(const float* __restrict__ Wl, const float* __restrict__ Wr,
                            const float* __restrict__ F1, const float* __restrict__ F2,
                            const float* __restrict__ N1, const float* __restrict__ N2,
                            const float* __restrict__ D1,
                            unsigned short* __restrict__ wLR, unsigned short* __restrict__ wF1,
                            unsigned short* __restrict__ wF2, unsigned short* __restrict__ wN1,
                            unsigned short* __restrict__ wN2, unsigned short* __restrict__ wD1) {
  int idx = blockIdx.x * blockDim.x + threadIdx.x;
  if (idx < SEG_LR) {  // [l][c:512][k:64] <- Wl/Wr [l][64][256]
    int l = idx / (512 * 64), rem = idx % (512 * 64);
    int c = rem / 64, k = rem % 64;
    float v = (c < 256) ? Wl[(size_t)l * 64 * 256 + k * 256 + c]
                        : Wr[(size_t)l * 64 * 256 + k * 256 + (c - 256)];
    wLR[idx] = f2b(v);
    return;
  }
  idx -= SEG_LR;
  if (idx < SEG_F1) {  // K=64 Co=128
    int l = idx / (128 * 64), rem = idx % (128 * 64);
    int c = rem / 64, k = rem % 64;
    wF1[idx] = f2b(F1[(size_t)l * 64 * 128 + k * 128 + c]);
    return;
  }
  idx -= SEG_F1;
  if (idx < SEG_F2) {  // K=128 Co=64
    int l = idx / (64 * 128), rem = idx % (64 * 128);
    int c = rem / 128, k = rem % 128;
    wF2[idx] = f2b(F2[(size_t)l * 128 * 64 + k * 64 + c]);
    return;
  }
  idx -= SEG_F2;
  if (idx < SEG_N) {  // K=64 Co=64
    int l = idx / (64 * 64), rem = idx % (64 * 64);
    int c = rem / 64, k = rem % 64;
    wN1[idx] = f2b(N1[(size_t)l * 64 * 64 + k * 64 + c]);
    return;
  }
  idx -= SEG_N;
  if (idx < SEG_N) {
    int l = idx / (64 * 64), rem = idx % (64 * 64);
    int c = rem / 64, k = rem % 64;
    wN2[idx] = f2b(N2[(size_t)l * 64 * 64 + k * 64 + c]);
    return;
  }
  idx -= SEG_N;
  if (idx < SEG_D) {
    int c = idx / 64, k = idx % 64;
    wD1[idx] = f2b(D1[k * 64 + c]);
  }
}

// ---------------- encoder (also emits bf16 shadow) ----------------
__global__ void k_encoder(const float* __restrict__ x, const float* __restrict__ W,
                          const float* __restrict__ bias, float* __restrict__ h,
                          unsigned short* __restrict__ hb, int n) {
  int idx = blockIdx.x * blockDim.x + threadIdx.x;
  if (idx >= n * 64) return;
  int i = idx >> 6, d = idx & 63;
  float acc = bias[d];
#pragma unroll
  for (int k = 0; k < NIN; k++) acc += x[i * NIN + k] * W[k * 64 + d];
  h[idx] = acc;
  hb[idx] = f2b(acc);
}

// ---------------- MFMA bf16 GEMM: C = act(A[n,K]bf16 @ W[K,Co]bf16 + bias) (+res) ------
template <int K, int ACT, bool RES, bool BIAS, bool OUTF, bool OUTB>
__global__ __launch_bounds__(256) void k_mgemm(const unsigned short* __restrict__ A,
                                               const unsigned short* __restrict__ Wt,
                                               const float* __restrict__ bias,
                                               const float* __restrict__ res,
                                               float* __restrict__ C,
                                               unsigned short* __restrict__ Cb,
                                               int n, int Co) {
  constexpr int NF = K / 32;
  const int lane = threadIdx.x & 63, wave = threadIdx.x >> 6;
  const int row0 = blockIdx.x * 64 + wave * 16;
  const int c0 = blockIdx.y * 64;
  const int karow = (lane >> 4) * 8;
  const int arow = row0 + (lane & 15);
  const size_t abase = (size_t)(arow < n ? arow : 0) * K + karow;

  short8v a[NF];
#pragma unroll
  for (int f = 0; f < NF; f++)
    a[f] = *(const short8v*)(A + abase + f * 32);

  f32x4 acc[4];
#pragma unroll
  for (int cc = 0; cc < 4; cc++) {
    const int c = c0 + cc * 16 + (lane & 15);
    f32x4 t = {0.f, 0.f, 0.f, 0.f};
#pragma unroll
    for (int f = 0; f < NF; f++) {
      short8v b = *(const short8v*)(Wt + (size_t)c * K + f * 32 + karow);
      t = __builtin_amdgcn_mfma_f32_16x16x32_bf16(a[f], b, t, 0, 0, 0);
    }
    acc[cc] = t;
  }

#pragma unroll
  for (int cc = 0; cc < 4; cc++) {
    const int c = c0 + cc * 16 + (lane & 15);
    const float bv = BIAS ? bias[c] : 0.f;
#pragma unroll
    for (int r = 0; r < 4; r++) {
      const int row = row0 + (lane >> 4) * 4 + r;
      if (row < n) {
        float v = acc[cc][r] + bv;
        if (ACT == 1) v = fmaxf(v, 0.2f * v);
        else if (ACT == 2) v = gelu_t(v);
        if (RES) v += res[(size_t)row * Co + c];
        if (OUTF) C[(size_t)row * Co + c] = v;
        if (OUTB) Cb[(size_t)row * Co + c] = f2b(v);
      }
    }
  }
}

// ---------------- GATv2 aggregation + residual + LayerNorm (fused) ----------------
// xlr[N][512] bf16: cols 0..255 = xl, 256..511 = xr.
// One wave/node, 4 edge streams (q), lane r owns head (r>>2) dims [(r&3)*16,+16).
// 1-deep software pipeline: next esrc + gathers issued before current VALU.
__global__ __launch_bounds__(256) void k_gat(const unsigned short* __restrict__ xlr,
                                             const float* __restrict__ att,
                                             const float* __restrict__ gbias,
                                             const float* __restrict__ lng,
                                             const float* __restrict__ lnb,
                                             const float* __restrict__ h,
                                             const int* __restrict__ indptr,
                                             const int* __restrict__ esrc,
                                             float* __restrict__ h2,
                                             unsigned short* __restrict__ h2b, int n) {
  const int wave = threadIdx.x >> 6, lane = threadIdx.x & 63;
  const int node = blockIdx.x * 4 + wave;
  if (node >= n) return;
  const int q = lane >> 4, r = lane & 15;
  const int c = r & 3;
  const int doff = (r >> 2) * 64 + c * 16;  // this lane's 16-elem chunk within 256

  float xr_d[16], att_d[16];
  {
    const uint4* xp = (const uint4*)(xlr + (size_t)node * 512 + 256 + doff);
    uint4 u0 = xp[0], u1 = xp[1];
    unpack8(u0, xr_d);
    unpack8(u1, xr_d + 8);
    const float4* ap = (const float4*)(att + doff);
#pragma unroll
    for (int k = 0; k < 4; k++) {
      float4 a = ap[k];
      att_d[4 * k] = a.x; att_d[4 * k + 1] = a.y;
      att_d[4 * k + 2] = a.z; att_d[4 * k + 3] = a.w;
    }
  }

  float acc[16] = {};
  float den = 0.f;
  const int beg = indptr[node], end = indptr[node + 1];

  // pipeline prologue: load first edge's data
  int j0 = beg + q;
  bool valid = j0 < end;
  {
    int s0 = esrc[valid ? j0 : beg];
    const uint4* xp0 = (const uint4*)(xlr + (size_t)s0 * 512 + doff);
    uint4 u0 = xp0[0], u1 = xp0[1];

    for (int jb = beg; jb < end; jb += 4) {
      const uint4 cu0 = u0, cu1 = u1;
      const bool cvalid = valid;
      if (jb + 4 < end) {  // uniform: prefetch next iteration
        const int jn = jb + 4 + q;
        valid = jn < end;
        int sn = esrc[valid ? jn : beg];
        const uint4* xpn = (const uint4*)(xlr + (size_t)sn * 512 + doff);
        u0 = xpn[0];
        u1 = xpn[1];
      }
      float xs[16];
      unpack8(cu0, xs);
      unpack8(cu1, xs + 8);
      float p0 = 0.f, p1 = 0.f, p2 = 0.f, p3 = 0.f;
#pragma unroll
      for (int k = 0; k < 4; k++) {
        float t0 = xs[4 * k + 0] + xr_d[4 * k + 0]; t0 = fmaxf(t0, 0.2f * t0); p0 = fmaf(t0, att_d[4 * k + 0], p0);
        float t1 = xs[4 * k + 1] + xr_d[4 * k + 1]; t1 = fmaxf(t1, 0.2f * t1); p1 = fmaf(t1, att_d[4 * k + 1], p1);
        float t2 = xs[4 * k + 2] + xr_d[4 * k + 2]; t2 = fmaxf(t2, 0.2f * t2); p2 = fmaf(t2, att_d[4 * k + 2], p2);
        float t3 = xs[4 * k + 3] + xr_d[4 * k + 3]; t3 = fmaxf(t3, 0.2f * t3); p3 = fmaf(t3, att_d[4 * k + 3], p3);
      }
      float p = (p0 + p1) + (p2 + p3);
      p += dppf<0xB1>(p);  // xor1 within quad
      p += dppf<0x4E>(p);  // xor2 within quad -> full 64-dim head score
      const float pw = cvalid ? __expf(fminf(p, 60.f)) : 0.f;
      den += pw;
#pragma unroll
      for (int d = 0; d < 16; d++) acc[d] = fmaf(pw, xs[d], acc[d]);
    }
  }

  // merge the 4 edge streams
  den += __shfl_xor(den, 16, 64);
  den += __shfl_xor(den, 32, 64);
#pragma unroll
  for (int d = 0; d < 16; d++) {
    acc[d] += __shfl_xor(acc[d], 16, 64);
    acc[d] += __shfl_xor(acc[d], 32, 64);
  }

  const float rden = 0.25f / (den + 1e-16f);  // fold head-mean's 1/4
  float y[16];
  float s4 = 0.f;
  const float4* hp = (const float4*)(h + (size_t)node * 64 + c * 16);
  const float4* gp = (const float4*)(gbias + c * 16);
#pragma unroll
  for (int k = 0; k < 4; k++) {
    float4 hv = hp[k], gv = gp[k];
    float hf[4] = {hv.x, hv.y, hv.z, hv.w};
    float gf[4] = {gv.x, gv.y, gv.z, gv.w};
#pragma unroll
    for (int d2 = 0; d2 < 4; d2++) {
      int d = 4 * k + d2;
      float v = acc[d] * rden;
      v += dppf<0x124>(v);  // row_ror:4
      v += dppf<0x128>(v);  // row_ror:8 -> sum over 4 heads
      y[d] = hf[d2] + v + gf[d2];
      s4 += y[d];
    }
  }

  const float mu = wave_sum(s4) * (1.f / 1024.f);
  float v4 = 0.f;
  float dv[16];
#pragma unroll
  for (int d = 0; d < 16; d++) {
    dv[d] = y[d] - mu;
    v4 += dv[d] * dv[d];
  }
  const float var = wave_sum(v4) * (1.f / 1024.f);
  const float rstd = rsqrtf(var + 1e-5f);

  if (lane < 4) {  // q=0, head=0, c=lane: owns dims [lane*16, +16)
    float4* outp = (float4*)(h2 + (size_t)node * 64 + lane * 16);
    uint2* outb = (uint2*)(h2b + (size_t)node * 64 + lane * 16);
    const float4* lgp = (const float4*)(lng + lane * 16);
    const float4* lbp = (const float4*)(lnb + lane * 16);
#pragma unroll
    for (int k = 0; k < 4; k++) {
      float4 g = lgp[k], b = lbp[k];
      float o0 = dv[4 * k + 0] * rstd * g.x + b.x;
      float o1 = dv[4 * k + 1] * rstd * g.y + b.y;
      float o2 = dv[4 * k + 2] * rstd * g.z + b.z;
      float o3 = dv[4 * k + 3] * rstd * g.w + b.w;
      float4 of; of.x = o0; of.y = o1; of.z = o2; of.w = o3;
      outp[k] = of;
      uint2 pk;
      pk.x = (unsigned int)f2b(o0) | ((unsigned int)f2b(o1) << 16);
      pk.y = (unsigned int)f2b(o2) | ((unsigned int)f2b(o3) << 16);
      outb[k] = pk;
    }
  }
}

// ---------------- pooling stage 1: partial mean/max, grid (B, 8) ----------------
__global__ void k_pool_part(const float* __restrict__ lat, const int* __restrict__ starts,
                            float* __restrict__ psum, float* __restrict__ pmax) {
  int b = blockIdx.x, p = blockIdx.y;
  int t = threadIdx.x;
  int lane = t & 63, sub = t >> 6;
  int s = starts[b], e = starts[b + 1];
  float sum = 0.f, mx = -3.4e38f;
  for (int i = s + p * 4 + sub; i < e; i += 32) {
    float v = lat[(size_t)i * 64 + lane];
    sum += v;
    mx = fmaxf(mx, v);
  }
  __shared__ float ls[4][64], lm[4][64];
  ls[sub][lane] = sum;
  lm[sub][lane] = mx;
  __syncthreads();
  if (sub == 0) {
#pragma unroll
    for (int j = 1; j < 4; j++) {
      sum += ls[j][lane];
      mx = fmaxf(mx, lm[j][lane]);
    }
    psum[(b * 8 + p) * 64 + lane] = sum;
    pmax[(b * 8 + p) * 64 + lane] = mx;
  }
}

// ---------------- pooling stage 2: reduce partials + ctx MLP ----------------
__global__ void k_ctx2(const float* __restrict__ psum, const float* __restrict__ pmax,
                       const int* __restrict__ starts,
                       const float* __restrict__ W1, const float* __restrict__ b1,
                       const float* __restrict__ W2, const float* __restrict__ b2,
                       float* __restrict__ ctx) {
  int b = blockIdx.x;
  int t = threadIdx.x;  // 128 threads
  __shared__ float g[128], tt[64];
  int cnt = starts[b + 1] - starts[b];
  if (t < 64) {
    float sm = 0.f;
#pragma unroll
    for (int p = 0; p < 8; p++) sm += psum[(b * 8 + p) * 64 + t];
    g[t] = sm / fmaxf((float)cnt, 1.0f);
  } else {
    float mx = -3.4e38f;
#pragma unroll
    for (int p = 0; p < 8; p++) mx = fmaxf(mx, pmax[(b * 8 + p) * 64 + (t - 64)]);
    g[t] = mx;
  }
  __syncthreads();
  if (t < 64) {
    float acc = b1[t];
    for (int k = 0; k < 128; k++) acc += g[k] * W1[k * 64 + t];
    tt[t] = gelu_t(acc);
  }
  __syncthreads();
  if (t < 64) {
    float acc2 = b2[t];
    for (int k = 0; k < 64; k++) acc2 += tt[k] * W2[k * 64 + t];
    ctx[b * 64 + t] = acc2;
  }
}

__global__ void k_add_ctx(float* __restrict__ h, unsigned short* __restrict__ hb,
                          const float* __restrict__ ctx,
                          const int* __restrict__ batch, int n) {
  int idx = blockIdx.x * blockDim.x + threadIdx.x;
  if (idx >= n * 64) return;
  int i = idx >> 6, d = idx & 63;
  float v = h[idx] + ctx[batch[i] * 64 + d];
  h[idx] = v;
  hb[idx] = f2b(v);
}

// ---------------- decoder stage 2: out = tD(bf16) @ W2 + b2 ([64,2]) ----------------
__global__ void k_dec2(const unsigned short* __restrict__ tD, const float* __restrict__ W2,
                       const float* __restrict__ b2, float* __restrict__ out, int n) {
  int i = blockIdx.x * blockDim.x + threadIdx.x;
  if (i >= n) return;
  const uint4* rp = (const uint4*)(tD + (size_t)i * 64);
  float a0 = b2[0], a1 = b2[1];
#pragma unroll
  for (int cblk = 0; cblk < 8; cblk++) {
    uint4 u = rp[cblk];
    float xs[8];
    unpack8(u, xs);
#pragma unroll
    for (int d = 0; d < 8; d++) {
      int k = cblk * 8 + d;
      a0 = fmaf(xs[d], W2[k * 2 + 0], a0);
      a1 = fmaf(xs[d], W2[k * 2 + 1], a1);
    }
  }
  out[2 * i] = a0;
  out[2 * i + 1] = a1;
}

// ---------------- host ----------------
extern "C" void kernel_launch(void* const* d_in, const int* in_sizes, int n_in,
                              void* d_out, int out_size, void* d_ws, size_t ws_size,
                              hipStream_t stream) {
  const float* x = (const float*)d_in[0];
  const int* ei = (const int*)d_in[1];
  const int* batch = (const int*)d_in[2];
  const float* enc_W = (const float*)d_in[3];
  const float* enc_b = (const float*)d_in[4];
  const float* gat_Wl = (const float*)d_in[5];
  const float* gat_Wr = (const float*)d_in[6];
  const float* gat_att = (const float*)d_in[7];
  const float* gat_b = (const float*)d_in[8];
  const float* ln_g = (const float*)d_in[9];
  const float* ln_b = (const float*)d_in[10];
  const float* ffn_W1 = (const float*)d_in[11];
  const float* ffn_b1 = (const float*)d_in[12];
  const float* ffn_W2 = (const float*)d_in[13];
  const float* ffn_b2 = (const float*)d_in[14];
  const float* n2g_W1 = (const float*)d_in[15];
  const float* n2g_b1 = (const float*)d_in[16];
  const float* n2g_W2 = (const float*)d_in[17];
  const float* n2g_b2 = (const float*)d_in[18];
  const float* g2n_W1 = (const float*)d_in[19];
  const float* g2n_b1 = (const float*)d_in[20];
  const float* g2n_W2 = (const float*)d_in[21];
  const float* g2n_b2 = (const float*)d_in[22];
  const float* dec_W1 = (const float*)d_in[23];
  const float* dec_b1 = (const float*)d_in[24];
  const float* dec_W2 = (const float*)d_in[25];
  const float* dec_b2 = (const float*)d_in[26];

  const int N = NN, E = EE;
  const int* e_src = ei;
  const int* e_dst = ei + E;

  // ---- workspace carve: fp32, int, then bf16 (16B-aligned) ----
  float* h = (float*)d_ws;                 // N*64
  float* h2 = h + (size_t)N * 64;          // N*64
  float* t1 = h2 + (size_t)N * 64;         // N*128 (tmpA = t1, lat = t1 + N*64)
  float* ctx = t1 + (size_t)N * 128;       // B*64
  float* psum = ctx + BBATCH * 64;         // B*8*64
  float* pmax = psum + BBATCH * 8 * 64;    // B*8*64
  int* cnt = (int*)(pmax + BBATCH * 8 * 64);  // N
  int* indptr = cnt + N;                   // N+1
  int* esrc = indptr + N + 1;              // E+N
  int* bsum = esrc + (E + N);              // 64
  int* starts = bsum + 64;                 // B+1
  size_t off = (size_t)(starts + BBATCH + 1) - (size_t)d_ws;
  off = (off + 15) & ~(size_t)15;
  unsigned short* hb = (unsigned short*)((char*)d_ws + off);   // N*64
  unsigned short* h2b = hb + (size_t)N * 64;                   // N*64
  unsigned short* tb = h2b + (size_t)N * 64;                   // N*128
  unsigned short* xlr = tb + (size_t)N * 128;                  // N*512 (xl | xr)
  unsigned short* wLR = xlr + (size_t)N * 512;                 // 4*512*64
  unsigned short* wF1 = wLR + SEG_LR;                          // 4*128*64
  unsigned short* wF2 = wF1 + SEG_F1;                          // 4*64*128
  unsigned short* wN1 = wF2 + SEG_F2;                          // 4*64*64
  unsigned short* wN2 = wN1 + SEG_N;
  unsigned short* wD1 = wN2 + SEG_N;                           // 64*64

  float* lat = t1 + (size_t)N * 64;

  const int TPB = 256;
  const int NBLK_SCAN = (N + 1 + 1023) / 1024;

  // ---- weight prep (one dispatch) ----
  hipLaunchKernelGGL(k_wprep_all, dim3((WPREP_TOTAL + 255) / 256), dim3(256), 0, stream,
                     gat_Wl, gat_Wr, ffn_W1, ffn_W2, n2g_W1, n2g_W2, dec_W1,
                     wLR, wF1, wF2, wN1, wN2, wD1);

  // ---- CSR build ----
  hipLaunchKernelGGL(k_init_cnt, dim3((N + TPB - 1) / TPB), dim3(TPB), 0, stream, cnt, N);
  hipLaunchKernelGGL(k_count_edges, dim3((E + TPB - 1) / TPB), dim3(TPB), 0, stream, e_dst, E, cnt);
  hipLaunchKernelGGL(k_scan_bsum, dim3(NBLK_SCAN), dim3(256), 0, stream, cnt, N, bsum);
  hipLaunchKernelGGL(k_scan_offsets, dim3(1), dim3(64), 0, stream, bsum, NBLK_SCAN);
  hipLaunchKernelGGL(k_scan_final, dim3(NBLK_SCAN), dim3(256), 0, stream, cnt, N, bsum, indptr);
  hipLaunchKernelGGL(k_csr_self, dim3((N + TPB - 1) / TPB), dim3(TPB), 0, stream, indptr, cnt, esrc, N);
  hipLaunchKernelGGL(k_csr_fill, dim3((E + TPB - 1) / TPB), dim3(TPB), 0, stream, e_src, e_dst, E, cnt, esrc);
  hipLaunchKernelGGL(k_batch_starts, dim3((N + TPB - 1) / TPB), dim3(TPB), 0, stream, batch, N, BBATCH, starts);

  // ---- encoder ----
  hipLaunchKernelGGL(k_encoder, dim3((N * 64 + TPB - 1) / TPB), dim3(TPB), 0, stream,
                     x, enc_W, enc_b, h, hb, N);

  const int GN = (N + 63) / 64;  // 782

  for (int l = 0; l < NLAYER; l++) {
    const unsigned short* LRt = wLR + (size_t)l * 512 * 64;
    const unsigned short* F1t = wF1 + (size_t)l * 128 * 64;
    const unsigned short* F2t = wF2 + (size_t)l * 64 * 128;
    const unsigned short* N1t = wN1 + (size_t)l * 64 * 64;
    const unsigned short* N2t = wN2 + (size_t)l * 64 * 64;
    const float* attl = gat_att + (size_t)l * 256;
    const float* gbl = gat_b + (size_t)l * 64;
    const float* lngl = ln_g + (size_t)l * 64;
    const float* lnbl = ln_b + (size_t)l * 64;
    const float* fb1 = ffn_b1 + (size_t)l * 128;
    const float* fb2 = ffn_b2 + (size_t)l * 64;
    const float* nb1 = n2g_b1 + (size_t)l * 64;
    const float* nb2 = n2g_b2 + (size_t)l * 64;
    const float* gW1 = g2n_W1 + (size_t)l * 128 * 64;
    const float* gb1 = g2n_b1 + (size_t)l * 64;
    const float* gW2 = g2n_W2 + (size_t)l * 64 * 64;
    const float* gb2 = g2n_b2 + (size_t)l * 64;

    // xlr = h @ [Wl|Wr]  (bf16 out, no bias) — one dispatch, Co=512
    hipLaunchKernelGGL((k_mgemm<64, 0, false, false, false, true>), dim3(GN, 8), dim3(256), 0, stream,
                       hb, LRt, nullptr, nullptr, nullptr, xlr, N, 512);
    // GAT aggregate + residual + LN -> h2 (+bf16)
    hipLaunchKernelGGL(k_gat, dim3((N + 3) / 4), dim3(256), 0, stream,
                       xlr, attl, gbl, lngl, lnbl, h, indptr, esrc, h2, h2b, N);
    // FFN1: tb = leaky(h2 @ W1 + b1)  (bf16 only)
    hipLaunchKernelGGL((k_mgemm<64, 1, false, true, false, true>), dim3(GN, 2), dim3(256), 0, stream,
                       h2b, F1t, fb1, nullptr, nullptr, tb, N, 128);
    // FFN2: h = tb @ W2 + b2 + h2  (fp32 + bf16)
    hipLaunchKernelGGL((k_mgemm<128, 0, true, true, true, true>), dim3(GN, 1), dim3(256), 0, stream,
                       tb, F2t, fb2, h2, h, hb, N, 64);
    // n2g1: tb = gelu(h @ nW1 + nb1)  (bf16 only)
    hipLaunchKernelGGL((k_mgemm<64, 2, false, true, false, true>), dim3(GN, 1), dim3(256), 0, stream,
                       hb, N1t, nb1, nullptr, nullptr, tb, N, 64);
    // n2g2: lat = tb @ nW2 + nb2  (fp32)
    hipLaunchKernelGGL((k_mgemm<64, 0, false, true, true, false>), dim3(GN, 1), dim3(256), 0, stream,
                       tb, N2t, nb2, nullptr, lat, nullptr, N, 64);
    // pooling: partials then reduce+MLP
    hipLaunchKernelGGL(k_pool_part, dim3(BBATCH, 8), dim3(256), 0, stream,
                       lat, starts, psum, pmax);
    hipLaunchKernelGGL(k_ctx2, dim3(BBATCH), dim3(128), 0, stream,
                       psum, pmax, starts, gW1, gb1, gW2, gb2, ctx);
    hipLaunchKernelGGL(k_add_ctx, dim3((N * 64 + TPB - 1) / TPB), dim3(TPB), 0, stream,
                       h, hb, ctx, batch, N);
  }

  // decoder: tb = gelu(h @ dW1 + db1) (bf16), then out = tb @ W2 + b2
  hipLaunchKernelGGL((k_mgemm<64, 2, false, true, false, true>), dim3(GN, 1), dim3(256), 0, stream,
                     hb, wD1, dec_b1, nullptr, nullptr, tb, N, 64);
  hipLaunchKernelGGL(k_dec2, dim3((N + TPB - 1) / TPB), dim3(TPB), 0, stream,
                     tb, dec_W2, dec_b2, (float*)d_out, N);
}

// Round 7
// 869.399 us; speedup vs baseline: 2.4559x; 1.0851x over previous
//
#include <hip/hip_runtime.h>
#include <hip/hip_bf16.h>
#include <math.h>

#define NN 50000
#define EE 800000
#define BBATCH 64
#define DDIM 64
#define NLAYER 4
#define NIN 7
#define NHEAD 4

typedef __attribute__((ext_vector_type(8))) short short8v;   // 8 bf16 (4 VGPRs)
typedef __attribute__((ext_vector_type(4))) float f32x4;     // mfma acc

// ---------------- device helpers ----------------
static __device__ __forceinline__ float wave_sum(float v) {
#pragma unroll
  for (int m = 32; m > 0; m >>= 1) v += __shfl_xor(v, m, 64);
  return v;
}

static __device__ __forceinline__ float gelu_t(float x) {
  float z = 0.7978845608f * (x + 0.044715f * x * x * x);
  float t = 2.f / (1.f + __expf(-2.f * z)) - 1.f;
  return 0.5f * x * (1.f + t);
}

static __device__ __forceinline__ unsigned short f2b(float v) {
  __hip_bfloat16 b = __float2bfloat16(v);
  return *reinterpret_cast<unsigned short*>(&b);
}

// order-preserving float -> uint key (0 is below every real key)
static __device__ __forceinline__ unsigned fkey(float x) {
  unsigned u = __builtin_bit_cast(unsigned, x);
  return (u >> 31) ? ~u : (u | 0x80000000u);
}
static __device__ __forceinline__ float fkey_inv(unsigned k) {
  unsigned u = (k & 0x80000000u) ? (k ^ 0x80000000u) : ~k;
  return __builtin_bit_cast(float, u);
}

// cross-lane add via DPP (VALU pipe, no LDS)
template <int CTRL>
static __device__ __forceinline__ float dppf(float v) {
  int x = __builtin_amdgcn_mov_dpp(__builtin_bit_cast(int, v), CTRL, 0xF, 0xF, true);
  return __builtin_bit_cast(float, x);
}
// quad_perm [1,0,3,2]=0xB1 (xor1), [2,3,0,1]=0x4E (xor2), row_ror:4=0x124, row_ror:8=0x128

static __device__ __forceinline__ void unpack8(uint4 u, float* xs) {
  unsigned int w[4] = {u.x, u.y, u.z, u.w};
#pragma unroll
  for (int k = 0; k < 4; k++) {
    xs[2 * k]     = __builtin_bit_cast(float, w[k] << 16);
    xs[2 * k + 1] = __builtin_bit_cast(float, w[k] & 0xFFFF0000u);
  }
}

// ---------------- CSR build ----------------
__global__ void k_init_cnt(int* cnt, int n) {
  int i = blockIdx.x * blockDim.x + threadIdx.x;
  if (i < n) cnt[i] = 1;  // self loop
}

__global__ void k_count_edges(const int* __restrict__ dst, int e, int* cnt) {
  int i = blockIdx.x * blockDim.x + threadIdx.x;
  if (i < e) atomicAdd(&cnt[dst[i]], 1);
}

__global__ void k_scan_bsum(const int* __restrict__ cnt, int n, int* bsum) {
  __shared__ int red[256];
  int b = blockIdx.x, t = threadIdx.x;
  int s = 0;
  for (int i = b * 1024 + t; i < (b + 1) * 1024; i += 256)
    if (i < n) s += cnt[i];
  red[t] = s;
  __syncthreads();
  for (int o = 128; o > 0; o >>= 1) {
    if (t < o) red[t] += red[t + o];
    __syncthreads();
  }
  if (t == 0) bsum[b] = red[0];
}

__global__ void k_scan_offsets(int* bsum, int nb) {
  if (threadIdx.x == 0 && blockIdx.x == 0) {
    int acc = 0;
    for (int i = 0; i < nb; i++) { int v = bsum[i]; bsum[i] = acc; acc += v; }
  }
}

__global__ void k_scan_final(const int* __restrict__ cnt, int n,
                             const int* __restrict__ bsum, int* indptr) {
  __shared__ int lds[256];
  int b = blockIdx.x, t = threadIdx.x;
  int base = b * 1024;
  int v[4];
  int s = 0;
#pragma unroll
  for (int j = 0; j < 4; j++) {
    int i = base + t * 4 + j;
    v[j] = (i < n) ? cnt[i] : 0;
    s += v[j];
  }
  lds[t] = s;
  __syncthreads();
  for (int o = 1; o < 256; o <<= 1) {
    int x = (t >= o) ? lds[t - o] : 0;
    __syncthreads();
    lds[t] += x;
    __syncthreads();
  }
  int run = bsum[b] + lds[t] - s;
#pragma unroll
  for (int j = 0; j < 4; j++) {
    int i = base + t * 4 + j;
    if (i <= n) indptr[i] = run;
    run += v[j];
  }
}

__global__ void k_csr_self(const int* __restrict__ indptr, int* nxt, int* esrc, int n) {
  int i = blockIdx.x * blockDim.x + threadIdx.x;
  if (i < n) {
    int p = indptr[i];
    esrc[p] = i;
    nxt[i] = p + 1;
  }
}

__global__ void k_csr_fill(const int* __restrict__ src, const int* __restrict__ dst,
                           int e, int* nxt, int* esrc) {
  int i = blockIdx.x * blockDim.x + threadIdx.x;
  if (i < e) {
    int p = atomicAdd(&nxt[dst[i]], 1);
    esrc[p] = src[i];
  }
}

// ---------------- batch segment starts (batch is sorted) ----------------
__global__ void k_batch_starts(const int* __restrict__ batch, int n, int nb, int* starts) {
  int i = blockIdx.x * blockDim.x + threadIdx.x;
  if (i >= n) return;
  int b = batch[i];
  if (i == 0) {
    for (int x = 0; x <= b; x++) starts[x] = 0;
  } else {
    int pb = batch[i - 1];
    if (pb != b)
      for (int x = pb + 1; x <= b; x++) starts[x] = i;
  }
  if (i == n - 1) {
    for (int x = b + 1; x <= nb; x++) starts[x] = n;
  }
}

// ---------------- merged weight prep: all fp32 W -> bf16 W^T in one dispatch ----------------
#define SEG_LR (4 * 512 * 64)
#define SEG_F1 (4 * 128 * 64)
#define SEG_F2 (4 * 64 * 128)
#define SEG_N  (4 * 64 * 64)
#define SEG_D  (64 * 64)
#define WPREP_TOTAL (SEG_LR + SEG_F1 + SEG_F2 + 2 * SEG_N + SEG_D)
__global__ void k_wprep_all(const float* __restrict__ Wl, const float* __restrict__ Wr,
                            const float* __restrict__ F1, const float* __restrict__ F2,
                            const float* __restrict__ N1, const float* __restrict__ N2,
                            const float* __restrict__ D1,
                            unsigned short* __restrict__ wLR, unsigned short* __restrict__ wF1,
                            unsigned short* __restrict__ wF2, unsigned short* __restrict__ wN1,
                            unsigned short* __restrict__ wN2, unsigned short* __restrict__ wD1) {
  int idx = blockIdx.x * blockDim.x + threadIdx.x;
  if (idx < SEG_LR) {  // [l][c:512][k:64] <- Wl/Wr [l][64][256]
    int l = idx / (512 * 64), rem = idx % (512 * 64);
    int c = rem / 64, k = rem % 64;
    float v = (c < 256) ? Wl[(size_t)l * 64 * 256 + k * 256 + c]
                        : Wr[(size_t)l * 64 * 256 + k * 256 + (c - 256)];
    wLR[idx] = f2b(v);
    return;
  }
  idx -= SEG_LR;
  if (idx < SEG_F1) {  // K=64 Co=128
    int l = idx / (128 * 64), rem = idx % (128 * 64);
    int c = rem / 64, k = rem % 64;
    wF1[idx] = f2b(F1[(size_t)l * 64 * 128 + k * 128 + c]);
    return;
  }
  idx -= SEG_F1;
  if (idx < SEG_F2) {  // K=128 Co=64
    int l = idx / (64 * 128), rem = idx % (64 * 128);
    int c = rem / 128, k = rem % 128;
    wF2[idx] = f2b(F2[(size_t)l * 128 * 64 + k * 64 + c]);
    return;
  }
  idx -= SEG_F2;
  if (idx < SEG_N) {  // K=64 Co=64
    int l = idx / (64 * 64), rem = idx % (64 * 64);
    int c = rem / 64, k = rem % 64;
    wN1[idx] = f2b(N1[(size_t)l * 64 * 64 + k * 64 + c]);
    return;
  }
  idx -= SEG_N;
  if (idx < SEG_N) {
    int l = idx / (64 * 64), rem = idx % (64 * 64);
    int c = rem / 64, k = rem % 64;
    wN2[idx] = f2b(N2[(size_t)l * 64 * 64 + k * 64 + c]);
    return;
  }
  idx -= SEG_N;
  if (idx < SEG_D) {
    int c = idx / 64, k = idx % 64;
    wD1[idx] = f2b(D1[k * 64 + c]);
  }
}

// ---------------- encoder (also emits bf16 shadow) ----------------
__global__ void k_encoder(const float* __restrict__ x, const float* __restrict__ W,
                          const float* __restrict__ bias, float* __restrict__ h,
                          unsigned short* __restrict__ hb, int n) {
  int idx = blockIdx.x * blockDim.x + threadIdx.x;
  if (idx >= n * 64) return;
  int i = idx >> 6, d = idx & 63;
  float acc = bias[d];
#pragma unroll
  for (int k = 0; k < NIN; k++) acc += x[i * NIN + k] * W[k * 64 + d];
  h[idx] = acc;
  hb[idx] = f2b(acc);
}

// ---------------- MFMA bf16 GEMM (used for xlr only now) ----------------
template <int K, int ACT, bool RES, bool BIAS, bool OUTF, bool OUTB>
__global__ __launch_bounds__(256) void k_mgemm(const unsigned short* __restrict__ A,
                                               const unsigned short* __restrict__ Wt,
                                               const float* __restrict__ bias,
                                               const float* __restrict__ res,
                                               float* __restrict__ C,
                                               unsigned short* __restrict__ Cb,
                                               int n, int Co) {
  constexpr int NF = K / 32;
  const int lane = threadIdx.x & 63, wave = threadIdx.x >> 6;
  const int row0 = blockIdx.x * 64 + wave * 16;
  const int c0 = blockIdx.y * 64;
  const int karow = (lane >> 4) * 8;
  const int arow = row0 + (lane & 15);
  const size_t abase = (size_t)(arow < n ? arow : 0) * K + karow;

  short8v a[NF];
#pragma unroll
  for (int f = 0; f < NF; f++)
    a[f] = *(const short8v*)(A + abase + f * 32);

  f32x4 acc[4];
#pragma unroll
  for (int cc = 0; cc < 4; cc++) {
    const int c = c0 + cc * 16 + (lane & 15);
    f32x4 t = {0.f, 0.f, 0.f, 0.f};
#pragma unroll
    for (int f = 0; f < NF; f++) {
      short8v b = *(const short8v*)(Wt + (size_t)c * K + f * 32 + karow);
      t = __builtin_amdgcn_mfma_f32_16x16x32_bf16(a[f], b, t, 0, 0, 0);
    }
    acc[cc] = t;
  }

#pragma unroll
  for (int cc = 0; cc < 4; cc++) {
    const int c = c0 + cc * 16 + (lane & 15);
    const float bv = BIAS ? bias[c] : 0.f;
#pragma unroll
    for (int r = 0; r < 4; r++) {
      const int row = row0 + (lane >> 4) * 4 + r;
      if (row < n) {
        float v = acc[cc][r] + bv;
        if (ACT == 1) v = fmaxf(v, 0.2f * v);
        else if (ACT == 2) v = gelu_t(v);
        if (RES) v += res[(size_t)row * Co + c];
        if (OUTF) C[(size_t)row * Co + c] = v;
        if (OUTB) Cb[(size_t)row * Co + c] = f2b(v);
      }
    }
  }
}

// ---------------- fused FFN: h = (leaky(h2@W1+b1))@W2 + b2 + h2 ----------------
// Stage1 (K=64 -> 128, leaky) -> LDS bf16 [16][128] per wave -> Stage2 (K=128 -> 64)
__global__ __launch_bounds__(256) void k_ffn(const unsigned short* __restrict__ A,  // h2b
                                             const unsigned short* __restrict__ W1t, // [128][64]
                                             const float* __restrict__ b1,
                                             const unsigned short* __restrict__ W2t, // [64][128]
                                             const float* __restrict__ b2,
                                             const float* __restrict__ res,          // h2 fp32
                                             float* __restrict__ C,
                                             unsigned short* __restrict__ Cb, int n) {
  __shared__ unsigned short tl[4][16 * 136];
  const int lane = threadIdx.x & 63, wave = threadIdx.x >> 6;
  const int row0 = blockIdx.x * 64 + wave * 16;
  const int karow = (lane >> 4) * 8;
  const int arow = row0 + (lane & 15);
  const size_t abase = (size_t)(arow < n ? arow : 0) * 64 + karow;
  short8v a0 = *(const short8v*)(A + abase);
  short8v a1 = *(const short8v*)(A + abase + 32);

#pragma unroll
  for (int cc = 0; cc < 8; cc++) {
    const int c = cc * 16 + (lane & 15);
    f32x4 t = {0.f, 0.f, 0.f, 0.f};
    t = __builtin_amdgcn_mfma_f32_16x16x32_bf16(a0, *(const short8v*)(W1t + (size_t)c * 64 + karow), t, 0, 0, 0);
    t = __builtin_amdgcn_mfma_f32_16x16x32_bf16(a1, *(const short8v*)(W1t + (size_t)c * 64 + 32 + karow), t, 0, 0, 0);
    const float bv = b1[c];
#pragma unroll
    for (int r = 0; r < 4; r++) {
      float v = t[r] + bv;
      v = fmaxf(v, 0.2f * v);
      int rr = (lane >> 4) * 4 + r;
      tl[wave][rr * 136 + c] = f2b(v);
    }
  }
  __syncthreads();

  short8v a2[4];
#pragma unroll
  for (int f = 0; f < 4; f++)
    a2[f] = *(const short8v*)(&tl[wave][(lane & 15) * 136 + f * 32 + karow]);

#pragma unroll
  for (int cc = 0; cc < 4; cc++) {
    const int c = cc * 16 + (lane & 15);
    f32x4 t = {0.f, 0.f, 0.f, 0.f};
#pragma unroll
    for (int f = 0; f < 4; f++)
      t = __builtin_amdgcn_mfma_f32_16x16x32_bf16(a2[f], *(const short8v*)(W2t + (size_t)c * 128 + f * 32 + karow), t, 0, 0, 0);
    const float bv = b2[c];
#pragma unroll
    for (int r = 0; r < 4; r++) {
      const int row = row0 + (lane >> 4) * 4 + r;
      if (row < n) {
        float v = t[r] + bv + res[(size_t)row * 64 + c];
        C[(size_t)row * 64 + c] = v;
        Cb[(size_t)row * 64 + c] = f2b(v);
      }
    }
  }
}

// ---------------- fused n2g: lat = gelu(h@N1+b1)@N2+b2, pooled in-kernel ----------------
__global__ __launch_bounds__(256) void k_n2g(const unsigned short* __restrict__ A,   // hb
                                             const unsigned short* __restrict__ W1t, // [64][64]
                                             const float* __restrict__ b1,
                                             const unsigned short* __restrict__ W2t, // [64][64]
                                             const float* __restrict__ b2,
                                             const int* __restrict__ batch,
                                             float* __restrict__ psum,
                                             unsigned int* __restrict__ pmax, int n) {
  __shared__ unsigned short tl[4][16 * 72];
  __shared__ float s_sum[64];
  __shared__ unsigned s_max[64];
  const int lane = threadIdx.x & 63, wave = threadIdx.x >> 6;
  const int row0b = blockIdx.x * 64;
  const int row0 = row0b + wave * 16;
  const int karow = (lane >> 4) * 8;
  const int arow = row0 + (lane & 15);
  const size_t abase = (size_t)(arow < n ? arow : 0) * 64 + karow;
  if (threadIdx.x < 64) { s_sum[threadIdx.x] = 0.f; s_max[threadIdx.x] = 0u; }
  short8v a0 = *(const short8v*)(A + abase);
  short8v a1 = *(const short8v*)(A + abase + 32);

#pragma unroll
  for (int cc = 0; cc < 4; cc++) {
    const int c = cc * 16 + (lane & 15);
    f32x4 t = {0.f, 0.f, 0.f, 0.f};
    t = __builtin_amdgcn_mfma_f32_16x16x32_bf16(a0, *(const short8v*)(W1t + (size_t)c * 64 + karow), t, 0, 0, 0);
    t = __builtin_amdgcn_mfma_f32_16x16x32_bf16(a1, *(const short8v*)(W1t + (size_t)c * 64 + 32 + karow), t, 0, 0, 0);
    const float bv = b1[c];
#pragma unroll
    for (int r = 0; r < 4; r++) {
      int rr = (lane >> 4) * 4 + r;
      tl[wave][rr * 72 + c] = f2b(gelu_t(t[r] + bv));
    }
  }
  __syncthreads();

  short8v a2[2];
#pragma unroll
  for (int f = 0; f < 2; f++)
    a2[f] = *(const short8v*)(&tl[wave][(lane & 15) * 72 + f * 32 + karow]);

  float pv[4][4];
#pragma unroll
  for (int cc = 0; cc < 4; cc++) {
    const int c = cc * 16 + (lane & 15);
    f32x4 t = {0.f, 0.f, 0.f, 0.f};
    t = __builtin_amdgcn_mfma_f32_16x16x32_bf16(a2[0], *(const short8v*)(W2t + (size_t)c * 64 + karow), t, 0, 0, 0);
    t = __builtin_amdgcn_mfma_f32_16x16x32_bf16(a2[1], *(const short8v*)(W2t + (size_t)c * 64 + 32 + karow), t, 0, 0, 0);
    const float bv = b2[c];
#pragma unroll
    for (int r = 0; r < 4; r++) pv[cc][r] = t[r] + bv;
  }

  // pooling epilogue
  const int blo = batch[row0b];
  const int last = row0b + 63 < n ? row0b + 63 : n - 1;
  const int bhi = batch[last];
  if (blo == bhi && row0b + 63 < n) {
    // fast path: whole block one batch, all rows valid
#pragma unroll
    for (int cc = 0; cc < 4; cc++) {
      const int c = cc * 16 + (lane & 15);
      float s = pv[cc][0] + pv[cc][1] + pv[cc][2] + pv[cc][3];
      float mx = fmaxf(fmaxf(pv[cc][0], pv[cc][1]), fmaxf(pv[cc][2], pv[cc][3]));
      atomicAdd(&s_sum[c], s);
      atomicMax(&s_max[c], fkey(mx));
    }
    __syncthreads();
    if (threadIdx.x < 64) {
      atomicAdd(&psum[blo * 64 + threadIdx.x], s_sum[threadIdx.x]);
      atomicMax(&pmax[blo * 64 + threadIdx.x], s_max[threadIdx.x]);
    }
  } else {
    // slow path: per-value atomics (rare: batch straddle or n-edge)
#pragma unroll
    for (int cc = 0; cc < 4; cc++) {
      const int c = cc * 16 + (lane & 15);
#pragma unroll
      for (int r = 0; r < 4; r++) {
        const int row = row0 + (lane >> 4) * 4 + r;
        if (row < n) {
          const int b = batch[row];
          atomicAdd(&psum[b * 64 + c], pv[cc][r]);
          atomicMax(&pmax[b * 64 + c], fkey(pv[cc][r]));
        }
      }
    }
  }
}

// ---------------- GATv2 aggregation + residual + LayerNorm (fused, 2-deep pipeline) ------
__global__ __launch_bounds__(256) void k_gat(const unsigned short* __restrict__ xlr,
                                             const float* __restrict__ att,
                                             const float* __restrict__ gbias,
                                             const float* __restrict__ lng,
                                             const float* __restrict__ lnb,
                                             const float* __restrict__ h,
                                             const int* __restrict__ indptr,
                                             const int* __restrict__ esrc,
                                             float* __restrict__ h2,
                                             unsigned short* __restrict__ h2b, int n) {
  const int wave = threadIdx.x >> 6, lane = threadIdx.x & 63;
  const int node = blockIdx.x * 4 + wave;
  if (node >= n) return;
  const int q = lane >> 4, r = lane & 15;
  const int c = r & 3;
  const int doff = (r >> 2) * 64 + c * 16;

  float xr_d[16], att_d[16];
  {
    const uint4* xp = (const uint4*)(xlr + (size_t)node * 512 + 256 + doff);
    uint4 u0 = xp[0], u1 = xp[1];
    unpack8(u0, xr_d);
    unpack8(u1, xr_d + 8);
    const float4* ap = (const float4*)(att + doff);
#pragma unroll
    for (int k = 0; k < 4; k++) {
      float4 a = ap[k];
      att_d[4 * k] = a.x; att_d[4 * k + 1] = a.y;
      att_d[4 * k + 2] = a.z; att_d[4 * k + 3] = a.w;
    }
  }

  float acc[16] = {};
  float den = 0.f;
  const int beg = indptr[node], end = indptr[node + 1];

  // 2-deep pipeline: data 1 ahead, esrc index 2 ahead
  int j0 = beg + q;
  int s_cur = esrc[(j0 < end) ? j0 : beg];
  const uint4* xp0 = (const uint4*)(xlr + (size_t)s_cur * 512 + doff);
  uint4 u0 = xp0[0], u1 = xp0[1];
  int jn1 = beg + 4 + q;
  int s_nxt = esrc[(jn1 < end && beg + 4 < end) ? jn1 : beg];

  for (int jb = beg; jb < end; jb += 4) {
    const uint4 cu0 = u0, cu1 = u1;
    const bool cvalid = (jb + q) < end;
    if (jb + 4 < end) {
      const uint4* xpn = (const uint4*)(xlr + (size_t)s_nxt * 512 + doff);
      u0 = xpn[0];
      u1 = xpn[1];
      if (jb + 8 < end) {
        const int jn = jb + 8 + q;
        s_nxt = esrc[(jn < end) ? jn : beg];
      }
    }
    float xs[16];
    unpack8(cu0, xs);
    unpack8(cu1, xs + 8);
    float p0 = 0.f, p1 = 0.f, p2 = 0.f, p3 = 0.f;
#pragma unroll
    for (int k = 0; k < 4; k++) {
      float t0 = xs[4 * k + 0] + xr_d[4 * k + 0]; t0 = fmaxf(t0, 0.2f * t0); p0 = fmaf(t0, att_d[4 * k + 0], p0);
      float t1 = xs[4 * k + 1] + xr_d[4 * k + 1]; t1 = fmaxf(t1, 0.2f * t1); p1 = fmaf(t1, att_d[4 * k + 1], p1);
      float t2 = xs[4 * k + 2] + xr_d[4 * k + 2]; t2 = fmaxf(t2, 0.2f * t2); p2 = fmaf(t2, att_d[4 * k + 2], p2);
      float t3 = xs[4 * k + 3] + xr_d[4 * k + 3]; t3 = fmaxf(t3, 0.2f * t3); p3 = fmaf(t3, att_d[4 * k + 3], p3);
    }
    float p = (p0 + p1) + (p2 + p3);
    p += dppf<0xB1>(p);
    p += dppf<0x4E>(p);
    const float pw = cvalid ? __expf(fminf(p, 60.f)) : 0.f;
    den += pw;
#pragma unroll
    for (int d = 0; d < 16; d++) acc[d] = fmaf(pw, xs[d], acc[d]);
  }

  den += __shfl_xor(den, 16, 64);
  den += __shfl_xor(den, 32, 64);
#pragma unroll
  for (int d = 0; d < 16; d++) {
    acc[d] += __shfl_xor(acc[d], 16, 64);
    acc[d] += __shfl_xor(acc[d], 32, 64);
  }

  const float rden = 0.25f / (den + 1e-16f);
  float y[16];
  float s4 = 0.f;
  const float4* hp = (const float4*)(h + (size_t)node * 64 + c * 16);
  const float4* gp = (const float4*)(gbias + c * 16);
#pragma unroll
  for (int k = 0; k < 4; k++) {
    float4 hv = hp[k], gv = gp[k];
    float hf[4] = {hv.x, hv.y, hv.z, hv.w};
    float gf[4] = {gv.x, gv.y, gv.z, gv.w};
#pragma unroll
    for (int d2 = 0; d2 < 4; d2++) {
      int d = 4 * k + d2;
      float v = acc[d] * rden;
      v += dppf<0x124>(v);
      v += dppf<0x128>(v);
      y[d] = hf[d2] + v + gf[d2];
      s4 += y[d];
    }
  }

  const float mu = wave_sum(s4) * (1.f / 1024.f);
  float v4 = 0.f;
  float dv[16];
#pragma unroll
  for (int d = 0; d < 16; d++) {
    dv[d] = y[d] - mu;
    v4 += dv[d] * dv[d];
  }
  const float var = wave_sum(v4) * (1.f / 1024.f);
  const float rstd = rsqrtf(var + 1e-5f);

  if (lane < 4) {
    float4* outp = (float4*)(h2 + (size_t)node * 64 + lane * 16);
    uint2* outb = (uint2*)(h2b + (size_t)node * 64 + lane * 16);
    const float4* lgp = (const float4*)(lng + lane * 16);
    const float4* lbp = (const float4*)(lnb + lane * 16);
#pragma unroll
    for (int k = 0; k < 4; k++) {
      float4 g = lgp[k], b = lbp[k];
      float o0 = dv[4 * k + 0] * rstd * g.x + b.x;
      float o1 = dv[4 * k + 1] * rstd * g.y + b.y;
      float o2 = dv[4 * k + 2] * rstd * g.z + b.z;
      float o3 = dv[4 * k + 3] * rstd * g.w + b.w;
      float4 of; of.x = o0; of.y = o1; of.z = o2; of.w = o3;
      outp[k] = of;
      uint2 pk;
      pk.x = (unsigned int)f2b(o0) | ((unsigned int)f2b(o1) << 16);
      pk.y = (unsigned int)f2b(o2) | ((unsigned int)f2b(o3) << 16);
      outb[k] = pk;
    }
  }
}

// ---------------- ctx MLP from pooled psum/pmax ----------------
__global__ void k_ctx2(const float* __restrict__ psum, const unsigned int* __restrict__ pmax,
                       const int* __restrict__ starts,
                       const float* __restrict__ W1, const float* __restrict__ b1,
                       const float* __restrict__ W2, const float* __restrict__ b2,
                       float* __restrict__ ctx) {
  int b = blockIdx.x;
  int t = threadIdx.x;  // 128 threads
  __shared__ float g[128], tt[64];
  int cnt = starts[b + 1] - starts[b];
  if (t < 64) {
    g[t] = psum[b * 64 + t] / fmaxf((float)cnt, 1.0f);
  } else {
    g[t] = fkey_inv(pmax[b * 64 + (t - 64)]);
  }
  __syncthreads();
  if (t < 64) {
    float acc = b1[t];
    for (int k = 0; k < 128; k++) acc += g[k] * W1[k * 64 + t];
    tt[t] = gelu_t(acc);
  }
  __syncthreads();
  if (t < 64) {
    float acc2 = b2[t];
    for (int k = 0; k < 64; k++) acc2 += tt[k] * W2[k * 64 + t];
    ctx[b * 64 + t] = acc2;
  }
}

__global__ void k_add_ctx(float* __restrict__ h, unsigned short* __restrict__ hb,
                          const float* __restrict__ ctx,
                          const int* __restrict__ batch, int n) {
  int idx = blockIdx.x * blockDim.x + threadIdx.x;
  if (idx >= n * 64) return;
  int i = idx >> 6, d = idx & 63;
  float v = h[idx] + ctx[batch[i] * 64 + d];
  h[idx] = v;
  hb[idx] = f2b(v);
}

// ---------------- fused decoder: out = gelu(h@W1+b1)@W2 + b2 ----------------
__global__ __launch_bounds__(256) void k_dec(const unsigned short* __restrict__ A,   // hb
                                             const unsigned short* __restrict__ W1t, // [64][64]
                                             const float* __restrict__ b1,
                                             const float* __restrict__ W2,           // [64][2] fp32
                                             const float* __restrict__ b2,
                                             float* __restrict__ out, int n) {
  const int lane = threadIdx.x & 63, wave = threadIdx.x >> 6;
  const int row0 = blockIdx.x * 64 + wave * 16;
  const int karow = (lane >> 4) * 8;
  const int arow = row0 + (lane & 15);
  const size_t abase = (size_t)(arow < n ? arow : 0) * 64 + karow;
  short8v a0 = *(const short8v*)(A + abase);
  short8v a1 = *(const short8v*)(A + abase + 32);

  float o0[4] = {}, o1[4] = {};
#pragma unroll
  for (int cc = 0; cc < 4; cc++) {
    const int cidx = cc * 16 + (lane & 15);
    f32x4 t = {0.f, 0.f, 0.f, 0.f};
    t = __builtin_amdgcn_mfma_f32_16x16x32_bf16(a0, *(const short8v*)(W1t + (size_t)cidx * 64 + karow), t, 0, 0, 0);
    t = __builtin_amdgcn_mfma_f32_16x16x32_bf16(a1, *(const short8v*)(W1t + (size_t)cidx * 64 + 32 + karow), t, 0, 0, 0);
    const float bv = b1[cidx];
    const float w0 = W2[cidx * 2 + 0], w1 = W2[cidx * 2 + 1];
#pragma unroll
    for (int r = 0; r < 4; r++) {
      float v = gelu_t(t[r] + bv);
      o0[r] = fmaf(v, w0, o0[r]);
      o1[r] = fmaf(v, w1, o1[r]);
    }
  }
  // reduce across the 16 col-lanes
#pragma unroll
  for (int m = 1; m < 16; m <<= 1) {
#pragma unroll
    for (int r = 0; r < 4; r++) {
      o0[r] += __shfl_xor(o0[r], m, 64);
      o1[r] += __shfl_xor(o1[r], m, 64);
    }
  }
  if ((lane & 15) == 0) {
#pragma unroll
    for (int r = 0; r < 4; r++) {
      const int row = row0 + (lane >> 4) * 4 + r;
      if (row < n) {
        out[2 * row] = o0[r] + b2[0];
        out[2 * row + 1] = o1[r] + b2[1];
      }
    }
  }
}

// ---------------- host ----------------
extern "C" void kernel_launch(void* const* d_in, const int* in_sizes, int n_in,
                              void* d_out, int out_size, void* d_ws, size_t ws_size,
                              hipStream_t stream) {
  const float* x = (const float*)d_in[0];
  const int* ei = (const int*)d_in[1];
  const int* batch = (const int*)d_in[2];
  const float* enc_W = (const float*)d_in[3];
  const float* enc_b = (const float*)d_in[4];
  const float* gat_Wl = (const float*)d_in[5];
  const float* gat_Wr = (const float*)d_in[6];
  const float* gat_att = (const float*)d_in[7];
  const float* gat_b = (const float*)d_in[8];
  const float* ln_g = (const float*)d_in[9];
  const float* ln_b = (const float*)d_in[10];
  const float* ffn_W1 = (const float*)d_in[11];
  const float* ffn_b1 = (const float*)d_in[12];
  const float* ffn_W2 = (const float*)d_in[13];
  const float* ffn_b2 = (const float*)d_in[14];
  const float* n2g_W1 = (const float*)d_in[15];
  const float* n2g_b1 = (const float*)d_in[16];
  const float* n2g_W2 = (const float*)d_in[17];
  const float* n2g_b2 = (const float*)d_in[18];
  const float* g2n_W1 = (const float*)d_in[19];
  const float* g2n_b1 = (const float*)d_in[20];
  const float* g2n_W2 = (const float*)d_in[21];
  const float* g2n_b2 = (const float*)d_in[22];
  const float* dec_W1 = (const float*)d_in[23];
  const float* dec_b1 = (const float*)d_in[24];
  const float* dec_W2 = (const float*)d_in[25];
  const float* dec_b2 = (const float*)d_in[26];

  const int N = NN, E = EE;
  const int* e_src = ei;
  const int* e_dst = ei + E;

  // ---- workspace carve: fp32, int, then bf16 (16B-aligned) ----
  float* h = (float*)d_ws;                 // N*64
  float* h2 = h + (size_t)N * 64;          // N*64
  float* ctx = h2 + (size_t)N * 64;        // B*64
  float* psum = ctx + BBATCH * 64;         // B*64 (pooled sums)
  unsigned int* pmax = (unsigned int*)(psum + BBATCH * 64);  // B*64 (keyed max)
  int* cnt = (int*)(pmax + BBATCH * 64);   // N
  int* indptr = cnt + N;                   // N+1
  int* esrc = indptr + N + 1;              // E+N
  int* bsum = esrc + (E + N);              // 64
  int* starts = bsum + 64;                 // B+1
  size_t off = (size_t)(starts + BBATCH + 1) - (size_t)d_ws;
  off = (off + 15) & ~(size_t)15;
  unsigned short* hb = (unsigned short*)((char*)d_ws + off);   // N*64
  unsigned short* h2b = hb + (size_t)N * 64;                   // N*64
  unsigned short* xlr = h2b + (size_t)N * 64;                  // N*512 (xl | xr)
  unsigned short* wLR = xlr + (size_t)N * 512;                 // 4*512*64
  unsigned short* wF1 = wLR + SEG_LR;                          // 4*128*64
  unsigned short* wF2 = wF1 + SEG_F1;                          // 4*64*128
  unsigned short* wN1 = wF2 + SEG_F2;                          // 4*64*64
  unsigned short* wN2 = wN1 + SEG_N;
  unsigned short* wD1 = wN2 + SEG_N;                           // 64*64

  const int TPB = 256;
  const int NBLK_SCAN = (N + 1 + 1023) / 1024;

  // ---- weight prep (one dispatch) ----
  hipLaunchKernelGGL(k_wprep_all, dim3((WPREP_TOTAL + 255) / 256), dim3(256), 0, stream,
                     gat_Wl, gat_Wr, ffn_W1, ffn_W2, n2g_W1, n2g_W2, dec_W1,
                     wLR, wF1, wF2, wN1, wN2, wD1);

  // ---- CSR build ----
  hipLaunchKernelGGL(k_init_cnt, dim3((N + TPB - 1) / TPB), dim3(TPB), 0, stream, cnt, N);
  hipLaunchKernelGGL(k_count_edges, dim3((E + TPB - 1) / TPB), dim3(TPB), 0, stream, e_dst, E, cnt);
  hipLaunchKernelGGL(k_scan_bsum, dim3(NBLK_SCAN), dim3(256), 0, stream, cnt, N, bsum);
  hipLaunchKernelGGL(k_scan_offsets, dim3(1), dim3(64), 0, stream, bsum, NBLK_SCAN);
  hipLaunchKernelGGL(k_scan_final, dim3(NBLK_SCAN), dim3(256), 0, stream, cnt, N, bsum, indptr);
  hipLaunchKernelGGL(k_csr_self, dim3((N + TPB - 1) / TPB), dim3(TPB), 0, stream, indptr, cnt, esrc, N);
  hipLaunchKernelGGL(k_csr_fill, dim3((E + TPB - 1) / TPB), dim3(TPB), 0, stream, e_src, e_dst, E, cnt, esrc);
  hipLaunchKernelGGL(k_batch_starts, dim3((N + TPB - 1) / TPB), dim3(TPB), 0, stream, batch, N, BBATCH, starts);

  // ---- encoder ----
  hipLaunchKernelGGL(k_encoder, dim3((N * 64 + TPB - 1) / TPB), dim3(TPB), 0, stream,
                     x, enc_W, enc_b, h, hb, N);

  const int GN = (N + 63) / 64;  // 782

  for (int l = 0; l < NLAYER; l++) {
    const unsigned short* LRt = wLR + (size_t)l * 512 * 64;
    const unsigned short* F1t = wF1 + (size_t)l * 128 * 64;
    const unsigned short* F2t = wF2 + (size_t)l * 64 * 128;
    const unsigned short* N1t = wN1 + (size_t)l * 64 * 64;
    const unsigned short* N2t = wN2 + (size_t)l * 64 * 64;
    const float* attl = gat_att + (size_t)l * 256;
    const float* gbl = gat_b + (size_t)l * 64;
    const float* lngl = ln_g + (size_t)l * 64;
    const float* lnbl = ln_b + (size_t)l * 64;
    const float* fb1 = ffn_b1 + (size_t)l * 128;
    const float* fb2 = ffn_b2 + (size_t)l * 64;
    const float* nb1 = n2g_b1 + (size_t)l * 64;
    const float* nb2 = n2g_b2 + (size_t)l * 64;
    const float* gW1 = g2n_W1 + (size_t)l * 128 * 64;
    const float* gb1 = g2n_b1 + (size_t)l * 64;
    const float* gW2 = g2n_W2 + (size_t)l * 64 * 64;
    const float* gb2 = g2n_b2 + (size_t)l * 64;

    // xlr = h @ [Wl|Wr]  (bf16 out) — one dispatch, Co=512
    hipLaunchKernelGGL((k_mgemm<64, 0, false, false, false, true>), dim3(GN, 8), dim3(256), 0, stream,
                       hb, LRt, nullptr, nullptr, nullptr, xlr, N, 512);
    // GAT aggregate + residual + LN -> h2 (+bf16)
    hipLaunchKernelGGL(k_gat, dim3((N + 3) / 4), dim3(256), 0, stream,
                       xlr, attl, gbl, lngl, lnbl, h, indptr, esrc, h2, h2b, N);
    // fused FFN -> h (+hb)
    hipLaunchKernelGGL(k_ffn, dim3(GN), dim3(256), 0, stream,
                       h2b, F1t, fb1, F2t, fb2, h2, h, hb, N);
    // reset pooled accumulators, then fused n2g + pooling
    hipMemsetAsync(psum, 0, BBATCH * 64 * (sizeof(float) + sizeof(unsigned int)), stream);
    hipLaunchKernelGGL(k_n2g, dim3(GN), dim3(256), 0, stream,
                       hb, N1t, nb1, N2t, nb2, batch, psum, pmax, N);
    // ctx MLP + broadcast-add
    hipLaunchKernelGGL(k_ctx2, dim3(BBATCH), dim3(128), 0, stream,
                       psum, pmax, starts, gW1, gb1, gW2, gb2, ctx);
    hipLaunchKernelGGL(k_add_ctx, dim3((N * 64 + TPB - 1) / TPB), dim3(TPB), 0, stream,
                       h, hb, ctx, batch, N);
  }

  // fused decoder
  hipLaunchKernelGGL(k_dec, dim3(GN), dim3(256), 0, stream,
                     hb, wD1, dec_b1, dec_W2, dec_b2, (float*)d_out, N);
}